// Round 11
// baseline (76876.764 us; speedup 1.0000x reference)
//
#include <hip/hip_runtime.h>

typedef __attribute__((ext_vector_type(8))) _Float16 half8;
typedef __attribute__((ext_vector_type(4))) float f32x4;
typedef __attribute__((ext_vector_type(4))) int   i32x4;

#define DEV static __device__ __forceinline__

DEV i32x4 mfma8i(i32x4 a, i32x4 b, i32x4 c){
  return __builtin_amdgcn_mfma_i32_16x16x64_i8(a, b, c, 0, 0, 0);
}
DEV void spin_ge(unsigned int* p, unsigned int target){
  while (__hip_atomic_load(p, __ATOMIC_ACQUIRE, __HIP_MEMORY_SCOPE_AGENT) < target)
    __builtin_amdgcn_s_sleep(2);
}
DEV void sig_inc(unsigned int* p){
  __hip_atomic_fetch_add(p, 1u, __ATOMIC_RELEASE, __HIP_MEMORY_SCOPE_AGENT);
}

// W5 x H5 plane products grouped by scale d=i+j (d=2..7)
DEV void str_h(const i32x4* W, const i32x4* B, i32x4* G){
  G[0]=mfma8i(W[0],B[0],G[0]);
  G[1]=mfma8i(W[0],B[1],G[1]); G[1]=mfma8i(W[1],B[0],G[1]);
  G[2]=mfma8i(W[0],B[2],G[2]); G[2]=mfma8i(W[1],B[1],G[2]); G[2]=mfma8i(W[2],B[0],G[2]);
  G[3]=mfma8i(W[0],B[3],G[3]); G[3]=mfma8i(W[1],B[2],G[3]); G[3]=mfma8i(W[2],B[1],G[3]); G[3]=mfma8i(W[3],B[0],G[3]);
  G[4]=mfma8i(W[0],B[4],G[4]); G[4]=mfma8i(W[1],B[3],G[4]); G[4]=mfma8i(W[2],B[2],G[4]); G[4]=mfma8i(W[3],B[1],G[4]); G[4]=mfma8i(W[4],B[0],G[4]);
  G[5]=mfma8i(W[1],B[4],G[5]); G[5]=mfma8i(W[2],B[3],G[5]); G[5]=mfma8i(W[3],B[2],G[5]); G[5]=mfma8i(W[4],B[1],G[5]);
}
// W5 x X6 plane products grouped by scale (d=2..7)
DEV void str_x(const i32x4* W, const i32x4* X, i32x4* G){
  G[0]=mfma8i(W[0],X[0],G[0]);
  G[1]=mfma8i(W[0],X[1],G[1]); G[1]=mfma8i(W[1],X[0],G[1]);
  G[2]=mfma8i(W[0],X[2],G[2]); G[2]=mfma8i(W[1],X[1],G[2]); G[2]=mfma8i(W[2],X[0],G[2]);
  G[3]=mfma8i(W[0],X[3],G[3]); G[3]=mfma8i(W[1],X[2],G[3]); G[3]=mfma8i(W[2],X[1],G[3]); G[3]=mfma8i(W[3],X[0],G[3]);
  G[4]=mfma8i(W[0],X[4],G[4]); G[4]=mfma8i(W[1],X[3],G[4]); G[4]=mfma8i(W[2],X[2],G[4]); G[4]=mfma8i(W[3],X[1],G[4]); G[4]=mfma8i(W[4],X[0],G[4]);
  G[5]=mfma8i(W[0],X[5],G[5]); G[5]=mfma8i(W[1],X[4],G[5]); G[5]=mfma8i(W[2],X[3],G[5]); G[5]=mfma8i(W[3],X[2],G[5]); G[5]=mfma8i(W[4],X[1],G[5]);
}

// ---------------- prep ----------------
__global__ void k_prep_zero(unsigned int* cnt){
  if (threadIdx.x < 16) cnt[threadIdx.x] = 0u;
}

// W planes: W = p1*2^-11 + ... + p5*2^-39 (trunc 2^-40)
DEV void wsplit5(float v, char* o1, char* o2, char* o3, char* o4, char* o5){
  float q1 = rintf(v * 0x1p11f);
  float r1 = fmaf(q1, -0x1p-11f, v);
  float q2 = rintf(r1 * 0x1p18f);
  float r2 = fmaf(q2, -0x1p-18f, r1);
  float q3 = rintf(r2 * 0x1p25f);
  float r3 = fmaf(q3, -0x1p-25f, r2);
  float q4 = rintf(r3 * 0x1p32f);
  float r4 = fmaf(q4, -0x1p-32f, r3);
  float q5 = rintf(r4 * 0x1p39f);
  *o1=(char)(int)q1; *o2=(char)(int)q2; *o3=(char)(int)q3;
  *o4=(char)(int)q4; *o5=(char)(int)q5;
}

__global__ void k_prep_w0(const float* __restrict__ Wih0, const float* __restrict__ Whh0,
                          char* __restrict__ p1, char* __restrict__ p2, char* __restrict__ p3,
                          char* __restrict__ p4, char* __restrict__ p5){
  int idx = blockIdx.x * 256 + threadIdx.x;      // 1179648
  int k = idx % 576;
  int r = (idx / 576) & 63;
  int j = idx / 36864;
  int R = (r & 3) * 512 + j * 16 + (r >> 2);
  float v = (k < 512) ? Whh0[(size_t)R * 512 + k] : Wih0[(size_t)R * 64 + (k - 512)];
  wsplit5(v, p1 + idx, p2 + idx, p3 + idx, p4 + idx, p5 + idx);
}

__global__ void k_prep_w1(const float* __restrict__ Wih1, const float* __restrict__ Whh1,
                          char* __restrict__ p1, char* __restrict__ p2, char* __restrict__ p3,
                          char* __restrict__ p4, char* __restrict__ p5){
  int idx = blockIdx.x * 256 + threadIdx.x;      // 2097152
  int k = idx & 1023;
  int r = (idx >> 10) & 63;
  int j = idx >> 16;
  int R = (r & 3) * 512 + j * 16 + (r >> 2);
  float v = (k < 512) ? Wih1[(size_t)R * 512 + k] : Whh1[(size_t)R * 512 + (k - 512)];
  wsplit5(v, p1 + idx, p2 + idx, p3 + idx, p4 + idx, p5 + idx);
}

__global__ void k_prep_b(const float* __restrict__ bih0, const float* __restrict__ bhh0,
                         const float* __restrict__ bih1, const float* __restrict__ bhh1,
                         double* __restrict__ bias0, double* __restrict__ bias1){
  int idx = blockIdx.x * 256 + threadIdx.x;      // 4096
  int i2 = idx & 2047;
  int j = i2 >> 6, r = i2 & 63;
  int R = (r & 3) * 512 + j * 16 + (r >> 2);
  if (idx < 2048) bias0[i2] = (double)bih0[R] + (double)bhh0[R];
  else            bias1[i2] = (double)bih1[R] + (double)bhh1[R];
}

// W_a -> 4 i8 planes (2^-11,-18,-25,-32; residual <= 2^-33)
__global__ void k_prep_wa(const float* __restrict__ Wa,
                          char* __restrict__ p1, char* __restrict__ p2,
                          char* __restrict__ p3, char* __restrict__ p4){
  int idx = blockIdx.x * 256 + threadIdx.x;      // 262144
  float v = Wa[idx];
  float q1 = rintf(v * 0x1p11f);
  float r1 = fmaf(q1, -0x1p-11f, v);
  float q2 = rintf(r1 * 0x1p18f);
  float r2 = fmaf(q2, -0x1p-18f, r1);
  float q3 = rintf(r2 * 0x1p25f);
  float r3 = fmaf(q3, -0x1p-25f, r2);
  float q4 = rintf(r3 * 0x1p32f);
  p1[idx]=(char)(int)q1; p2[idx]=(char)(int)q2;
  p3[idx]=(char)(int)q3; p4[idx]=(char)(int)q4;
}

// h split from f64: 5 planes at 2^-6,-13,-20,-27,-34 (trunc 2^-35)
DEV void hsplit5(double hd, char* o1, char* o2, char* o3, char* o4, char* o5){
  double q1 = rint(hd * 64.0);
  double r1 = hd - q1 * 0x1p-6;
  double q2 = rint(r1 * 0x1p13);
  double r2 = r1 - q2 * 0x1p-13;
  double q3 = rint(r2 * 0x1p20);
  double r3 = r2 - q3 * 0x1p-20;
  double q4 = rint(r3 * 0x1p27);
  double r4 = r3 - q4 * 0x1p-27;
  double q5 = rint(r4 * 0x1p34);
  *o1=(char)(int)q1; *o2=(char)(int)q2; *o3=(char)(int)q3;
  *o4=(char)(int)q4; *o5=(char)(int)q5;
}

DEV double sigd(double xv){ return 1.0 / (1.0 + exp(-xv)); }

// group scales
__constant__ double SH_[6] = {0x1p-17, 0x1p-24, 0x1p-31, 0x1p-38, 0x1p-45, 0x1p-52};
__constant__ double SX_[6] = {0x1p-13, 0x1p-20, 0x1p-27, 0x1p-34, 0x1p-41, 0x1p-48};

// ---------------- fused persistent 2-layer LSTM (exact-integer GEMM, f64 cell) ----------
__global__ __launch_bounds__(256, 1) void k_lstm_fused(
    const float* __restrict__ x,
    const char* w0p1, const char* w0p2, const char* w0p3, const char* w0p4, const char* w0p5,
    const double* __restrict__ bias0,
    const char* w1p1, const char* w1p2, const char* w1p3, const char* w1p4, const char* w1p5,
    const double* __restrict__ bias1,
    char* h1a, char* h1b, char* h1c, char* h1d, char* h1e,
    char* h2a, char* h2b, char* h2c, char* h2d, char* h2e,
    _Float16* __restrict__ h2h, char* __restrict__ h2l8,
    unsigned int* __restrict__ cnt)
{
  const int wg   = blockIdx.x;
  const int tid  = threadIdx.x;
  const int w    = tid >> 6;
  const int lane = tid & 63;
  const int l15  = lane & 15;
  const int l4   = lane >> 4;
  unsigned int* cntL0 = cnt;        // [4] h1[t] published (32 incs/step/group)
  unsigned int* cntC  = cnt + 4;    // [4] h1[t] consumed
  unsigned int* cntH2 = cnt + 8;    // [4] h2[t] published

  const int isL1 = wg >= 128;
  const int wgl  = isL1 ? wg - 128 : wg;
  const int gi   = wgl >> 5;
  const int j    = wgl & 31;
  const int r0   = w * 16 + l15;
  const int b0   = gi * 32 + l15;
  const int b1   = b0 + 16;
  const int hid  = j * 16 + w * 4 + l4;
  const size_t ringmt0 = (size_t)b0 * 512;
  const size_t ringmt1 = (size_t)b1 * 512;

  char* h1p[5] = {h1a, h1b, h1c, h1d, h1e};
  char* h2p[5] = {h2a, h2b, h2c, h2d, h2e};
  const i32x4 z = {0,0,0,0};

  if (!isL1){
    // ---------- layer 0 ----------
    const char* wp[5] = {w0p1, w0p2, w0p3, w0p4, w0p5};
    i32x4 W[5][9];
    {
      const size_t rowb = ((size_t)j * 64 + r0) * 576;
      #pragma unroll
      for (int p = 0; p < 5; ++p)
        #pragma unroll
        for (int c = 0; c < 9; ++c)
          W[p][c] = *(const i32x4*)(wp[p] + rowb + c * 64 + l4 * 16);
    }
    double bsd[4];
    #pragma unroll
    for (int q = 0; q < 4; ++q) bsd[q] = bias0[j * 64 + w * 16 + l4 * 4 + q];
    double c0 = 0.0, c1 = 0.0;

    for (int t = 0; t < 1024; ++t){
      i32x4 XA[6], XB[6];
      {
        #pragma unroll
        for (int mt = 0; mt < 2; ++mt){
          const float* xr = x + ((size_t)(mt ? b1 : b0) * 1024 + t) * 64 + l4 * 16;
          unsigned int a[6][4] = {{0,0,0,0},{0,0,0,0},{0,0,0,0},{0,0,0,0},{0,0,0,0},{0,0,0,0}};
          #pragma unroll
          for (int i = 0; i < 16; ++i){
            float v = xr[i];
            float q1 = rintf(v * 4.0f);
            float r1 = fmaf(q1, -0.25f, v);
            float q2 = rintf(r1 * 0x1p9f);
            float r2 = fmaf(q2, -0x1p-9f, r1);
            float q3 = rintf(r2 * 0x1p16f);
            float r3 = fmaf(q3, -0x1p-16f, r2);
            float q4 = rintf(r3 * 0x1p23f);
            float r4 = fmaf(q4, -0x1p-23f, r3);
            float q5 = rintf(r4 * 0x1p30f);
            float r5 = fmaf(q5, -0x1p-30f, r4);
            float q6 = rintf(r5 * 0x1p37f);
            int wi = i >> 2, sh = (i & 3) * 8;
            a[0][wi] |= ((unsigned)(unsigned char)(char)(int)q1) << sh;
            a[1][wi] |= ((unsigned)(unsigned char)(char)(int)q2) << sh;
            a[2][wi] |= ((unsigned)(unsigned char)(char)(int)q3) << sh;
            a[3][wi] |= ((unsigned)(unsigned char)(char)(int)q4) << sh;
            a[4][wi] |= ((unsigned)(unsigned char)(char)(int)q5) << sh;
            a[5][wi] |= ((unsigned)(unsigned char)(char)(int)q6) << sh;
          }
          i32x4* X = mt ? XB : XA;
          #pragma unroll
          for (int p = 0; p < 6; ++p)
            X[p] = i32x4{(int)a[p][0], (int)a[p][1], (int)a[p][2], (int)a[p][3]};
        }
      }
      i32x4 Gha[6], Ghb[6], Gxa[6], Gxb[6];
      #pragma unroll
      for (int k = 0; k < 6; ++k){ Gha[k]=z; Ghb[k]=z; Gxa[k]=z; Gxb[k]=z; }
      {
        i32x4 Wc[5];
        #pragma unroll
        for (int p = 0; p < 5; ++p) Wc[p] = W[p][8];
        str_x(Wc, XA, Gxa);
        str_x(Wc, XB, Gxb);
      }

      if (tid == 0){
        if (t >= 8) spin_ge(cntC + gi, 32u * (unsigned)(t - 7));    // 8-slot ring free
        spin_ge(cntL0 + gi, 32u * (unsigned)t);                     // peers' h1[t-1]
        __threadfence();
      }
      __syncthreads();

      if (t > 0){
        const size_t sb = (size_t)((t - 1) & 7) << 16;
        #pragma unroll
        for (int c = 0; c < 8; ++c){
          i32x4 Wc[5], Ba[5], Bb[5];
          #pragma unroll
          for (int p = 0; p < 5; ++p){
            Wc[p] = W[p][c];
            Ba[p] = *(const i32x4*)(h1p[p] + sb + ringmt0 + c * 64 + l4 * 16);
            Bb[p] = *(const i32x4*)(h1p[p] + sb + ringmt1 + c * 64 + l4 * 16);
          }
          str_h(Wc, Ba, Gha);
          str_h(Wc, Bb, Ghb);
        }
      }

      const size_t rb = (size_t)(t & 7) << 16;
      #pragma unroll
      for (int mt = 0; mt < 2; ++mt){
        i32x4* Gh = mt ? Ghb : Gha;
        i32x4* Gx = mt ? Gxb : Gxa;
        double g[4];
        #pragma unroll
        for (int q = 0; q < 4; ++q){
          double s = bsd[q];
          #pragma unroll
          for (int k = 0; k < 6; ++k)
            s += (double)Gh[k][q] * SH_[k] + (double)Gx[k][q] * SX_[k];
          g[q] = s;
        }
        double& cs = mt ? c1 : c0;
        cs = sigd(g[1]) * cs + sigd(g[0]) * tanh(g[2]);
        double hv = sigd(g[3]) * tanh(cs);
        size_t o = rb + (mt ? ringmt1 : ringmt0) + hid;
        char v1c, v2c, v3c, v4c, v5c;
        hsplit5(hv, &v1c, &v2c, &v3c, &v4c, &v5c);
        h1p[0][o]=v1c; h1p[1][o]=v2c; h1p[2][o]=v3c; h1p[3][o]=v4c; h1p[4][o]=v5c;
      }

      __syncthreads();
      if (tid == 0){ __threadfence(); sig_inc(cntL0 + gi); }
    }
  } else {
    // ---------- layer 1 ----------
    const char* wp[5] = {w1p1, w1p2, w1p3, w1p4, w1p5};
    i32x4 W[5][16];
    {
      const size_t rowb = ((size_t)j * 64 + r0) * 1024;
      #pragma unroll
      for (int p = 0; p < 5; ++p)
        #pragma unroll
        for (int c = 0; c < 16; ++c)
          W[p][c] = *(const i32x4*)(wp[p] + rowb + c * 64 + l4 * 16);
    }
    double bsd[4];
    #pragma unroll
    for (int q = 0; q < 4; ++q) bsd[q] = bias1[j * 64 + w * 16 + l4 * 4 + q];
    double c0 = 0.0, c1 = 0.0;

    for (int t = 0; t < 1024; ++t){
      if (tid == 0){ spin_ge(cntL0 + gi, 32u * (unsigned)(t + 1)); __threadfence(); }
      __syncthreads();

      i32x4 Gha[6], Ghb[6];
      #pragma unroll
      for (int k = 0; k < 6; ++k){ Gha[k]=z; Ghb[k]=z; }
      {
        const size_t sb = (size_t)(t & 7) << 16;
        #pragma unroll
        for (int c = 0; c < 8; ++c){
          i32x4 Wc[5], Ba[5], Bb[5];
          #pragma unroll
          for (int p = 0; p < 5; ++p){
            Wc[p] = W[p][c];
            Ba[p] = *(const i32x4*)(h1p[p] + sb + ringmt0 + c * 64 + l4 * 16);
            Bb[p] = *(const i32x4*)(h1p[p] + sb + ringmt1 + c * 64 + l4 * 16);
          }
          str_h(Wc, Ba, Gha);
          str_h(Wc, Bb, Ghb);
        }
      }
      __syncthreads();   // h1 ring reads drained
      if (tid == 0){
        __threadfence();
        sig_inc(cntC + gi);                                         // ring slot consumed
        spin_ge(cntH2 + gi, 32u * (unsigned)t);                     // peers' h2[t-1]
        __threadfence();
      }
      __syncthreads();

      if (t > 0){
        const size_t sb = (size_t)((t - 1) & 3) << 16;
        #pragma unroll
        for (int c = 0; c < 8; ++c){
          i32x4 Wc[5], Ba[5], Bb[5];
          #pragma unroll
          for (int p = 0; p < 5; ++p){
            Wc[p] = W[p][8 + c];
            Ba[p] = *(const i32x4*)(h2p[p] + sb + ringmt0 + c * 64 + l4 * 16);
            Bb[p] = *(const i32x4*)(h2p[p] + sb + ringmt1 + c * 64 + l4 * 16);
          }
          str_h(Wc, Ba, Gha);
          str_h(Wc, Bb, Ghb);
        }
      }

      const size_t rb = (size_t)(t & 3) << 16;
      #pragma unroll
      for (int mt = 0; mt < 2; ++mt){
        i32x4* Gh = mt ? Ghb : Gha;
        double g[4];
        #pragma unroll
        for (int q = 0; q < 4; ++q){
          double s = bsd[q];
          #pragma unroll
          for (int k = 0; k < 6; ++k) s += (double)Gh[k][q] * SH_[k];
          g[q] = s;
        }
        double& cs = mt ? c1 : c0;
        cs = sigd(g[1]) * cs + sigd(g[0]) * tanh(g[2]);
        double hv = sigd(g[3]) * tanh(cs);
        size_t o = rb + (mt ? ringmt1 : ringmt0) + hid;
        char v1c, v2c, v3c, v4c, v5c;
        hsplit5(hv, &v1c, &v2c, &v3c, &v4c, &v5c);
        h2p[0][o]=v1c; h2p[1][o]=v2c; h2p[2][o]=v3c; h2p[3][o]=v4c; h2p[4][o]=v5c;
        // attention-facing: f16 hi + RELATIVE i8 residual (units of ulp(hh)/256)
        float hf = (float)hv;
        _Float16 hh = (_Float16)hf;
        float rs = hf - (float)hh;                    // exact in f32
        union { _Float16 h; unsigned short u; } cb; cb.h = hh;
        int E = (cb.u >> 10) & 31; if (E < 1) E = 1;
        int qr = (int)rintf(ldexpf(rs, 33 - E));
        qr = qr < -127 ? -127 : (qr > 127 ? 127 : qr);
        size_t pb = ((size_t)(mt ? b1 : b0) * 1024 + t) * 512 + hid;
        h2h[pb] = hh;
        h2l8[pb] = (char)qr;
      }

      __syncthreads();
      if (tid == 0){ __threadfence(); sig_inc(cntH2 + gi); }
    }
  }
}

// ---------------- attention energies: exact integer GEMM + f64 epilogue ----------------
// 32 rows/block; h reconstructed exactly in f32, split to 4 i8 planes in LDS;
// W_a 4 i8 planes; 15 scale-grouped i8 MFMA streams; tanh/v_a/sum in f64.
__global__ __launch_bounds__(256) void k_att_e(
    const _Float16* __restrict__ h2, const char* __restrict__ h2l8,
    const char* __restrict__ wa1, const char* __restrict__ wa2,
    const char* __restrict__ wa3, const char* __restrict__ wa4,
    const float* __restrict__ b_a, const float* __restrict__ v_a,
    const float* __restrict__ b_v, double* __restrict__ e)
{
  __shared__ char Ap[4][32][528];
  __shared__ char Wp[2][4][16][528];
  __shared__ double partial[2][32];
  const int tid  = threadIdx.x;
  const int w    = tid >> 6;
  const int mt   = w & 1;
  const int nh   = w >> 1;
  const int lane = tid & 63;
  const int l15  = lane & 15;
  const int l4   = lane >> 4;
  const size_t rid0 = (size_t)blockIdx.x * 32;

  // stage h: reconstruct exact f32 from f16 + rel-i8, split into 4 i8 planes
  for (int i = tid; i < 2048; i += 256){
    int row = i >> 6, c8 = (i & 63) << 3;
    const _Float16* hp = h2 + (rid0 + row) * 512 + c8;
    const char*     rp = h2l8 + (rid0 + row) * 512 + c8;
    unsigned long long o1 = 0, o2 = 0, o3 = 0, o4 = 0;
    #pragma unroll
    for (int q = 0; q < 8; ++q){
      union { _Float16 h; unsigned short u; } cb; cb.h = hp[q];
      int E = (cb.u >> 10) & 31; if (E < 1) E = 1;
      float h = (float)cb.h + ldexpf((float)rp[q], E - 33);
      float q1 = rintf(h * 64.f);     float r1 = fmaf(q1, -0x1p-6f, h);
      float q2 = rintf(r1 * 0x1p13f); float r2 = fmaf(q2, -0x1p-13f, r1);
      float q3 = rintf(r2 * 0x1p20f); float r3 = fmaf(q3, -0x1p-20f, r2);
      float q4 = rintf(r3 * 0x1p27f);
      o1 |= ((unsigned long long)(unsigned char)(char)(int)q1) << (8 * q);
      o2 |= ((unsigned long long)(unsigned char)(char)(int)q2) << (8 * q);
      o3 |= ((unsigned long long)(unsigned char)(char)(int)q3) << (8 * q);
      o4 |= ((unsigned long long)(unsigned char)(char)(int)q4) << (8 * q);
    }
    *(unsigned long long*)&Ap[0][row][c8] = o1;
    *(unsigned long long*)&Ap[1][row][c8] = o2;
    *(unsigned long long*)&Ap[2][row][c8] = o3;
    *(unsigned long long*)&Ap[3][row][c8] = o4;
  }
  __syncthreads();

  const int sh = tid >> 7;         // staging half (0: nh0, 1: nh1)
  const int st = tid & 127;
  double ep0 = 0.0, ep1 = 0.0, ep2 = 0.0, ep3 = 0.0;
  for (int it = 0; it < 16; ++it){
    if (it) __syncthreads();
    {
      int nt = sh * 16 + it;
      for (int i = st; i < 512; i += 128){
        int row = (i >> 5) & 15, c16 = (i & 31) << 4;
        size_t go = (size_t)(nt * 16 + row) * 512 + c16;
        *(i32x4*)&Wp[sh][0][row][c16] = *(const i32x4*)(wa1 + go);
        *(i32x4*)&Wp[sh][1][row][c16] = *(const i32x4*)(wa2 + go);
        *(i32x4*)&Wp[sh][2][row][c16] = *(const i32x4*)(wa3 + go);
        *(i32x4*)&Wp[sh][3][row][c16] = *(const i32x4*)(wa4 + go);
      }
    }
    __syncthreads();
    i32x4 G0={0,0,0,0},G1={0,0,0,0},G2={0,0,0,0},G3={0,0,0,0},G4={0,0,0,0},G5={0,0,0,0};
    #pragma unroll
    for (int c = 0; c < 8; ++c){
      int ko = c * 64 + l4 * 16;
      i32x4 A1 = *(const i32x4*)&Ap[0][mt * 16 + l15][ko];
      i32x4 A2 = *(const i32x4*)&Ap[1][mt * 16 + l15][ko];
      i32x4 A3 = *(const i32x4*)&Ap[2][mt * 16 + l15][ko];
      i32x4 A4 = *(const i32x4*)&Ap[3][mt * 16 + l15][ko];
      i32x4 B1 = *(const i32x4*)&Wp[nh][0][l15][ko];
      i32x4 B2 = *(const i32x4*)&Wp[nh][1][l15][ko];
      i32x4 B3 = *(const i32x4*)&Wp[nh][2][l15][ko];
      i32x4 B4 = *(const i32x4*)&Wp[nh][3][l15][ko];
      G0 = mfma8i(A1, B1, G0);
      G1 = mfma8i(A1, B2, G1); G1 = mfma8i(A2, B1, G1);
      G2 = mfma8i(A1, B3, G2); G2 = mfma8i(A2, B2, G2); G2 = mfma8i(A3, B1, G2);
      G3 = mfma8i(A1, B4, G3); G3 = mfma8i(A2, B3, G3); G3 = mfma8i(A3, B2, G3); G3 = mfma8i(A4, B1, G3);
      G4 = mfma8i(A2, B4, G4); G4 = mfma8i(A3, B3, G4); G4 = mfma8i(A4, B2, G4);
      G5 = mfma8i(A3, B4, G5); G5 = mfma8i(A4, B3, G5);
    }
    int n = (nh * 16 + it) * 16 + l15;
    double ban = (double)b_a[n], van = (double)v_a[n];
    // A plane j scale 2^(1-7j), W plane i scale 2^-(4+7i) -> product 2^-(3+7d) = SH_[d-2]
    #pragma unroll
    for (int q = 0; q < 4; ++q){
      double val = (double)G0[q]*SH_[0] + (double)G1[q]*SH_[1] + (double)G2[q]*SH_[2]
                 + (double)G3[q]*SH_[3] + (double)G4[q]*SH_[4] + (double)G5[q]*SH_[5] + ban;
      double tv = tanh(val) * van;
      if (q == 0) ep0 += tv; else if (q == 1) ep1 += tv;
      else if (q == 2) ep2 += tv; else ep3 += tv;
    }
  }
  #pragma unroll
  for (int m = 1; m < 16; m <<= 1){
    ep0 += __shfl_xor(ep0, m); ep1 += __shfl_xor(ep1, m);
    ep2 += __shfl_xor(ep2, m); ep3 += __shfl_xor(ep3, m);
  }
  if (l15 == 0){
    int rbase = mt * 16 + l4 * 4;
    partial[nh][rbase + 0] = ep0;
    partial[nh][rbase + 1] = ep1;
    partial[nh][rbase + 2] = ep2;
    partial[nh][rbase + 3] = ep3;
  }
  __syncthreads();
  if (tid < 32)
    e[rid0 + tid] = partial[0][tid] + partial[1][tid] + (double)b_v[0];
}

// ---------------- entmax15 (f64) + context + FC ----------------
__global__ __launch_bounds__(256) void k_entmax(
    const double* __restrict__ e, const _Float16* __restrict__ h2,
    const float* __restrict__ fcW, const float* __restrict__ fcb,
    float* __restrict__ out)
{
  __shared__ double xu[1024], sbd[1024], t0d[1024], t1d[1024];
  __shared__ float sbf[1024];
  __shared__ float red4[4];
  __shared__ double redd[4];
  __shared__ double scald;
  const int tid  = threadIdx.x;
  const int b    = blockIdx.x;
  const int wv   = tid >> 6;
  const int lane = tid & 63;

  double lm = -1e300;
  for (int i = tid; i < 1024; i += 256){
    double v = e[b * 1024 + i];
    xu[i] = v;
    lm = fmax(lm, v);
  }
  for (int m = 32; m >= 1; m >>= 1) lm = fmax(lm, __shfl_xor(lm, m));
  if (lane == 0) redd[wv] = lm;
  __syncthreads();
  double rowmax = fmax(fmax(redd[0], redd[1]), fmax(redd[2], redd[3]));
  __syncthreads();
  for (int i = tid; i < 1024; i += 256){
    double v = xu[i] - rowmax;
    xu[i] = v; sbd[i] = v;
  }
  __syncthreads();

  // bitonic ascending sort (f64)
  for (int ksz = 2; ksz <= 1024; ksz <<= 1){
    for (int jj = ksz >> 1; jj > 0; jj >>= 1){
      for (int i = tid; i < 1024; i += 256){
        int ixj = i ^ jj;
        if (ixj > i){
          double a = sbd[i], c = sbd[ixj];
          if (((i & ksz) == 0) ? (a > c) : (a < c)){ sbd[i] = c; sbd[ixj] = a; }
        }
      }
      __syncthreads();
    }
  }

  // descending view; inclusive scan (f64)
  for (int i = tid; i < 1024; i += 256) t0d[i] = sbd[1023 - i];
  __syncthreads();
  double* src = t0d; double* dst = t1d;
  for (int off = 1; off < 1024; off <<= 1){
    for (int i = tid; i < 1024; i += 256)
      dst[i] = src[i] + ((i >= off) ? src[i - off] : 0.0);
    __syncthreads();
    double* tmp = src; src = dst; dst = tmp;
  }

  float lc = 0.f;
  for (int i = tid; i < 1024; i += 256){
    double xs_i = sbd[1023 - i];
    double sup = (double)(i + 1) * xs_i - src[i] + 0.5;
    if (sup > 0.0) lc += 1.f;
  }
  for (int m = 32; m >= 1; m >>= 1) lc += __shfl_xor(lc, m);
  if (lane == 0) red4[wv] = lc;
  __syncthreads();
  if (tid == 0){
    int cntS = (int)(red4[0] + red4[1] + red4[2] + red4[3] + 0.5f);
    int ss = cntS < 1 ? 1 : (cntS > 1023 ? 1023 : cntS);
    double xss = sbd[1023 - ss];
    scald = ((double)(ss + 1) * xss - src[ss] + 0.5) / (double)(ss + 1);
  }
  __syncthreads();
  double tau = scald;

  double ls = 0.0;
  for (int i = tid; i < 1024; i += 256){
    double d = xu[i] - tau;
    double y = (d > 0.0) ? sqrt(d) : 0.0;
    dst[i] = y;
    ls += y;
  }
  for (int m = 32; m >= 1; m >>= 1) ls += __shfl_xor(ls, m);
  if (lane == 0) redd[wv] = ls;
  __syncthreads();
  double Z = redd[0] + redd[1] + redd[2] + redd[3];
  __syncthreads();
  for (int i = tid; i < 1024; i += 256){
    float a = (float)(dst[i] / Z);
    sbf[i] = a;
    out[128 + b * 1024 + i] = a;
  }
  __syncthreads();

  // context over nonzero weights + FC (O=1)
  const int h0 = tid * 2;
  float cx0 = 0.f, cx1 = 0.f;
  for (int s = 0; s < 1024; ++s){
    float wt = sbf[s];
    if (wt > 0.f){
      unsigned int u = *(const unsigned int*)(h2 + ((size_t)b * 1024 + s) * 512 + h0);
      union { unsigned int u; _Float16 h[2]; } cv; cv.u = u;
      cx0 += wt * (float)cv.h[0];
      cx1 += wt * (float)cv.h[1];
    }
  }
  float p = fcW[h0] * cx0 + fcW[h0 + 1] * cx1;
  for (int m = 32; m >= 1; m >>= 1) p += __shfl_xor(p, m);
  if (lane == 0) red4[wv] = p;
  __syncthreads();
  if (tid == 0) out[b] = red4[0] + red4[1] + red4[2] + red4[3] + fcb[0];
}

// ---------------- host launch ----------------
extern "C" void kernel_launch(void* const* d_in, const int* in_sizes, int n_in,
                              void* d_out, int out_size, void* d_ws, size_t ws_size,
                              hipStream_t stream)
{
  (void)in_sizes; (void)n_in; (void)out_size;
  const float* x    = (const float*)d_in[0];
  const float* Wih0 = (const float*)d_in[1];
  const float* Whh0 = (const float*)d_in[2];
  const float* bih0 = (const float*)d_in[3];
  const float* bhh0 = (const float*)d_in[4];
  const float* Wih1 = (const float*)d_in[5];
  const float* Whh1 = (const float*)d_in[6];
  const float* bih1 = (const float*)d_in[7];
  const float* bhh1 = (const float*)d_in[8];
  const float* Wa   = (const float*)d_in[9];
  const float* ba   = (const float*)d_in[10];
  const float* va   = (const float*)d_in[11];
  const float* bv   = (const float*)d_in[12];
  const float* fcW  = (const float*)d_in[13];
  const float* fcb  = (const float*)d_in[14];

  const size_t NEED = 223773696ull;
  if (ws_size < NEED) return;

  char* ws = (char*)d_ws;
  unsigned int* cnt = (unsigned int*)(ws);                  // 1 KiB
  char* w0p[5]; for (int p = 0; p < 5; ++p) w0p[p] = ws + 1024ull + (size_t)p * 1179648ull;
  double* bias0 = (double*)(ws + 5899264ull);               // 16,384
  char* w1p[5]; for (int p = 0; p < 5; ++p) w1p[p] = ws + 5915648ull + (size_t)p * 2097152ull;
  double* bias1 = (double*)(ws + 16401408ull);              // 16,384
  char* wa1 = ws + 16417792ull;                             // 4 x 262,144
  char* wa2 = wa1 + 262144ull;
  char* wa3 = wa2 + 262144ull;
  char* wa4 = wa3 + 262144ull;
  char* h1p[5]; for (int p = 0; p < 5; ++p) h1p[p] = ws + 17466368ull + (size_t)p * 524288ull;  // 8 slots
  char* h2p[5]; for (int p = 0; p < 5; ++p) h2p[p] = ws + 20087808ull + (size_t)p * 262144ull;  // 4 slots
  double* ebuf = (double*)(ws + 21398528ull);               // 1,048,576
  _Float16* h2h = (_Float16*)(ws + 22447104ull);            // 134,217,728
  char* h2l8 = ws + 156664832ull;                           // 67,108,864
  float* out = (float*)d_out;

  k_prep_zero<<<1, 64, 0, stream>>>(cnt);
  k_prep_w0<<<4608, 256, 0, stream>>>(Wih0, Whh0, w0p[0], w0p[1], w0p[2], w0p[3], w0p[4]);
  k_prep_w1<<<8192, 256, 0, stream>>>(Wih1, Whh1, w1p[0], w1p[1], w1p[2], w1p[3], w1p[4]);
  k_prep_b<<<16, 256, 0, stream>>>(bih0, bhh0, bih1, bhh1, bias0, bias1);
  k_prep_wa<<<1024, 256, 0, stream>>>(Wa, wa1, wa2, wa3, wa4);
  k_lstm_fused<<<256, 256, 0, stream>>>(x,
      w0p[0], w0p[1], w0p[2], w0p[3], w0p[4], bias0,
      w1p[0], w1p[1], w1p[2], w1p[3], w1p[4], bias1,
      h1p[0], h1p[1], h1p[2], h1p[3], h1p[4],
      h2p[0], h2p[1], h2p[2], h2p[3], h2p[4],
      h2h, h2l8, cnt);
  k_att_e<<<4096, 256, 0, stream>>>(h2h, h2l8, wa1, wa2, wa3, wa4, ba, va, bv, ebuf);
  k_entmax<<<128, 256, 0, stream>>>(ebuf, h2h, fcW, fcb, out);
}

// Round 12
// 49035.385 us; speedup vs baseline: 1.5678x; 1.5678x over previous
//
#include <hip/hip_runtime.h>

typedef __attribute__((ext_vector_type(8))) _Float16 half8;
typedef __attribute__((ext_vector_type(4))) float f32x4;
typedef __attribute__((ext_vector_type(4))) int   i32x4;

#define DEV static __device__ __forceinline__

DEV i32x4 mfma8i(i32x4 a, i32x4 b, i32x4 c){
  return __builtin_amdgcn_mfma_i32_16x16x64_i8(a, b, c, 0, 0, 0);
}
// RELAXED poll (no per-iteration L2 invalidate) + single ACQUIRE on exit
DEV void spin_ge(unsigned int* p, unsigned int target){
  while (__hip_atomic_load(p, __ATOMIC_RELAXED, __HIP_MEMORY_SCOPE_AGENT) < target)
    __builtin_amdgcn_s_sleep(2);
  (void)__hip_atomic_load(p, __ATOMIC_ACQUIRE, __HIP_MEMORY_SCOPE_AGENT);
}
DEV void sig_inc(unsigned int* p){
  __hip_atomic_fetch_add(p, 1u, __ATOMIC_RELEASE, __HIP_MEMORY_SCOPE_AGENT);
}

// W5 x H5 plane products grouped by scale d=i+j (d=2..7)
DEV void str_h(const i32x4* W, const i32x4* B, i32x4* G){
  G[0]=mfma8i(W[0],B[0],G[0]);
  G[1]=mfma8i(W[0],B[1],G[1]); G[1]=mfma8i(W[1],B[0],G[1]);
  G[2]=mfma8i(W[0],B[2],G[2]); G[2]=mfma8i(W[1],B[1],G[2]); G[2]=mfma8i(W[2],B[0],G[2]);
  G[3]=mfma8i(W[0],B[3],G[3]); G[3]=mfma8i(W[1],B[2],G[3]); G[3]=mfma8i(W[2],B[1],G[3]); G[3]=mfma8i(W[3],B[0],G[3]);
  G[4]=mfma8i(W[0],B[4],G[4]); G[4]=mfma8i(W[1],B[3],G[4]); G[4]=mfma8i(W[2],B[2],G[4]); G[4]=mfma8i(W[3],B[1],G[4]); G[4]=mfma8i(W[4],B[0],G[4]);
  G[5]=mfma8i(W[1],B[4],G[5]); G[5]=mfma8i(W[2],B[3],G[5]); G[5]=mfma8i(W[3],B[2],G[5]); G[5]=mfma8i(W[4],B[1],G[5]);
}
// W5 x X6 plane products grouped by scale (d=2..7)
DEV void str_x(const i32x4* W, const i32x4* X, i32x4* G){
  G[0]=mfma8i(W[0],X[0],G[0]);
  G[1]=mfma8i(W[0],X[1],G[1]); G[1]=mfma8i(W[1],X[0],G[1]);
  G[2]=mfma8i(W[0],X[2],G[2]); G[2]=mfma8i(W[1],X[1],G[2]); G[2]=mfma8i(W[2],X[0],G[2]);
  G[3]=mfma8i(W[0],X[3],G[3]); G[3]=mfma8i(W[1],X[2],G[3]); G[3]=mfma8i(W[2],X[1],G[3]); G[3]=mfma8i(W[3],X[0],G[3]);
  G[4]=mfma8i(W[0],X[4],G[4]); G[4]=mfma8i(W[1],X[3],G[4]); G[4]=mfma8i(W[2],X[2],G[4]); G[4]=mfma8i(W[3],X[1],G[4]); G[4]=mfma8i(W[4],X[0],G[4]);
  G[5]=mfma8i(W[0],X[5],G[5]); G[5]=mfma8i(W[1],X[4],G[5]); G[5]=mfma8i(W[2],X[3],G[5]); G[5]=mfma8i(W[3],X[2],G[5]); G[5]=mfma8i(W[4],X[1],G[5]);
}

// ---------------- prep ----------------
__global__ void k_prep_zero(unsigned int* cnt){
  if (threadIdx.x < 16) cnt[threadIdx.x] = 0u;
}

// W planes: W = p1*2^-11 + ... + p5*2^-39 (trunc 2^-40)
DEV void wsplit5(float v, char* o1, char* o2, char* o3, char* o4, char* o5){
  float q1 = rintf(v * 0x1p11f);
  float r1 = fmaf(q1, -0x1p-11f, v);
  float q2 = rintf(r1 * 0x1p18f);
  float r2 = fmaf(q2, -0x1p-18f, r1);
  float q3 = rintf(r2 * 0x1p25f);
  float r3 = fmaf(q3, -0x1p-25f, r2);
  float q4 = rintf(r3 * 0x1p32f);
  float r4 = fmaf(q4, -0x1p-32f, r3);
  float q5 = rintf(r4 * 0x1p39f);
  *o1=(char)(int)q1; *o2=(char)(int)q2; *o3=(char)(int)q3;
  *o4=(char)(int)q4; *o5=(char)(int)q5;
}

__global__ void k_prep_w0(const float* __restrict__ Wih0, const float* __restrict__ Whh0,
                          char* __restrict__ p1, char* __restrict__ p2, char* __restrict__ p3,
                          char* __restrict__ p4, char* __restrict__ p5){
  int idx = blockIdx.x * 256 + threadIdx.x;      // 1179648
  int k = idx % 576;
  int r = (idx / 576) & 63;
  int j = idx / 36864;
  int R = (r & 3) * 512 + j * 16 + (r >> 2);
  float v = (k < 512) ? Whh0[(size_t)R * 512 + k] : Wih0[(size_t)R * 64 + (k - 512)];
  wsplit5(v, p1 + idx, p2 + idx, p3 + idx, p4 + idx, p5 + idx);
}

__global__ void k_prep_w1(const float* __restrict__ Wih1, const float* __restrict__ Whh1,
                          char* __restrict__ p1, char* __restrict__ p2, char* __restrict__ p3,
                          char* __restrict__ p4, char* __restrict__ p5){
  int idx = blockIdx.x * 256 + threadIdx.x;      // 2097152
  int k = idx & 1023;
  int r = (idx >> 10) & 63;
  int j = idx >> 16;
  int R = (r & 3) * 512 + j * 16 + (r >> 2);
  float v = (k < 512) ? Wih1[(size_t)R * 512 + k] : Whh1[(size_t)R * 512 + (k - 512)];
  wsplit5(v, p1 + idx, p2 + idx, p3 + idx, p4 + idx, p5 + idx);
}

__global__ void k_prep_b(const float* __restrict__ bih0, const float* __restrict__ bhh0,
                         const float* __restrict__ bih1, const float* __restrict__ bhh1,
                         double* __restrict__ bias0, double* __restrict__ bias1){
  int idx = blockIdx.x * 256 + threadIdx.x;      // 4096
  int i2 = idx & 2047;
  int j = i2 >> 6, r = i2 & 63;
  int R = (r & 3) * 512 + j * 16 + (r >> 2);
  if (idx < 2048) bias0[i2] = (double)bih0[R] + (double)bhh0[R];
  else            bias1[i2] = (double)bih1[R] + (double)bhh1[R];
}

// W_a -> 4 i8 planes (2^-11,-18,-25,-32; residual <= 2^-33)
__global__ void k_prep_wa(const float* __restrict__ Wa,
                          char* __restrict__ p1, char* __restrict__ p2,
                          char* __restrict__ p3, char* __restrict__ p4){
  int idx = blockIdx.x * 256 + threadIdx.x;      // 262144
  float v = Wa[idx];
  float q1 = rintf(v * 0x1p11f);
  float r1 = fmaf(q1, -0x1p-11f, v);
  float q2 = rintf(r1 * 0x1p18f);
  float r2 = fmaf(q2, -0x1p-18f, r1);
  float q3 = rintf(r2 * 0x1p25f);
  float r3 = fmaf(q3, -0x1p-25f, r2);
  float q4 = rintf(r3 * 0x1p32f);
  p1[idx]=(char)(int)q1; p2[idx]=(char)(int)q2;
  p3[idx]=(char)(int)q3; p4[idx]=(char)(int)q4;
}

// h split from f64: 5 planes at 2^-6,-13,-20,-27,-34 (trunc 2^-35)
DEV void hsplit5(double hd, char* o1, char* o2, char* o3, char* o4, char* o5){
  double q1 = rint(hd * 64.0);
  double r1 = hd - q1 * 0x1p-6;
  double q2 = rint(r1 * 0x1p13);
  double r2 = r1 - q2 * 0x1p-13;
  double q3 = rint(r2 * 0x1p20);
  double r3 = r2 - q3 * 0x1p-20;
  double q4 = rint(r3 * 0x1p27);
  double r4 = r3 - q4 * 0x1p-27;
  double q5 = rint(r4 * 0x1p34);
  *o1=(char)(int)q1; *o2=(char)(int)q2; *o3=(char)(int)q3;
  *o4=(char)(int)q4; *o5=(char)(int)q5;
}

DEV double sigd(double xv){ return 1.0 / (1.0 + exp(-xv)); }

// group scales
__constant__ double SH_[6] = {0x1p-17, 0x1p-24, 0x1p-31, 0x1p-38, 0x1p-45, 0x1p-52};
__constant__ double SX_[6] = {0x1p-13, 0x1p-20, 0x1p-27, 0x1p-34, 0x1p-41, 0x1p-48};

// ---------------- fused persistent 2-layer LSTM (exact-integer GEMM, f64 cell) ----------
__global__ __launch_bounds__(256, 1) void k_lstm_fused(
    const float* __restrict__ x,
    const char* w0p1, const char* w0p2, const char* w0p3, const char* w0p4, const char* w0p5,
    const double* __restrict__ bias0,
    const char* w1p1, const char* w1p2, const char* w1p3, const char* w1p4, const char* w1p5,
    const double* __restrict__ bias1,
    char* h1a, char* h1b, char* h1c, char* h1d, char* h1e,
    char* h2a, char* h2b, char* h2c, char* h2d, char* h2e,
    _Float16* __restrict__ h2h, char* __restrict__ h2l8,
    unsigned int* __restrict__ cnt)
{
  const int wg   = blockIdx.x;
  const int tid  = threadIdx.x;
  const int w    = tid >> 6;
  const int lane = tid & 63;
  const int l15  = lane & 15;
  const int l4   = lane >> 4;
  unsigned int* cntL0 = cnt;        // [4] h1[t] published (32 incs/step/group)
  unsigned int* cntC  = cnt + 4;    // [4] h1[t] consumed
  unsigned int* cntH2 = cnt + 8;    // [4] h2[t] published

  const int isL1 = wg >= 128;
  const int wgl  = isL1 ? wg - 128 : wg;
  const int gi   = wgl >> 5;
  const int j    = wgl & 31;
  const int r0   = w * 16 + l15;
  const int b0   = gi * 32 + l15;
  const int b1   = b0 + 16;
  const int hid  = j * 16 + w * 4 + l4;
  const size_t ringmt0 = (size_t)b0 * 512;
  const size_t ringmt1 = (size_t)b1 * 512;

  char* h1p[5] = {h1a, h1b, h1c, h1d, h1e};
  char* h2p[5] = {h2a, h2b, h2c, h2d, h2e};
  const i32x4 z = {0,0,0,0};

  if (!isL1){
    // ---------- layer 0 ----------
    const char* wp[5] = {w0p1, w0p2, w0p3, w0p4, w0p5};
    i32x4 W[5][9];
    {
      const size_t rowb = ((size_t)j * 64 + r0) * 576;
      #pragma unroll
      for (int p = 0; p < 5; ++p)
        #pragma unroll
        for (int c = 0; c < 9; ++c)
          W[p][c] = *(const i32x4*)(wp[p] + rowb + c * 64 + l4 * 16);
    }
    double bsd[4];
    #pragma unroll
    for (int q = 0; q < 4; ++q) bsd[q] = bias0[j * 64 + w * 16 + l4 * 4 + q];
    double c0 = 0.0, c1 = 0.0;

    for (int t = 0; t < 1024; ++t){
      i32x4 XA[6], XB[6];
      {
        #pragma unroll
        for (int mt = 0; mt < 2; ++mt){
          const float* xr = x + ((size_t)(mt ? b1 : b0) * 1024 + t) * 64 + l4 * 16;
          unsigned int a[6][4] = {{0,0,0,0},{0,0,0,0},{0,0,0,0},{0,0,0,0},{0,0,0,0},{0,0,0,0}};
          #pragma unroll
          for (int i = 0; i < 16; ++i){
            float v = xr[i];
            float q1 = rintf(v * 4.0f);
            float r1 = fmaf(q1, -0.25f, v);
            float q2 = rintf(r1 * 0x1p9f);
            float r2 = fmaf(q2, -0x1p-9f, r1);
            float q3 = rintf(r2 * 0x1p16f);
            float r3 = fmaf(q3, -0x1p-16f, r2);
            float q4 = rintf(r3 * 0x1p23f);
            float r4 = fmaf(q4, -0x1p-23f, r3);
            float q5 = rintf(r4 * 0x1p30f);
            float r5 = fmaf(q5, -0x1p-30f, r4);
            float q6 = rintf(r5 * 0x1p37f);
            int wi = i >> 2, sh = (i & 3) * 8;
            a[0][wi] |= ((unsigned)(unsigned char)(char)(int)q1) << sh;
            a[1][wi] |= ((unsigned)(unsigned char)(char)(int)q2) << sh;
            a[2][wi] |= ((unsigned)(unsigned char)(char)(int)q3) << sh;
            a[3][wi] |= ((unsigned)(unsigned char)(char)(int)q4) << sh;
            a[4][wi] |= ((unsigned)(unsigned char)(char)(int)q5) << sh;
            a[5][wi] |= ((unsigned)(unsigned char)(char)(int)q6) << sh;
          }
          i32x4* X = mt ? XB : XA;
          #pragma unroll
          for (int p = 0; p < 6; ++p)
            X[p] = i32x4{(int)a[p][0], (int)a[p][1], (int)a[p][2], (int)a[p][3]};
        }
      }
      i32x4 Gha[6], Ghb[6], Gxa[6], Gxb[6];
      #pragma unroll
      for (int k = 0; k < 6; ++k){ Gha[k]=z; Ghb[k]=z; Gxa[k]=z; Gxb[k]=z; }
      {
        i32x4 Wc[5];
        #pragma unroll
        for (int p = 0; p < 5; ++p) Wc[p] = W[p][8];
        str_x(Wc, XA, Gxa);
        str_x(Wc, XB, Gxb);
      }

      if (tid == 0){
        if (t >= 8) spin_ge(cntC + gi, 32u * (unsigned)(t - 7));    // 8-slot ring free
        spin_ge(cntL0 + gi, 32u * (unsigned)t);                     // peers' h1[t-1]
      }
      __syncthreads();

      if (t > 0){
        const size_t sb = (size_t)((t - 1) & 7) << 16;
        #pragma unroll
        for (int c = 0; c < 8; ++c){
          i32x4 Wc[5], Ba[5], Bb[5];
          #pragma unroll
          for (int p = 0; p < 5; ++p){
            Wc[p] = W[p][c];
            Ba[p] = *(const i32x4*)(h1p[p] + sb + ringmt0 + c * 64 + l4 * 16);
            Bb[p] = *(const i32x4*)(h1p[p] + sb + ringmt1 + c * 64 + l4 * 16);
          }
          str_h(Wc, Ba, Gha);
          str_h(Wc, Bb, Ghb);
        }
      }

      const size_t rb = (size_t)(t & 7) << 16;
      #pragma unroll
      for (int mt = 0; mt < 2; ++mt){
        i32x4* Gh = mt ? Ghb : Gha;
        i32x4* Gx = mt ? Gxb : Gxa;
        double g[4];
        #pragma unroll
        for (int q = 0; q < 4; ++q){
          double s = bsd[q];
          #pragma unroll
          for (int k = 0; k < 6; ++k)
            s += (double)Gh[k][q] * SH_[k] + (double)Gx[k][q] * SX_[k];
          g[q] = s;
        }
        double& cs = mt ? c1 : c0;
        cs = sigd(g[1]) * cs + sigd(g[0]) * tanh(g[2]);
        double hv = sigd(g[3]) * tanh(cs);
        size_t o = rb + (mt ? ringmt1 : ringmt0) + hid;
        char v1c, v2c, v3c, v4c, v5c;
        hsplit5(hv, &v1c, &v2c, &v3c, &v4c, &v5c);
        h1p[0][o]=v1c; h1p[1][o]=v2c; h1p[2][o]=v3c; h1p[3][o]=v4c; h1p[4][o]=v5c;
      }

      __syncthreads();
      if (tid == 0) sig_inc(cntL0 + gi);
    }
  } else {
    // ---------- layer 1 ----------
    const char* wp[5] = {w1p1, w1p2, w1p3, w1p4, w1p5};
    i32x4 W[5][16];
    {
      const size_t rowb = ((size_t)j * 64 + r0) * 1024;
      #pragma unroll
      for (int p = 0; p < 5; ++p)
        #pragma unroll
        for (int c = 0; c < 16; ++c)
          W[p][c] = *(const i32x4*)(wp[p] + rowb + c * 64 + l4 * 16);
    }
    double bsd[4];
    #pragma unroll
    for (int q = 0; q < 4; ++q) bsd[q] = bias1[j * 64 + w * 16 + l4 * 4 + q];
    double c0 = 0.0, c1 = 0.0;

    for (int t = 0; t < 1024; ++t){
      if (tid == 0) spin_ge(cntL0 + gi, 32u * (unsigned)(t + 1));   // h1[t] ready
      __syncthreads();

      i32x4 Gha[6], Ghb[6];
      #pragma unroll
      for (int k = 0; k < 6; ++k){ Gha[k]=z; Ghb[k]=z; }
      {
        const size_t sb = (size_t)(t & 7) << 16;
        #pragma unroll
        for (int c = 0; c < 8; ++c){
          i32x4 Wc[5], Ba[5], Bb[5];
          #pragma unroll
          for (int p = 0; p < 5; ++p){
            Wc[p] = W[p][c];
            Ba[p] = *(const i32x4*)(h1p[p] + sb + ringmt0 + c * 64 + l4 * 16);
            Bb[p] = *(const i32x4*)(h1p[p] + sb + ringmt1 + c * 64 + l4 * 16);
          }
          str_h(Wc, Ba, Gha);
          str_h(Wc, Bb, Ghb);
        }
      }
      __syncthreads();   // h1 ring reads drained
      if (tid == 0){
        sig_inc(cntC + gi);                                         // ring slot consumed
        spin_ge(cntH2 + gi, 32u * (unsigned)t);                     // peers' h2[t-1]
      }
      __syncthreads();

      if (t > 0){
        const size_t sb = (size_t)((t - 1) & 3) << 16;
        #pragma unroll
        for (int c = 0; c < 8; ++c){
          i32x4 Wc[5], Ba[5], Bb[5];
          #pragma unroll
          for (int p = 0; p < 5; ++p){
            Wc[p] = W[p][8 + c];
            Ba[p] = *(const i32x4*)(h2p[p] + sb + ringmt0 + c * 64 + l4 * 16);
            Bb[p] = *(const i32x4*)(h2p[p] + sb + ringmt1 + c * 64 + l4 * 16);
          }
          str_h(Wc, Ba, Gha);
          str_h(Wc, Bb, Ghb);
        }
      }

      const size_t rb = (size_t)(t & 3) << 16;
      #pragma unroll
      for (int mt = 0; mt < 2; ++mt){
        i32x4* Gh = mt ? Ghb : Gha;
        double g[4];
        #pragma unroll
        for (int q = 0; q < 4; ++q){
          double s = bsd[q];
          #pragma unroll
          for (int k = 0; k < 6; ++k) s += (double)Gh[k][q] * SH_[k];
          g[q] = s;
        }
        double& cs = mt ? c1 : c0;
        cs = sigd(g[1]) * cs + sigd(g[0]) * tanh(g[2]);
        double hv = sigd(g[3]) * tanh(cs);
        size_t o = rb + (mt ? ringmt1 : ringmt0) + hid;
        char v1c, v2c, v3c, v4c, v5c;
        hsplit5(hv, &v1c, &v2c, &v3c, &v4c, &v5c);
        h2p[0][o]=v1c; h2p[1][o]=v2c; h2p[2][o]=v3c; h2p[3][o]=v4c; h2p[4][o]=v5c;
        // attention-facing: f16 hi + RELATIVE i8 residual (units of ulp(hh)/256)
        float hf = (float)hv;
        _Float16 hh = (_Float16)hf;
        float rs = hf - (float)hh;                    // exact in f32
        union { _Float16 h; unsigned short u; } cb; cb.h = hh;
        int E = (cb.u >> 10) & 31; if (E < 1) E = 1;
        int qr = (int)rintf(ldexpf(rs, 33 - E));
        qr = qr < -127 ? -127 : (qr > 127 ? 127 : qr);
        size_t pb = ((size_t)(mt ? b1 : b0) * 1024 + t) * 512 + hid;
        h2h[pb] = hh;
        h2l8[pb] = (char)qr;
      }

      __syncthreads();
      if (tid == 0) sig_inc(cntH2 + gi);
    }
  }
}

// ---------------- attention energies: exact integer GEMM + f64 epilogue ----------------
__global__ __launch_bounds__(256) void k_att_e(
    const _Float16* __restrict__ h2, const char* __restrict__ h2l8,
    const char* __restrict__ wa1, const char* __restrict__ wa2,
    const char* __restrict__ wa3, const char* __restrict__ wa4,
    const float* __restrict__ b_a, const float* __restrict__ v_a,
    const float* __restrict__ b_v, double* __restrict__ e)
{
  __shared__ char Ap[4][32][528];
  __shared__ char Wp[2][4][16][528];
  __shared__ double partial[2][32];
  const int tid  = threadIdx.x;
  const int w    = tid >> 6;
  const int mt   = w & 1;
  const int nh   = w >> 1;
  const int lane = tid & 63;
  const int l15  = lane & 15;
  const int l4   = lane >> 4;
  const size_t rid0 = (size_t)blockIdx.x * 32;

  // stage h: reconstruct exact f32 from f16 + rel-i8, split into 4 i8 planes
  for (int i = tid; i < 2048; i += 256){
    int row = i >> 6, c8 = (i & 63) << 3;
    const _Float16* hp = h2 + (rid0 + row) * 512 + c8;
    const char*     rp = h2l8 + (rid0 + row) * 512 + c8;
    unsigned long long o1 = 0, o2 = 0, o3 = 0, o4 = 0;
    #pragma unroll
    for (int q = 0; q < 8; ++q){
      union { _Float16 h; unsigned short u; } cb; cb.h = hp[q];
      int E = (cb.u >> 10) & 31; if (E < 1) E = 1;
      float h = (float)cb.h + ldexpf((float)rp[q], E - 33);
      float q1 = rintf(h * 64.f);     float r1 = fmaf(q1, -0x1p-6f, h);
      float q2 = rintf(r1 * 0x1p13f); float r2 = fmaf(q2, -0x1p-13f, r1);
      float q3 = rintf(r2 * 0x1p20f); float r3 = fmaf(q3, -0x1p-20f, r2);
      float q4 = rintf(r3 * 0x1p27f);
      o1 |= ((unsigned long long)(unsigned char)(char)(int)q1) << (8 * q);
      o2 |= ((unsigned long long)(unsigned char)(char)(int)q2) << (8 * q);
      o3 |= ((unsigned long long)(unsigned char)(char)(int)q3) << (8 * q);
      o4 |= ((unsigned long long)(unsigned char)(char)(int)q4) << (8 * q);
    }
    *(unsigned long long*)&Ap[0][row][c8] = o1;
    *(unsigned long long*)&Ap[1][row][c8] = o2;
    *(unsigned long long*)&Ap[2][row][c8] = o3;
    *(unsigned long long*)&Ap[3][row][c8] = o4;
  }
  __syncthreads();

  const int sh = tid >> 7;         // staging half (0: nh0, 1: nh1)
  const int st = tid & 127;
  double ep0 = 0.0, ep1 = 0.0, ep2 = 0.0, ep3 = 0.0;
  for (int it = 0; it < 16; ++it){
    if (it) __syncthreads();
    {
      int nt = sh * 16 + it;
      for (int i = st; i < 512; i += 128){
        int row = (i >> 5) & 15, c16 = (i & 31) << 4;
        size_t go = (size_t)(nt * 16 + row) * 512 + c16;
        *(i32x4*)&Wp[sh][0][row][c16] = *(const i32x4*)(wa1 + go);
        *(i32x4*)&Wp[sh][1][row][c16] = *(const i32x4*)(wa2 + go);
        *(i32x4*)&Wp[sh][2][row][c16] = *(const i32x4*)(wa3 + go);
        *(i32x4*)&Wp[sh][3][row][c16] = *(const i32x4*)(wa4 + go);
      }
    }
    __syncthreads();
    i32x4 G0={0,0,0,0},G1={0,0,0,0},G2={0,0,0,0},G3={0,0,0,0},G4={0,0,0,0},G5={0,0,0,0};
    #pragma unroll
    for (int c = 0; c < 8; ++c){
      int ko = c * 64 + l4 * 16;
      i32x4 A1 = *(const i32x4*)&Ap[0][mt * 16 + l15][ko];
      i32x4 A2 = *(const i32x4*)&Ap[1][mt * 16 + l15][ko];
      i32x4 A3 = *(const i32x4*)&Ap[2][mt * 16 + l15][ko];
      i32x4 A4 = *(const i32x4*)&Ap[3][mt * 16 + l15][ko];
      i32x4 B1 = *(const i32x4*)&Wp[nh][0][l15][ko];
      i32x4 B2 = *(const i32x4*)&Wp[nh][1][l15][ko];
      i32x4 B3 = *(const i32x4*)&Wp[nh][2][l15][ko];
      i32x4 B4 = *(const i32x4*)&Wp[nh][3][l15][ko];
      G0 = mfma8i(A1, B1, G0);
      G1 = mfma8i(A1, B2, G1); G1 = mfma8i(A2, B1, G1);
      G2 = mfma8i(A1, B3, G2); G2 = mfma8i(A2, B2, G2); G2 = mfma8i(A3, B1, G2);
      G3 = mfma8i(A1, B4, G3); G3 = mfma8i(A2, B3, G3); G3 = mfma8i(A3, B2, G3); G3 = mfma8i(A4, B1, G3);
      G4 = mfma8i(A2, B4, G4); G4 = mfma8i(A3, B3, G4); G4 = mfma8i(A4, B2, G4);
      G5 = mfma8i(A3, B4, G5); G5 = mfma8i(A4, B3, G5);
    }
    int n = (nh * 16 + it) * 16 + l15;
    double ban = (double)b_a[n], van = (double)v_a[n];
    #pragma unroll
    for (int q = 0; q < 4; ++q){
      double val = (double)G0[q]*SH_[0] + (double)G1[q]*SH_[1] + (double)G2[q]*SH_[2]
                 + (double)G3[q]*SH_[3] + (double)G4[q]*SH_[4] + (double)G5[q]*SH_[5] + ban;
      double tv = tanh(val) * van;
      if (q == 0) ep0 += tv; else if (q == 1) ep1 += tv;
      else if (q == 2) ep2 += tv; else ep3 += tv;
    }
  }
  #pragma unroll
  for (int m = 1; m < 16; m <<= 1){
    ep0 += __shfl_xor(ep0, m); ep1 += __shfl_xor(ep1, m);
    ep2 += __shfl_xor(ep2, m); ep3 += __shfl_xor(ep3, m);
  }
  if (l15 == 0){
    int rbase = mt * 16 + l4 * 4;
    partial[nh][rbase + 0] = ep0;
    partial[nh][rbase + 1] = ep1;
    partial[nh][rbase + 2] = ep2;
    partial[nh][rbase + 3] = ep3;
  }
  __syncthreads();
  if (tid < 32)
    e[rid0 + tid] = partial[0][tid] + partial[1][tid] + (double)b_v[0];
}

// ---------------- entmax15 (f64) + context + FC ----------------
__global__ __launch_bounds__(256) void k_entmax(
    const double* __restrict__ e, const _Float16* __restrict__ h2,
    const float* __restrict__ fcW, const float* __restrict__ fcb,
    float* __restrict__ out)
{
  __shared__ double xu[1024], sbd[1024], t0d[1024], t1d[1024];
  __shared__ float sbf[1024];
  __shared__ float red4[4];
  __shared__ double redd[4];
  __shared__ double scald;
  const int tid  = threadIdx.x;
  const int b    = blockIdx.x;
  const int wv   = tid >> 6;
  const int lane = tid & 63;

  double lm = -1e300;
  for (int i = tid; i < 1024; i += 256){
    double v = e[b * 1024 + i];
    xu[i] = v;
    lm = fmax(lm, v);
  }
  for (int m = 32; m >= 1; m >>= 1) lm = fmax(lm, __shfl_xor(lm, m));
  if (lane == 0) redd[wv] = lm;
  __syncthreads();
  double rowmax = fmax(fmax(redd[0], redd[1]), fmax(redd[2], redd[3]));
  __syncthreads();
  for (int i = tid; i < 1024; i += 256){
    double v = xu[i] - rowmax;
    xu[i] = v; sbd[i] = v;
  }
  __syncthreads();

  // bitonic ascending sort (f64)
  for (int ksz = 2; ksz <= 1024; ksz <<= 1){
    for (int jj = ksz >> 1; jj > 0; jj >>= 1){
      for (int i = tid; i < 1024; i += 256){
        int ixj = i ^ jj;
        if (ixj > i){
          double a = sbd[i], c = sbd[ixj];
          if (((i & ksz) == 0) ? (a > c) : (a < c)){ sbd[i] = c; sbd[ixj] = a; }
        }
      }
      __syncthreads();
    }
  }

  // descending view; inclusive scan (f64)
  for (int i = tid; i < 1024; i += 256) t0d[i] = sbd[1023 - i];
  __syncthreads();
  double* src = t0d; double* dst = t1d;
  for (int off = 1; off < 1024; off <<= 1){
    for (int i = tid; i < 1024; i += 256)
      dst[i] = src[i] + ((i >= off) ? src[i - off] : 0.0);
    __syncthreads();
    double* tmp = src; src = dst; dst = tmp;
  }

  float lc = 0.f;
  for (int i = tid; i < 1024; i += 256){
    double xs_i = sbd[1023 - i];
    double sup = (double)(i + 1) * xs_i - src[i] + 0.5;
    if (sup > 0.0) lc += 1.f;
  }
  for (int m = 32; m >= 1; m >>= 1) lc += __shfl_xor(lc, m);
  if (lane == 0) red4[wv] = lc;
  __syncthreads();
  if (tid == 0){
    int cntS = (int)(red4[0] + red4[1] + red4[2] + red4[3] + 0.5f);
    int ss = cntS < 1 ? 1 : (cntS > 1023 ? 1023 : cntS);
    double xss = sbd[1023 - ss];
    scald = ((double)(ss + 1) * xss - src[ss] + 0.5) / (double)(ss + 1);
  }
  __syncthreads();
  double tau = scald;

  double ls = 0.0;
  for (int i = tid; i < 1024; i += 256){
    double d = xu[i] - tau;
    double y = (d > 0.0) ? sqrt(d) : 0.0;
    dst[i] = y;
    ls += y;
  }
  for (int m = 32; m >= 1; m >>= 1) ls += __shfl_xor(ls, m);
  if (lane == 0) redd[wv] = ls;
  __syncthreads();
  double Z = redd[0] + redd[1] + redd[2] + redd[3];
  __syncthreads();
  for (int i = tid; i < 1024; i += 256){
    float a = (float)(dst[i] / Z);
    sbf[i] = a;
    out[128 + b * 1024 + i] = a;
  }
  __syncthreads();

  // context over nonzero weights + FC (O=1)
  const int h0 = tid * 2;
  float cx0 = 0.f, cx1 = 0.f;
  for (int s = 0; s < 1024; ++s){
    float wt = sbf[s];
    if (wt > 0.f){
      unsigned int u = *(const unsigned int*)(h2 + ((size_t)b * 1024 + s) * 512 + h0);
      union { unsigned int u; _Float16 h[2]; } cv; cv.u = u;
      cx0 += wt * (float)cv.h[0];
      cx1 += wt * (float)cv.h[1];
    }
  }
  float p = fcW[h0] * cx0 + fcW[h0 + 1] * cx1;
  for (int m = 32; m >= 1; m >>= 1) p += __shfl_xor(p, m);
  if (lane == 0) red4[wv] = p;
  __syncthreads();
  if (tid == 0) out[b] = red4[0] + red4[1] + red4[2] + red4[3] + fcb[0];
}

// ---------------- host launch ----------------
extern "C" void kernel_launch(void* const* d_in, const int* in_sizes, int n_in,
                              void* d_out, int out_size, void* d_ws, size_t ws_size,
                              hipStream_t stream)
{
  (void)in_sizes; (void)n_in; (void)out_size;
  const float* x    = (const float*)d_in[0];
  const float* Wih0 = (const float*)d_in[1];
  const float* Whh0 = (const float*)d_in[2];
  const float* bih0 = (const float*)d_in[3];
  const float* bhh0 = (const float*)d_in[4];
  const float* Wih1 = (const float*)d_in[5];
  const float* Whh1 = (const float*)d_in[6];
  const float* bih1 = (const float*)d_in[7];
  const float* bhh1 = (const float*)d_in[8];
  const float* Wa   = (const float*)d_in[9];
  const float* ba   = (const float*)d_in[10];
  const float* va   = (const float*)d_in[11];
  const float* bv   = (const float*)d_in[12];
  const float* fcW  = (const float*)d_in[13];
  const float* fcb  = (const float*)d_in[14];

  const size_t NEED = 223773696ull;
  if (ws_size < NEED) return;

  char* ws = (char*)d_ws;
  unsigned int* cnt = (unsigned int*)(ws);                  // 1 KiB
  char* w0p[5]; for (int p = 0; p < 5; ++p) w0p[p] = ws + 1024ull + (size_t)p * 1179648ull;
  double* bias0 = (double*)(ws + 5899264ull);               // 16,384
  char* w1p[5]; for (int p = 0; p < 5; ++p) w1p[p] = ws + 5915648ull + (size_t)p * 2097152ull;
  double* bias1 = (double*)(ws + 16401408ull);              // 16,384
  char* wa1 = ws + 16417792ull;                             // 4 x 262,144
  char* wa2 = wa1 + 262144ull;
  char* wa3 = wa2 + 262144ull;
  char* wa4 = wa3 + 262144ull;
  char* h1p[5]; for (int p = 0; p < 5; ++p) h1p[p] = ws + 17466368ull + (size_t)p * 524288ull;  // 8 slots
  char* h2p[5]; for (int p = 0; p < 5; ++p) h2p[p] = ws + 20087808ull + (size_t)p * 262144ull;  // 4 slots
  double* ebuf = (double*)(ws + 21398528ull);               // 1,048,576
  _Float16* h2h = (_Float16*)(ws + 22447104ull);            // 134,217,728
  char* h2l8 = ws + 156664832ull;                           // 67,108,864
  float* out = (float*)d_out;

  k_prep_zero<<<1, 64, 0, stream>>>(cnt);
  k_prep_w0<<<4608, 256, 0, stream>>>(Wih0, Whh0, w0p[0], w0p[1], w0p[2], w0p[3], w0p[4]);
  k_prep_w1<<<8192, 256, 0, stream>>>(Wih1, Whh1, w1p[0], w1p[1], w1p[2], w1p[3], w1p[4]);
  k_prep_b<<<16, 256, 0, stream>>>(bih0, bhh0, bih1, bhh1, bias0, bias1);
  k_prep_wa<<<1024, 256, 0, stream>>>(Wa, wa1, wa2, wa3, wa4);
  k_lstm_fused<<<256, 256, 0, stream>>>(x,
      w0p[0], w0p[1], w0p[2], w0p[3], w0p[4], bias0,
      w1p[0], w1p[1], w1p[2], w1p[3], w1p[4], bias1,
      h1p[0], h1p[1], h1p[2], h1p[3], h1p[4],
      h2p[0], h2p[1], h2p[2], h2p[3], h2p[4],
      h2h, h2l8, cnt);
  k_att_e<<<4096, 256, 0, stream>>>(h2h, h2l8, wa1, wa2, wa3, wa4, ba, va, bv, ebuf);
  k_entmax<<<128, 256, 0, stream>>>(ebuf, h2h, fcW, fcb, out);
}

// Round 13
// 48990.112 us; speedup vs baseline: 1.5692x; 1.0009x over previous
//
#include <hip/hip_runtime.h>

typedef __attribute__((ext_vector_type(8))) _Float16 half8;
typedef __attribute__((ext_vector_type(4))) float f32x4;
typedef __attribute__((ext_vector_type(4))) int   i32x4;

#define DEV static __device__ __forceinline__

DEV i32x4 mfma8i(i32x4 a, i32x4 b, i32x4 c){
  return __builtin_amdgcn_mfma_i32_16x16x64_i8(a, b, c, 0, 0, 0);
}
DEV void flag_pub(unsigned int* p, unsigned int v){
  __hip_atomic_store(p, v, __ATOMIC_RELEASE, __HIP_MEMORY_SCOPE_AGENT);
}
DEV i32x4 ntl(const void* p){ return __builtin_nontemporal_load((const i32x4*)p); }

// W5 x H5 plane products grouped by scale d=i+j (d=2..7)
DEV void str_h(const i32x4* W, const i32x4* B, i32x4* G){
  G[0]=mfma8i(W[0],B[0],G[0]);
  G[1]=mfma8i(W[0],B[1],G[1]); G[1]=mfma8i(W[1],B[0],G[1]);
  G[2]=mfma8i(W[0],B[2],G[2]); G[2]=mfma8i(W[1],B[1],G[2]); G[2]=mfma8i(W[2],B[0],G[2]);
  G[3]=mfma8i(W[0],B[3],G[3]); G[3]=mfma8i(W[1],B[2],G[3]); G[3]=mfma8i(W[2],B[1],G[3]); G[3]=mfma8i(W[3],B[0],G[3]);
  G[4]=mfma8i(W[0],B[4],G[4]); G[4]=mfma8i(W[1],B[3],G[4]); G[4]=mfma8i(W[2],B[2],G[4]); G[4]=mfma8i(W[3],B[1],G[4]); G[4]=mfma8i(W[4],B[0],G[4]);
  G[5]=mfma8i(W[1],B[4],G[5]); G[5]=mfma8i(W[2],B[3],G[5]); G[5]=mfma8i(W[3],B[2],G[5]); G[5]=mfma8i(W[4],B[1],G[5]);
}
// W5 x X6 plane products grouped by scale (d=2..7)
DEV void str_x(const i32x4* W, const i32x4* X, i32x4* G){
  G[0]=mfma8i(W[0],X[0],G[0]);
  G[1]=mfma8i(W[0],X[1],G[1]); G[1]=mfma8i(W[1],X[0],G[1]);
  G[2]=mfma8i(W[0],X[2],G[2]); G[2]=mfma8i(W[1],X[1],G[2]); G[2]=mfma8i(W[2],X[0],G[2]);
  G[3]=mfma8i(W[0],X[3],G[3]); G[3]=mfma8i(W[1],X[2],G[3]); G[3]=mfma8i(W[2],X[1],G[3]); G[3]=mfma8i(W[3],X[0],G[3]);
  G[4]=mfma8i(W[0],X[4],G[4]); G[4]=mfma8i(W[1],X[3],G[4]); G[4]=mfma8i(W[2],X[2],G[4]); G[4]=mfma8i(W[3],X[1],G[4]); G[4]=mfma8i(W[4],X[0],G[4]);
  G[5]=mfma8i(W[0],X[5],G[5]); G[5]=mfma8i(W[1],X[4],G[5]); G[5]=mfma8i(W[2],X[3],G[5]); G[5]=mfma8i(W[3],X[2],G[5]); G[5]=mfma8i(W[4],X[1],G[5]);
}

// ---------------- prep ----------------
__global__ void k_prep_zero(unsigned int* cnt){
  cnt[threadIdx.x] = 0u;    // 256 flags
}

// W planes: W = p1*2^-11 + ... + p5*2^-39 (trunc 2^-40)
DEV void wsplit5(float v, char* o1, char* o2, char* o3, char* o4, char* o5){
  float q1 = rintf(v * 0x1p11f);
  float r1 = fmaf(q1, -0x1p-11f, v);
  float q2 = rintf(r1 * 0x1p18f);
  float r2 = fmaf(q2, -0x1p-18f, r1);
  float q3 = rintf(r2 * 0x1p25f);
  float r3 = fmaf(q3, -0x1p-25f, r2);
  float q4 = rintf(r3 * 0x1p32f);
  float r4 = fmaf(q4, -0x1p-32f, r3);
  float q5 = rintf(r4 * 0x1p39f);
  *o1=(char)(int)q1; *o2=(char)(int)q2; *o3=(char)(int)q3;
  *o4=(char)(int)q4; *o5=(char)(int)q5;
}

__global__ void k_prep_w0(const float* __restrict__ Wih0, const float* __restrict__ Whh0,
                          char* __restrict__ p1, char* __restrict__ p2, char* __restrict__ p3,
                          char* __restrict__ p4, char* __restrict__ p5){
  int idx = blockIdx.x * 256 + threadIdx.x;      // 1179648
  int k = idx % 576;
  int r = (idx / 576) & 63;
  int j = idx / 36864;
  int R = (r & 3) * 512 + j * 16 + (r >> 2);
  float v = (k < 512) ? Whh0[(size_t)R * 512 + k] : Wih0[(size_t)R * 64 + (k - 512)];
  wsplit5(v, p1 + idx, p2 + idx, p3 + idx, p4 + idx, p5 + idx);
}

__global__ void k_prep_w1(const float* __restrict__ Wih1, const float* __restrict__ Whh1,
                          char* __restrict__ p1, char* __restrict__ p2, char* __restrict__ p3,
                          char* __restrict__ p4, char* __restrict__ p5){
  int idx = blockIdx.x * 256 + threadIdx.x;      // 2097152
  int k = idx & 1023;
  int r = (idx >> 10) & 63;
  int j = idx >> 16;
  int R = (r & 3) * 512 + j * 16 + (r >> 2);
  float v = (k < 512) ? Wih1[(size_t)R * 512 + k] : Whh1[(size_t)R * 512 + (k - 512)];
  wsplit5(v, p1 + idx, p2 + idx, p3 + idx, p4 + idx, p5 + idx);
}

__global__ void k_prep_b(const float* __restrict__ bih0, const float* __restrict__ bhh0,
                         const float* __restrict__ bih1, const float* __restrict__ bhh1,
                         double* __restrict__ bias0, double* __restrict__ bias1){
  int idx = blockIdx.x * 256 + threadIdx.x;      // 4096
  int i2 = idx & 2047;
  int j = i2 >> 6, r = i2 & 63;
  int R = (r & 3) * 512 + j * 16 + (r >> 2);
  if (idx < 2048) bias0[i2] = (double)bih0[R] + (double)bhh0[R];
  else            bias1[i2] = (double)bih1[R] + (double)bhh1[R];
}

// W_a -> 4 i8 planes (2^-11,-18,-25,-32; residual <= 2^-33)
__global__ void k_prep_wa(const float* __restrict__ Wa,
                          char* __restrict__ p1, char* __restrict__ p2,
                          char* __restrict__ p3, char* __restrict__ p4){
  int idx = blockIdx.x * 256 + threadIdx.x;      // 262144
  float v = Wa[idx];
  float q1 = rintf(v * 0x1p11f);
  float r1 = fmaf(q1, -0x1p-11f, v);
  float q2 = rintf(r1 * 0x1p18f);
  float r2 = fmaf(q2, -0x1p-18f, r1);
  float q3 = rintf(r2 * 0x1p25f);
  float r3 = fmaf(q3, -0x1p-25f, r2);
  float q4 = rintf(r3 * 0x1p32f);
  p1[idx]=(char)(int)q1; p2[idx]=(char)(int)q2;
  p3[idx]=(char)(int)q3; p4[idx]=(char)(int)q4;
}

// h split from f64: 5 planes at 2^-6,-13,-20,-27,-34 (trunc 2^-35)
DEV void hsplit5(double hd, char* o1, char* o2, char* o3, char* o4, char* o5){
  double q1 = rint(hd * 64.0);
  double r1 = hd - q1 * 0x1p-6;
  double q2 = rint(r1 * 0x1p13);
  double r2 = r1 - q2 * 0x1p-13;
  double q3 = rint(r2 * 0x1p20);
  double r3 = r2 - q3 * 0x1p-20;
  double q4 = rint(r3 * 0x1p27);
  double r4 = r3 - q4 * 0x1p-27;
  double q5 = rint(r4 * 0x1p34);
  *o1=(char)(int)q1; *o2=(char)(int)q2; *o3=(char)(int)q3;
  *o4=(char)(int)q4; *o5=(char)(int)q5;
}

DEV double sigd(double xv){ return 1.0 / (1.0 + exp(-xv)); }

// group scales
__constant__ double SH_[6] = {0x1p-17, 0x1p-24, 0x1p-31, 0x1p-38, 0x1p-45, 0x1p-52};
__constant__ double SX_[6] = {0x1p-13, 0x1p-20, 0x1p-27, 0x1p-34, 0x1p-41, 0x1p-48};

// ---------------- fused persistent 2-layer LSTM (exact-integer GEMM, f64 cell) ----------
// Flags: pflagL0[128] (L0 WG published h1[t] -> t+1), pflagH2[128] (L1 WG finished step t -> t+1).
// L1 finishing step t implies it consumed h1[t] (ring backpressure) and published h2[t].
__global__ __launch_bounds__(256, 1) void k_lstm_fused(
    const float* __restrict__ x,
    const char* w0p1, const char* w0p2, const char* w0p3, const char* w0p4, const char* w0p5,
    const double* __restrict__ bias0,
    const char* w1p1, const char* w1p2, const char* w1p3, const char* w1p4, const char* w1p5,
    const double* __restrict__ bias1,
    char* h1a, char* h1b, char* h1c, char* h1d, char* h1e,
    char* h2a, char* h2b, char* h2c, char* h2d, char* h2e,
    _Float16* __restrict__ h2h, char* __restrict__ h2l8,
    unsigned int* __restrict__ cnt)
{
  const int wg   = blockIdx.x;
  const int tid  = threadIdx.x;
  const int w    = tid >> 6;
  const int lane = tid & 63;
  const int l15  = lane & 15;
  const int l4   = lane >> 4;
  unsigned int* pflagL0 = cnt;          // [128]
  unsigned int* pflagH2 = cnt + 128;    // [128]

  const int isL1 = wg >= 128;
  const int wgl  = isL1 ? wg - 128 : wg;
  const int gi   = wgl >> 5;
  const int j    = wgl & 31;
  const int r0   = w * 16 + l15;
  const int b0   = gi * 32 + l15;
  const int b1   = b0 + 16;
  const int hid  = j * 16 + w * 4 + l4;
  const size_t ringmt0 = (size_t)b0 * 512;
  const size_t ringmt1 = (size_t)b1 * 512;

  char* h1p[5] = {h1a, h1b, h1c, h1d, h1e};
  char* h2p[5] = {h2a, h2b, h2c, h2d, h2e};
  const i32x4 z = {0,0,0,0};

  if (!isL1){
    // ---------- layer 0 ----------
    const char* wp[5] = {w0p1, w0p2, w0p3, w0p4, w0p5};
    i32x4 W[5][9];
    {
      const size_t rowb = ((size_t)j * 64 + r0) * 576;
      #pragma unroll
      for (int p = 0; p < 5; ++p)
        #pragma unroll
        for (int c = 0; c < 9; ++c)
          W[p][c] = *(const i32x4*)(wp[p] + rowb + c * 64 + l4 * 16);
    }
    double bsd[4];
    #pragma unroll
    for (int q = 0; q < 4; ++q) bsd[q] = bias0[j * 64 + w * 16 + l4 * 4 + q];
    double c0 = 0.0, c1 = 0.0;
    unsigned int* myflag  = pflagL0 + gi * 32 + ((lane < 32) ? lane : 0);
    unsigned int* bpflag  = pflagH2 + gi * 32 + ((lane >= 32) ? (lane - 32) : 0);

    for (int t = 0; t < 1024; ++t){
      i32x4 XA[6], XB[6];
      {
        #pragma unroll
        for (int mt = 0; mt < 2; ++mt){
          const float* xr = x + ((size_t)(mt ? b1 : b0) * 1024 + t) * 64 + l4 * 16;
          unsigned int a[6][4] = {{0,0,0,0},{0,0,0,0},{0,0,0,0},{0,0,0,0},{0,0,0,0},{0,0,0,0}};
          #pragma unroll
          for (int i = 0; i < 16; ++i){
            float v = xr[i];
            float q1 = rintf(v * 4.0f);
            float r1 = fmaf(q1, -0.25f, v);
            float q2 = rintf(r1 * 0x1p9f);
            float r2 = fmaf(q2, -0x1p-9f, r1);
            float q3 = rintf(r2 * 0x1p16f);
            float r3 = fmaf(q3, -0x1p-16f, r2);
            float q4 = rintf(r3 * 0x1p23f);
            float r4 = fmaf(q4, -0x1p-23f, r3);
            float q5 = rintf(r4 * 0x1p30f);
            float r5 = fmaf(q5, -0x1p-30f, r4);
            float q6 = rintf(r5 * 0x1p37f);
            int wi = i >> 2, sh = (i & 3) * 8;
            a[0][wi] |= ((unsigned)(unsigned char)(char)(int)q1) << sh;
            a[1][wi] |= ((unsigned)(unsigned char)(char)(int)q2) << sh;
            a[2][wi] |= ((unsigned)(unsigned char)(char)(int)q3) << sh;
            a[3][wi] |= ((unsigned)(unsigned char)(char)(int)q4) << sh;
            a[4][wi] |= ((unsigned)(unsigned char)(char)(int)q5) << sh;
            a[5][wi] |= ((unsigned)(unsigned char)(char)(int)q6) << sh;
          }
          i32x4* X = mt ? XB : XA;
          #pragma unroll
          for (int p = 0; p < 6; ++p)
            X[p] = i32x4{(int)a[p][0], (int)a[p][1], (int)a[p][2], (int)a[p][3]};
        }
      }
      i32x4 Gha[6], Ghb[6], Gxa[6], Gxb[6];
      #pragma unroll
      for (int k = 0; k < 6; ++k){ Gha[k]=z; Ghb[k]=z; Gxa[k]=z; Gxb[k]=z; }
      {
        i32x4 Wc[5];
        #pragma unroll
        for (int p = 0; p < 5; ++p) Wc[p] = W[p][8];
        str_x(Wc, XA, Gxa);
        str_x(Wc, XB, Gxb);
      }

      // wave-parallel poll: lanes<32 peers' h1[t-1]; lanes>=32 L1 backpressure (>= t-7)
      if (tid < 64){
        unsigned int* fp = (lane < 32) ? myflag : bpflag;
        unsigned int tgt = (lane < 32) ? (unsigned)t
                          : ((t >= 8) ? (unsigned)(t - 7) : 0u);
        for (;;){
          unsigned int v = __hip_atomic_load(fp, __ATOMIC_RELAXED, __HIP_MEMORY_SCOPE_AGENT);
          if (__all(v >= tgt)) break;
          __builtin_amdgcn_s_sleep(1);
        }
        if (lane == 0)
          (void)__hip_atomic_load(fp, __ATOMIC_ACQUIRE, __HIP_MEMORY_SCOPE_AGENT);
      }
      __syncthreads();

      if (t > 0){
        const size_t sb = (size_t)((t - 1) & 7) << 16;
        #pragma unroll
        for (int c = 0; c < 8; ++c){
          i32x4 Wc[5], Ba[5], Bb[5];
          #pragma unroll
          for (int p = 0; p < 5; ++p){
            Wc[p] = W[p][c];
            Ba[p] = ntl(h1p[p] + sb + ringmt0 + c * 64 + l4 * 16);
            Bb[p] = ntl(h1p[p] + sb + ringmt1 + c * 64 + l4 * 16);
          }
          str_h(Wc, Ba, Gha);
          str_h(Wc, Bb, Ghb);
        }
      }

      const size_t rb = (size_t)(t & 7) << 16;
      #pragma unroll
      for (int mt = 0; mt < 2; ++mt){
        i32x4* Gh = mt ? Ghb : Gha;
        i32x4* Gx = mt ? Gxb : Gxa;
        double g[4];
        #pragma unroll
        for (int q = 0; q < 4; ++q){
          double s = bsd[q];
          #pragma unroll
          for (int k = 0; k < 6; ++k)
            s += (double)Gh[k][q] * SH_[k] + (double)Gx[k][q] * SX_[k];
          g[q] = s;
        }
        double& cs = mt ? c1 : c0;
        cs = sigd(g[1]) * cs + sigd(g[0]) * tanh(g[2]);
        double hv = sigd(g[3]) * tanh(cs);
        size_t o = rb + (mt ? ringmt1 : ringmt0) + hid;
        char v1c, v2c, v3c, v4c, v5c;
        hsplit5(hv, &v1c, &v2c, &v3c, &v4c, &v5c);
        __builtin_nontemporal_store(v1c, h1p[0] + o);
        __builtin_nontemporal_store(v2c, h1p[1] + o);
        __builtin_nontemporal_store(v3c, h1p[2] + o);
        __builtin_nontemporal_store(v4c, h1p[3] + o);
        __builtin_nontemporal_store(v5c, h1p[4] + o);
      }

      __syncthreads();
      if (tid == 0) flag_pub(pflagL0 + wgl, (unsigned)(t + 1));
    }
  } else {
    // ---------- layer 1 ----------
    const char* wp[5] = {w1p1, w1p2, w1p3, w1p4, w1p5};
    i32x4 W[5][16];
    {
      const size_t rowb = ((size_t)j * 64 + r0) * 1024;
      #pragma unroll
      for (int p = 0; p < 5; ++p)
        #pragma unroll
        for (int c = 0; c < 16; ++c)
          W[p][c] = *(const i32x4*)(wp[p] + rowb + c * 64 + l4 * 16);
    }
    double bsd[4];
    #pragma unroll
    for (int q = 0; q < 4; ++q) bsd[q] = bias1[j * 64 + w * 16 + l4 * 4 + q];
    double c0 = 0.0, c1 = 0.0;
    unsigned int* srcflag = pflagL0 + gi * 32 + ((lane < 32) ? lane : 0);
    unsigned int* peerflag = pflagH2 + gi * 32 + ((lane >= 32) ? (lane - 32) : 0);

    for (int t = 0; t < 1024; ++t){
      // merged poll: lanes<32 h1[t] ready; lanes>=32 peers' h2[t-1]
      if (tid < 64){
        unsigned int* fp = (lane < 32) ? srcflag : peerflag;
        unsigned int tgt = (lane < 32) ? (unsigned)(t + 1)
                          : ((t > 0) ? (unsigned)t : 0u);
        for (;;){
          unsigned int v = __hip_atomic_load(fp, __ATOMIC_RELAXED, __HIP_MEMORY_SCOPE_AGENT);
          if (__all(v >= tgt)) break;
          __builtin_amdgcn_s_sleep(1);
        }
        if (lane == 0)
          (void)__hip_atomic_load(fp, __ATOMIC_ACQUIRE, __HIP_MEMORY_SCOPE_AGENT);
      }
      __syncthreads();

      i32x4 Gha[6], Ghb[6];
      #pragma unroll
      for (int k = 0; k < 6; ++k){ Gha[k]=z; Ghb[k]=z; }
      {
        const size_t sb = (size_t)(t & 7) << 16;
        #pragma unroll
        for (int c = 0; c < 8; ++c){
          i32x4 Wc[5], Ba[5], Bb[5];
          #pragma unroll
          for (int p = 0; p < 5; ++p){
            Wc[p] = W[p][c];
            Ba[p] = ntl(h1p[p] + sb + ringmt0 + c * 64 + l4 * 16);
            Bb[p] = ntl(h1p[p] + sb + ringmt1 + c * 64 + l4 * 16);
          }
          str_h(Wc, Ba, Gha);
          str_h(Wc, Bb, Ghb);
        }
      }
      if (t > 0){
        const size_t sb = (size_t)((t - 1) & 3) << 16;
        #pragma unroll
        for (int c = 0; c < 8; ++c){
          i32x4 Wc[5], Ba[5], Bb[5];
          #pragma unroll
          for (int p = 0; p < 5; ++p){
            Wc[p] = W[p][8 + c];
            Ba[p] = ntl(h2p[p] + sb + ringmt0 + c * 64 + l4 * 16);
            Bb[p] = ntl(h2p[p] + sb + ringmt1 + c * 64 + l4 * 16);
          }
          str_h(Wc, Ba, Gha);
          str_h(Wc, Bb, Ghb);
        }
      }

      const size_t rb = (size_t)(t & 3) << 16;
      #pragma unroll
      for (int mt = 0; mt < 2; ++mt){
        i32x4* Gh = mt ? Ghb : Gha;
        double g[4];
        #pragma unroll
        for (int q = 0; q < 4; ++q){
          double s = bsd[q];
          #pragma unroll
          for (int k = 0; k < 6; ++k) s += (double)Gh[k][q] * SH_[k];
          g[q] = s;
        }
        double& cs = mt ? c1 : c0;
        cs = sigd(g[1]) * cs + sigd(g[0]) * tanh(g[2]);
        double hv = sigd(g[3]) * tanh(cs);
        size_t o = rb + (mt ? ringmt1 : ringmt0) + hid;
        char v1c, v2c, v3c, v4c, v5c;
        hsplit5(hv, &v1c, &v2c, &v3c, &v4c, &v5c);
        __builtin_nontemporal_store(v1c, h2p[0] + o);
        __builtin_nontemporal_store(v2c, h2p[1] + o);
        __builtin_nontemporal_store(v3c, h2p[2] + o);
        __builtin_nontemporal_store(v4c, h2p[3] + o);
        __builtin_nontemporal_store(v5c, h2p[4] + o);
        // attention-facing: f16 hi + RELATIVE i8 residual (units of ulp(hh)/256)
        float hf = (float)hv;
        _Float16 hh = (_Float16)hf;
        float rs = hf - (float)hh;                    // exact in f32
        union { _Float16 h; unsigned short u; } cb; cb.h = hh;
        int E = (cb.u >> 10) & 31; if (E < 1) E = 1;
        int qr = (int)rintf(ldexpf(rs, 33 - E));
        qr = qr < -127 ? -127 : (qr > 127 ? 127 : qr);
        size_t pb = ((size_t)(mt ? b1 : b0) * 1024 + t) * 512 + hid;
        __builtin_nontemporal_store(hh, h2h + pb);
        __builtin_nontemporal_store((char)qr, h2l8 + pb);
      }

      __syncthreads();
      // one release store: step t complete (h1[t] consumed AND h2[t] published)
      if (tid == 0) flag_pub(pflagH2 + wgl, (unsigned)(t + 1));
    }
  }
}

// ---------------- attention energies: exact integer GEMM + f64 epilogue ----------------
__global__ __launch_bounds__(256) void k_att_e(
    const _Float16* __restrict__ h2, const char* __restrict__ h2l8,
    const char* __restrict__ wa1, const char* __restrict__ wa2,
    const char* __restrict__ wa3, const char* __restrict__ wa4,
    const float* __restrict__ b_a, const float* __restrict__ v_a,
    const float* __restrict__ b_v, double* __restrict__ e)
{
  __shared__ char Ap[4][32][528];
  __shared__ char Wp[2][4][16][528];
  __shared__ double partial[2][32];
  const int tid  = threadIdx.x;
  const int w    = tid >> 6;
  const int mt   = w & 1;
  const int nh   = w >> 1;
  const int lane = tid & 63;
  const int l15  = lane & 15;
  const int l4   = lane >> 4;
  const size_t rid0 = (size_t)blockIdx.x * 32;

  // stage h: reconstruct exact f32 from f16 + rel-i8, split into 4 i8 planes
  for (int i = tid; i < 2048; i += 256){
    int row = i >> 6, c8 = (i & 63) << 3;
    const _Float16* hp = h2 + (rid0 + row) * 512 + c8;
    const char*     rp = h2l8 + (rid0 + row) * 512 + c8;
    unsigned long long o1 = 0, o2 = 0, o3 = 0, o4 = 0;
    #pragma unroll
    for (int q = 0; q < 8; ++q){
      union { _Float16 h; unsigned short u; } cb; cb.h = hp[q];
      int E = (cb.u >> 10) & 31; if (E < 1) E = 1;
      float h = (float)cb.h + ldexpf((float)rp[q], E - 33);
      float q1 = rintf(h * 64.f);     float r1 = fmaf(q1, -0x1p-6f, h);
      float q2 = rintf(r1 * 0x1p13f); float r2 = fmaf(q2, -0x1p-13f, r1);
      float q3 = rintf(r2 * 0x1p20f); float r3 = fmaf(q3, -0x1p-20f, r2);
      float q4 = rintf(r3 * 0x1p27f);
      o1 |= ((unsigned long long)(unsigned char)(char)(int)q1) << (8 * q);
      o2 |= ((unsigned long long)(unsigned char)(char)(int)q2) << (8 * q);
      o3 |= ((unsigned long long)(unsigned char)(char)(int)q3) << (8 * q);
      o4 |= ((unsigned long long)(unsigned char)(char)(int)q4) << (8 * q);
    }
    *(unsigned long long*)&Ap[0][row][c8] = o1;
    *(unsigned long long*)&Ap[1][row][c8] = o2;
    *(unsigned long long*)&Ap[2][row][c8] = o3;
    *(unsigned long long*)&Ap[3][row][c8] = o4;
  }
  __syncthreads();

  const int sh = tid >> 7;         // staging half (0: nh0, 1: nh1)
  const int st = tid & 127;
  double ep0 = 0.0, ep1 = 0.0, ep2 = 0.0, ep3 = 0.0;
  for (int it = 0; it < 16; ++it){
    if (it) __syncthreads();
    {
      int nt = sh * 16 + it;
      for (int i = st; i < 512; i += 128){
        int row = (i >> 5) & 15, c16 = (i & 31) << 4;
        size_t go = (size_t)(nt * 16 + row) * 512 + c16;
        *(i32x4*)&Wp[sh][0][row][c16] = *(const i32x4*)(wa1 + go);
        *(i32x4*)&Wp[sh][1][row][c16] = *(const i32x4*)(wa2 + go);
        *(i32x4*)&Wp[sh][2][row][c16] = *(const i32x4*)(wa3 + go);
        *(i32x4*)&Wp[sh][3][row][c16] = *(const i32x4*)(wa4 + go);
      }
    }
    __syncthreads();
    i32x4 G0={0,0,0,0},G1={0,0,0,0},G2={0,0,0,0},G3={0,0,0,0},G4={0,0,0,0},G5={0,0,0,0};
    #pragma unroll
    for (int c = 0; c < 8; ++c){
      int ko = c * 64 + l4 * 16;
      i32x4 A1 = *(const i32x4*)&Ap[0][mt * 16 + l15][ko];
      i32x4 A2 = *(const i32x4*)&Ap[1][mt * 16 + l15][ko];
      i32x4 A3 = *(const i32x4*)&Ap[2][mt * 16 + l15][ko];
      i32x4 A4 = *(const i32x4*)&Ap[3][mt * 16 + l15][ko];
      i32x4 B1 = *(const i32x4*)&Wp[nh][0][l15][ko];
      i32x4 B2 = *(const i32x4*)&Wp[nh][1][l15][ko];
      i32x4 B3 = *(const i32x4*)&Wp[nh][2][l15][ko];
      i32x4 B4 = *(const i32x4*)&Wp[nh][3][l15][ko];
      G0 = mfma8i(A1, B1, G0);
      G1 = mfma8i(A1, B2, G1); G1 = mfma8i(A2, B1, G1);
      G2 = mfma8i(A1, B3, G2); G2 = mfma8i(A2, B2, G2); G2 = mfma8i(A3, B1, G2);
      G3 = mfma8i(A1, B4, G3); G3 = mfma8i(A2, B3, G3); G3 = mfma8i(A3, B2, G3); G3 = mfma8i(A4, B1, G3);
      G4 = mfma8i(A2, B4, G4); G4 = mfma8i(A3, B3, G4); G4 = mfma8i(A4, B2, G4);
      G5 = mfma8i(A3, B4, G5); G5 = mfma8i(A4, B3, G5);
    }
    int n = (nh * 16 + it) * 16 + l15;
    double ban = (double)b_a[n], van = (double)v_a[n];
    #pragma unroll
    for (int q = 0; q < 4; ++q){
      double val = (double)G0[q]*SH_[0] + (double)G1[q]*SH_[1] + (double)G2[q]*SH_[2]
                 + (double)G3[q]*SH_[3] + (double)G4[q]*SH_[4] + (double)G5[q]*SH_[5] + ban;
      double tv = tanh(val) * van;
      if (q == 0) ep0 += tv; else if (q == 1) ep1 += tv;
      else if (q == 2) ep2 += tv; else ep3 += tv;
    }
  }
  #pragma unroll
  for (int m = 1; m < 16; m <<= 1){
    ep0 += __shfl_xor(ep0, m); ep1 += __shfl_xor(ep1, m);
    ep2 += __shfl_xor(ep2, m); ep3 += __shfl_xor(ep3, m);
  }
  if (l15 == 0){
    int rbase = mt * 16 + l4 * 4;
    partial[nh][rbase + 0] = ep0;
    partial[nh][rbase + 1] = ep1;
    partial[nh][rbase + 2] = ep2;
    partial[nh][rbase + 3] = ep3;
  }
  __syncthreads();
  if (tid < 32)
    e[rid0 + tid] = partial[0][tid] + partial[1][tid] + (double)b_v[0];
}

// ---------------- entmax15 (f64) + context + FC ----------------
__global__ __launch_bounds__(256) void k_entmax(
    const double* __restrict__ e, const _Float16* __restrict__ h2,
    const float* __restrict__ fcW, const float* __restrict__ fcb,
    float* __restrict__ out)
{
  __shared__ double xu[1024], sbd[1024], t0d[1024], t1d[1024];
  __shared__ float sbf[1024];
  __shared__ float red4[4];
  __shared__ double redd[4];
  __shared__ double scald;
  const int tid  = threadIdx.x;
  const int b    = blockIdx.x;
  const int wv   = tid >> 6;
  const int lane = tid & 63;

  double lm = -1e300;
  for (int i = tid; i < 1024; i += 256){
    double v = e[b * 1024 + i];
    xu[i] = v;
    lm = fmax(lm, v);
  }
  for (int m = 32; m >= 1; m >>= 1) lm = fmax(lm, __shfl_xor(lm, m));
  if (lane == 0) redd[wv] = lm;
  __syncthreads();
  double rowmax = fmax(fmax(redd[0], redd[1]), fmax(redd[2], redd[3]));
  __syncthreads();
  for (int i = tid; i < 1024; i += 256){
    double v = xu[i] - rowmax;
    xu[i] = v; sbd[i] = v;
  }
  __syncthreads();

  // bitonic ascending sort (f64)
  for (int ksz = 2; ksz <= 1024; ksz <<= 1){
    for (int jj = ksz >> 1; jj > 0; jj >>= 1){
      for (int i = tid; i < 1024; i += 256){
        int ixj = i ^ jj;
        if (ixj > i){
          double a = sbd[i], c = sbd[ixj];
          if (((i & ksz) == 0) ? (a > c) : (a < c)){ sbd[i] = c; sbd[ixj] = a; }
        }
      }
      __syncthreads();
    }
  }

  // descending view; inclusive scan (f64)
  for (int i = tid; i < 1024; i += 256) t0d[i] = sbd[1023 - i];
  __syncthreads();
  double* src = t0d; double* dst = t1d;
  for (int off = 1; off < 1024; off <<= 1){
    for (int i = tid; i < 1024; i += 256)
      dst[i] = src[i] + ((i >= off) ? src[i - off] : 0.0);
    __syncthreads();
    double* tmp = src; src = dst; dst = tmp;
  }

  float lc = 0.f;
  for (int i = tid; i < 1024; i += 256){
    double xs_i = sbd[1023 - i];
    double sup = (double)(i + 1) * xs_i - src[i] + 0.5;
    if (sup > 0.0) lc += 1.f;
  }
  for (int m = 32; m >= 1; m >>= 1) lc += __shfl_xor(lc, m);
  if (lane == 0) red4[wv] = lc;
  __syncthreads();
  if (tid == 0){
    int cntS = (int)(red4[0] + red4[1] + red4[2] + red4[3] + 0.5f);
    int ss = cntS < 1 ? 1 : (cntS > 1023 ? 1023 : cntS);
    double xss = sbd[1023 - ss];
    scald = ((double)(ss + 1) * xss - src[ss] + 0.5) / (double)(ss + 1);
  }
  __syncthreads();
  double tau = scald;

  double ls = 0.0;
  for (int i = tid; i < 1024; i += 256){
    double d = xu[i] - tau;
    double y = (d > 0.0) ? sqrt(d) : 0.0;
    dst[i] = y;
    ls += y;
  }
  for (int m = 32; m >= 1; m >>= 1) ls += __shfl_xor(ls, m);
  if (lane == 0) redd[wv] = ls;
  __syncthreads();
  double Z = redd[0] + redd[1] + redd[2] + redd[3];
  __syncthreads();
  for (int i = tid; i < 1024; i += 256){
    float a = (float)(dst[i] / Z);
    sbf[i] = a;
    out[128 + b * 1024 + i] = a;
  }
  __syncthreads();

  // context over nonzero weights + FC (O=1)
  const int h0 = tid * 2;
  float cx0 = 0.f, cx1 = 0.f;
  for (int s = 0; s < 1024; ++s){
    float wt = sbf[s];
    if (wt > 0.f){
      unsigned int u = *(const unsigned int*)(h2 + ((size_t)b * 1024 + s) * 512 + h0);
      union { unsigned int u; _Float16 h[2]; } cv; cv.u = u;
      cx0 += wt * (float)cv.h[0];
      cx1 += wt * (float)cv.h[1];
    }
  }
  float p = fcW[h0] * cx0 + fcW[h0 + 1] * cx1;
  for (int m = 32; m >= 1; m >>= 1) p += __shfl_xor(p, m);
  if (lane == 0) red4[wv] = p;
  __syncthreads();
  if (tid == 0) out[b] = red4[0] + red4[1] + red4[2] + red4[3] + fcb[0];
}

// ---------------- host launch ----------------
extern "C" void kernel_launch(void* const* d_in, const int* in_sizes, int n_in,
                              void* d_out, int out_size, void* d_ws, size_t ws_size,
                              hipStream_t stream)
{
  (void)in_sizes; (void)n_in; (void)out_size;
  const float* x    = (const float*)d_in[0];
  const float* Wih0 = (const float*)d_in[1];
  const float* Whh0 = (const float*)d_in[2];
  const float* bih0 = (const float*)d_in[3];
  const float* bhh0 = (const float*)d_in[4];
  const float* Wih1 = (const float*)d_in[5];
  const float* Whh1 = (const float*)d_in[6];
  const float* bih1 = (const float*)d_in[7];
  const float* bhh1 = (const float*)d_in[8];
  const float* Wa   = (const float*)d_in[9];
  const float* ba   = (const float*)d_in[10];
  const float* va   = (const float*)d_in[11];
  const float* bv   = (const float*)d_in[12];
  const float* fcW  = (const float*)d_in[13];
  const float* fcb  = (const float*)d_in[14];

  const size_t NEED = 223773696ull;
  if (ws_size < NEED) return;

  char* ws = (char*)d_ws;
  unsigned int* cnt = (unsigned int*)(ws);                  // 1 KiB (256 flags)
  char* w0p[5]; for (int p = 0; p < 5; ++p) w0p[p] = ws + 1024ull + (size_t)p * 1179648ull;
  double* bias0 = (double*)(ws + 5899264ull);               // 16,384
  char* w1p[5]; for (int p = 0; p < 5; ++p) w1p[p] = ws + 5915648ull + (size_t)p * 2097152ull;
  double* bias1 = (double*)(ws + 16401408ull);              // 16,384
  char* wa1 = ws + 16417792ull;                             // 4 x 262,144
  char* wa2 = wa1 + 262144ull;
  char* wa3 = wa2 + 262144ull;
  char* wa4 = wa3 + 262144ull;
  char* h1p[5]; for (int p = 0; p < 5; ++p) h1p[p] = ws + 17466368ull + (size_t)p * 524288ull;  // 8 slots
  char* h2p[5]; for (int p = 0; p < 5; ++p) h2p[p] = ws + 20087808ull + (size_t)p * 262144ull;  // 4 slots
  double* ebuf = (double*)(ws + 21398528ull);               // 1,048,576
  _Float16* h2h = (_Float16*)(ws + 22447104ull);            // 134,217,728
  char* h2l8 = ws + 156664832ull;                           // 67,108,864
  float* out = (float*)d_out;

  k_prep_zero<<<1, 256, 0, stream>>>(cnt);
  k_prep_w0<<<4608, 256, 0, stream>>>(Wih0, Whh0, w0p[0], w0p[1], w0p[2], w0p[3], w0p[4]);
  k_prep_w1<<<8192, 256, 0, stream>>>(Wih1, Whh1, w1p[0], w1p[1], w1p[2], w1p[3], w1p[4]);
  k_prep_b<<<16, 256, 0, stream>>>(bih0, bhh0, bih1, bhh1, bias0, bias1);
  k_prep_wa<<<1024, 256, 0, stream>>>(Wa, wa1, wa2, wa3, wa4);
  k_lstm_fused<<<256, 256, 0, stream>>>(x,
      w0p[0], w0p[1], w0p[2], w0p[3], w0p[4], bias0,
      w1p[0], w1p[1], w1p[2], w1p[3], w1p[4], bias1,
      h1p[0], h1p[1], h1p[2], h1p[3], h1p[4],
      h2p[0], h2p[1], h2p[2], h2p[3], h2p[4],
      h2h, h2l8, cnt);
  k_att_e<<<4096, 256, 0, stream>>>(h2h, h2l8, wa1, wa2, wa3, wa4, ba, va, bv, ebuf);
  k_entmax<<<128, 256, 0, stream>>>(ebuf, h2h, fcW, fcb, out);
}

// Round 14
// 26475.308 us; speedup vs baseline: 2.9037x; 1.8504x over previous
//
#include <hip/hip_runtime.h>

typedef __attribute__((ext_vector_type(8))) _Float16 half8;
typedef __attribute__((ext_vector_type(4))) float f32x4;
typedef __attribute__((ext_vector_type(4))) int   i32x4;

#define DEV static __device__ __forceinline__

DEV i32x4 mfma8i(i32x4 a, i32x4 b, i32x4 c){
  return __builtin_amdgcn_mfma_i32_16x16x64_i8(a, b, c, 0, 0, 0);
}
// MALL-bypass primitives (sc0 sc1 = system-coherent: skip L1+L2)
DEV void ld4(i32x4& d, const char* p){
  asm volatile("global_load_dwordx4 %0, %1, off sc0 sc1" : "=v"(d) : "v"(p));
}
DEV void st1(char* p, int v){
  asm volatile("global_store_byte %0, %1, off sc0 sc1" :: "v"(p), "v"(v) : "memory");
}
DEV void st_flag(unsigned int* p, unsigned int v){
  asm volatile("s_waitcnt vmcnt(0)" ::: "memory");
  asm volatile("global_store_dword %0, %1, off sc0 sc1" :: "v"(p), "v"(v) : "memory");
}
DEV void drain_vm(){ asm volatile("s_waitcnt vmcnt(0)" ::: "memory"); }
DEV void poll_ge(unsigned int* fp, unsigned int tgt){
  for (;;){
    unsigned int v = __hip_atomic_load(fp, __ATOMIC_RELAXED, __HIP_MEMORY_SCOPE_AGENT);
    if (__all(v >= tgt)) break;
    __builtin_amdgcn_s_sleep(1);
  }
}

// W5 x H5 plane products grouped by scale d=i+j (d=2..7)
DEV void str_h(const i32x4* W, const i32x4* B, i32x4* G){
  G[0]=mfma8i(W[0],B[0],G[0]);
  G[1]=mfma8i(W[0],B[1],G[1]); G[1]=mfma8i(W[1],B[0],G[1]);
  G[2]=mfma8i(W[0],B[2],G[2]); G[2]=mfma8i(W[1],B[1],G[2]); G[2]=mfma8i(W[2],B[0],G[2]);
  G[3]=mfma8i(W[0],B[3],G[3]); G[3]=mfma8i(W[1],B[2],G[3]); G[3]=mfma8i(W[2],B[1],G[3]); G[3]=mfma8i(W[3],B[0],G[3]);
  G[4]=mfma8i(W[0],B[4],G[4]); G[4]=mfma8i(W[1],B[3],G[4]); G[4]=mfma8i(W[2],B[2],G[4]); G[4]=mfma8i(W[3],B[1],G[4]); G[4]=mfma8i(W[4],B[0],G[4]);
  G[5]=mfma8i(W[1],B[4],G[5]); G[5]=mfma8i(W[2],B[3],G[5]); G[5]=mfma8i(W[3],B[2],G[5]); G[5]=mfma8i(W[4],B[1],G[5]);
}
// W5 x X6 plane products grouped by scale (d=2..7)
DEV void str_x(const i32x4* W, const i32x4* X, i32x4* G){
  G[0]=mfma8i(W[0],X[0],G[0]);
  G[1]=mfma8i(W[0],X[1],G[1]); G[1]=mfma8i(W[1],X[0],G[1]);
  G[2]=mfma8i(W[0],X[2],G[2]); G[2]=mfma8i(W[1],X[1],G[2]); G[2]=mfma8i(W[2],X[0],G[2]);
  G[3]=mfma8i(W[0],X[3],G[3]); G[3]=mfma8i(W[1],X[2],G[3]); G[3]=mfma8i(W[2],X[1],G[3]); G[3]=mfma8i(W[3],X[0],G[3]);
  G[4]=mfma8i(W[0],X[4],G[4]); G[4]=mfma8i(W[1],X[3],G[4]); G[4]=mfma8i(W[2],X[2],G[4]); G[4]=mfma8i(W[3],X[1],G[4]); G[4]=mfma8i(W[4],X[0],G[4]);
  G[5]=mfma8i(W[0],X[5],G[5]); G[5]=mfma8i(W[1],X[4],G[5]); G[5]=mfma8i(W[2],X[3],G[5]); G[5]=mfma8i(W[3],X[2],G[5]); G[5]=mfma8i(W[4],X[1],G[5]);
}

// pipelined 8-chunk bypass-read phase: two M-tiles, 5 planes, double-buffered,
// counted vmcnt(10) so the next chunk's loads stay in flight during MFMA.
DEV void phase8(const i32x4* W, const int pstride, const int wofs,
                char* const* hp, size_t a0, size_t a1,
                i32x4* Ga, i32x4* Gb)
{
  i32x4 P0[5], Q0[5], P1[5], Q1[5];
  #pragma unroll
  for (int p = 0; p < 5; ++p){ ld4(P0[p], hp[p] + a0); ld4(Q0[p], hp[p] + a1); }
  #pragma unroll
  for (int c = 0; c < 8; ++c){
    const bool cur0 = ((c & 1) == 0);
    if (c < 7){
      size_t o = (size_t)(c + 1) * 64;
      #pragma unroll
      for (int p = 0; p < 5; ++p){
        if (cur0){ ld4(P1[p], hp[p] + a0 + o); ld4(Q1[p], hp[p] + a1 + o); }
        else     { ld4(P0[p], hp[p] + a0 + o); ld4(Q0[p], hp[p] + a1 + o); }
      }
      asm volatile("s_waitcnt vmcnt(10)" ::: "memory");
    } else {
      asm volatile("s_waitcnt vmcnt(0)" ::: "memory");
    }
    __builtin_amdgcn_sched_barrier(0);
    i32x4 Wc[5];
    #pragma unroll
    for (int p = 0; p < 5; ++p) Wc[p] = W[p * pstride + wofs + c];
    if (cur0){ str_h(Wc, P0, Ga); str_h(Wc, Q0, Gb); }
    else     { str_h(Wc, P1, Ga); str_h(Wc, Q1, Gb); }
  }
}

// ---------------- prep ----------------
__global__ void k_prep_zero(unsigned int* cnt){
  cnt[threadIdx.x] = 0u;    // 256 flags
}

// W planes: W = p1*2^-11 + ... + p5*2^-39 (trunc 2^-40)
DEV void wsplit5(float v, char* o1, char* o2, char* o3, char* o4, char* o5){
  float q1 = rintf(v * 0x1p11f);
  float r1 = fmaf(q1, -0x1p-11f, v);
  float q2 = rintf(r1 * 0x1p18f);
  float r2 = fmaf(q2, -0x1p-18f, r1);
  float q3 = rintf(r2 * 0x1p25f);
  float r3 = fmaf(q3, -0x1p-25f, r2);
  float q4 = rintf(r3 * 0x1p32f);
  float r4 = fmaf(q4, -0x1p-32f, r3);
  float q5 = rintf(r4 * 0x1p39f);
  *o1=(char)(int)q1; *o2=(char)(int)q2; *o3=(char)(int)q3;
  *o4=(char)(int)q4; *o5=(char)(int)q5;
}

__global__ void k_prep_w0(const float* __restrict__ Wih0, const float* __restrict__ Whh0,
                          char* __restrict__ p1, char* __restrict__ p2, char* __restrict__ p3,
                          char* __restrict__ p4, char* __restrict__ p5){
  int idx = blockIdx.x * 256 + threadIdx.x;      // 1179648
  int k = idx % 576;
  int r = (idx / 576) & 63;
  int j = idx / 36864;
  int R = (r & 3) * 512 + j * 16 + (r >> 2);
  float v = (k < 512) ? Whh0[(size_t)R * 512 + k] : Wih0[(size_t)R * 64 + (k - 512)];
  wsplit5(v, p1 + idx, p2 + idx, p3 + idx, p4 + idx, p5 + idx);
}

__global__ void k_prep_w1(const float* __restrict__ Wih1, const float* __restrict__ Whh1,
                          char* __restrict__ p1, char* __restrict__ p2, char* __restrict__ p3,
                          char* __restrict__ p4, char* __restrict__ p5){
  int idx = blockIdx.x * 256 + threadIdx.x;      // 2097152
  int k = idx & 1023;
  int r = (idx >> 10) & 63;
  int j = idx >> 16;
  int R = (r & 3) * 512 + j * 16 + (r >> 2);
  float v = (k < 512) ? Wih1[(size_t)R * 512 + k] : Whh1[(size_t)R * 512 + (k - 512)];
  wsplit5(v, p1 + idx, p2 + idx, p3 + idx, p4 + idx, p5 + idx);
}

__global__ void k_prep_b(const float* __restrict__ bih0, const float* __restrict__ bhh0,
                         const float* __restrict__ bih1, const float* __restrict__ bhh1,
                         double* __restrict__ bias0, double* __restrict__ bias1){
  int idx = blockIdx.x * 256 + threadIdx.x;      // 4096
  int i2 = idx & 2047;
  int j = i2 >> 6, r = i2 & 63;
  int R = (r & 3) * 512 + j * 16 + (r >> 2);
  if (idx < 2048) bias0[i2] = (double)bih0[R] + (double)bhh0[R];
  else            bias1[i2] = (double)bih1[R] + (double)bhh1[R];
}

// W_a -> 4 i8 planes (2^-11,-18,-25,-32; residual <= 2^-33)
__global__ void k_prep_wa(const float* __restrict__ Wa,
                          char* __restrict__ p1, char* __restrict__ p2,
                          char* __restrict__ p3, char* __restrict__ p4){
  int idx = blockIdx.x * 256 + threadIdx.x;      // 262144
  float v = Wa[idx];
  float q1 = rintf(v * 0x1p11f);
  float r1 = fmaf(q1, -0x1p-11f, v);
  float q2 = rintf(r1 * 0x1p18f);
  float r2 = fmaf(q2, -0x1p-18f, r1);
  float q3 = rintf(r2 * 0x1p25f);
  float r3 = fmaf(q3, -0x1p-25f, r2);
  float q4 = rintf(r3 * 0x1p32f);
  p1[idx]=(char)(int)q1; p2[idx]=(char)(int)q2;
  p3[idx]=(char)(int)q3; p4[idx]=(char)(int)q4;
}

// h split from f64: 5 planes at 2^-6,-13,-20,-27,-34 (trunc 2^-35)
DEV void hsplit5(double hd, char* o1, char* o2, char* o3, char* o4, char* o5){
  double q1 = rint(hd * 64.0);
  double r1 = hd - q1 * 0x1p-6;
  double q2 = rint(r1 * 0x1p13);
  double r2 = r1 - q2 * 0x1p-13;
  double q3 = rint(r2 * 0x1p20);
  double r3 = r2 - q3 * 0x1p-20;
  double q4 = rint(r3 * 0x1p27);
  double r4 = r3 - q4 * 0x1p-27;
  double q5 = rint(r4 * 0x1p34);
  *o1=(char)(int)q1; *o2=(char)(int)q2; *o3=(char)(int)q3;
  *o4=(char)(int)q4; *o5=(char)(int)q5;
}

DEV double sigd(double xv){ return 1.0 / (1.0 + exp(-xv)); }

// group scales
__constant__ double SH_[6] = {0x1p-17, 0x1p-24, 0x1p-31, 0x1p-38, 0x1p-45, 0x1p-52};
__constant__ double SX_[6] = {0x1p-13, 0x1p-20, 0x1p-27, 0x1p-34, 0x1p-41, 0x1p-48};

// ---------------- fused persistent 2-layer LSTM (exact-integer GEMM, f64 cell) ----------
// Flags: pflagL0[128] (L0 WG published h1[t] -> t+1), pflagH2[128] (L1 WG finished step t -> t+1).
// All cross-WG data moves via MALL (sc0 sc1); no acquire/release cache maintenance anywhere.
__global__ __launch_bounds__(256, 1) void k_lstm_fused(
    const float* __restrict__ x,
    const char* w0p1, const char* w0p2, const char* w0p3, const char* w0p4, const char* w0p5,
    const double* __restrict__ bias0,
    const char* w1p1, const char* w1p2, const char* w1p3, const char* w1p4, const char* w1p5,
    const double* __restrict__ bias1,
    char* h1a, char* h1b, char* h1c, char* h1d, char* h1e,
    char* h2a, char* h2b, char* h2c, char* h2d, char* h2e,
    _Float16* __restrict__ h2h, char* __restrict__ h2l8,
    unsigned int* __restrict__ cnt)
{
  const int wg   = blockIdx.x;
  const int tid  = threadIdx.x;
  const int w    = tid >> 6;
  const int lane = tid & 63;
  const int l15  = lane & 15;
  const int l4   = lane >> 4;
  unsigned int* pflagL0 = cnt;          // [128]
  unsigned int* pflagH2 = cnt + 128;    // [128]

  const int isL1 = wg >= 128;
  const int wgl  = isL1 ? wg - 128 : wg;
  const int gi   = wgl >> 5;
  const int j    = wgl & 31;
  const int r0   = w * 16 + l15;
  const int b0   = gi * 32 + l15;
  const int b1   = b0 + 16;
  const int hid  = j * 16 + w * 4 + l4;
  const size_t ringmt0 = (size_t)b0 * 512;
  const size_t ringmt1 = (size_t)b1 * 512;

  char* h1p[5] = {h1a, h1b, h1c, h1d, h1e};
  char* h2p[5] = {h2a, h2b, h2c, h2d, h2e};
  const i32x4 z = {0,0,0,0};

  if (!isL1){
    // ---------- layer 0 ----------
    const char* wp[5] = {w0p1, w0p2, w0p3, w0p4, w0p5};
    i32x4 W[5 * 9];
    {
      const size_t rowb = ((size_t)j * 64 + r0) * 576;
      #pragma unroll
      for (int p = 0; p < 5; ++p)
        #pragma unroll
        for (int c = 0; c < 9; ++c)
          W[p * 9 + c] = *(const i32x4*)(wp[p] + rowb + c * 64 + l4 * 16);
    }
    double bsd[4];
    #pragma unroll
    for (int q = 0; q < 4; ++q) bsd[q] = bias0[j * 64 + w * 16 + l4 * 4 + q];
    double c0 = 0.0, c1 = 0.0;
    unsigned int* myflag  = pflagL0 + gi * 32 + ((lane < 32) ? lane : 0);
    unsigned int* bpflag  = pflagH2 + gi * 32 + ((lane >= 32) ? (lane - 32) : 0);

    for (int t = 0; t < 1024; ++t){
      i32x4 XA[6], XB[6];
      {
        #pragma unroll
        for (int mt = 0; mt < 2; ++mt){
          const float* xr = x + ((size_t)(mt ? b1 : b0) * 1024 + t) * 64 + l4 * 16;
          unsigned int a[6][4] = {{0,0,0,0},{0,0,0,0},{0,0,0,0},{0,0,0,0},{0,0,0,0},{0,0,0,0}};
          #pragma unroll
          for (int i = 0; i < 16; ++i){
            float v = xr[i];
            float q1 = rintf(v * 4.0f);
            float r1 = fmaf(q1, -0.25f, v);
            float q2 = rintf(r1 * 0x1p9f);
            float r2 = fmaf(q2, -0x1p-9f, r1);
            float q3 = rintf(r2 * 0x1p16f);
            float r3 = fmaf(q3, -0x1p-16f, r2);
            float q4 = rintf(r3 * 0x1p23f);
            float r4 = fmaf(q4, -0x1p-23f, r3);
            float q5 = rintf(r4 * 0x1p30f);
            float r5 = fmaf(q5, -0x1p-30f, r4);
            float q6 = rintf(r5 * 0x1p37f);
            int wi = i >> 2, sh = (i & 3) * 8;
            a[0][wi] |= ((unsigned)(unsigned char)(char)(int)q1) << sh;
            a[1][wi] |= ((unsigned)(unsigned char)(char)(int)q2) << sh;
            a[2][wi] |= ((unsigned)(unsigned char)(char)(int)q3) << sh;
            a[3][wi] |= ((unsigned)(unsigned char)(char)(int)q4) << sh;
            a[4][wi] |= ((unsigned)(unsigned char)(char)(int)q5) << sh;
            a[5][wi] |= ((unsigned)(unsigned char)(char)(int)q6) << sh;
          }
          i32x4* X = mt ? XB : XA;
          #pragma unroll
          for (int p = 0; p < 6; ++p)
            X[p] = i32x4{(int)a[p][0], (int)a[p][1], (int)a[p][2], (int)a[p][3]};
        }
      }
      i32x4 Gha[6], Ghb[6], Gxa[6], Gxb[6];
      #pragma unroll
      for (int k = 0; k < 6; ++k){ Gha[k]=z; Ghb[k]=z; Gxa[k]=z; Gxb[k]=z; }
      {
        i32x4 Wc[5];
        #pragma unroll
        for (int p = 0; p < 5; ++p) Wc[p] = W[p * 9 + 8];
        str_x(Wc, XA, Gxa);
        str_x(Wc, XB, Gxb);
      }

      // wave-parallel poll: lanes<32 peers' h1[t-1]; lanes>=32 L1 backpressure (>= t-7)
      if (tid < 64){
        unsigned int* fp = (lane < 32) ? myflag : bpflag;
        unsigned int tgt = (lane < 32) ? (unsigned)t
                          : ((t >= 8) ? (unsigned)(t - 7) : 0u);
        poll_ge(fp, tgt);
      }
      __syncthreads();

      if (t > 0){
        const size_t sb = (size_t)((t - 1) & 7) << 16;
        phase8(W, 9, 0, h1p, sb + ringmt0 + l4 * 16, sb + ringmt1 + l4 * 16, Gha, Ghb);
      }

      const size_t rb = (size_t)(t & 7) << 16;
      #pragma unroll
      for (int mt = 0; mt < 2; ++mt){
        i32x4* Gh = mt ? Ghb : Gha;
        i32x4* Gx = mt ? Gxb : Gxa;
        double g[4];
        #pragma unroll
        for (int q = 0; q < 4; ++q){
          double s = bsd[q];
          #pragma unroll
          for (int k = 0; k < 6; ++k)
            s += (double)Gh[k][q] * SH_[k] + (double)Gx[k][q] * SX_[k];
          g[q] = s;
        }
        double& cs = mt ? c1 : c0;
        cs = sigd(g[1]) * cs + sigd(g[0]) * tanh(g[2]);
        double hv = sigd(g[3]) * tanh(cs);
        size_t o = rb + (mt ? ringmt1 : ringmt0) + hid;
        char v1c, v2c, v3c, v4c, v5c;
        hsplit5(hv, &v1c, &v2c, &v3c, &v4c, &v5c);
        st1(h1p[0] + o, v1c); st1(h1p[1] + o, v2c); st1(h1p[2] + o, v3c);
        st1(h1p[3] + o, v4c); st1(h1p[4] + o, v5c);
      }

      drain_vm();
      __syncthreads();
      if (tid == 0) st_flag(pflagL0 + wgl, (unsigned)(t + 1));
    }
  } else {
    // ---------- layer 1 ----------
    const char* wp[5] = {w1p1, w1p2, w1p3, w1p4, w1p5};
    i32x4 W[5 * 16];
    {
      const size_t rowb = ((size_t)j * 64 + r0) * 1024;
      #pragma unroll
      for (int p = 0; p < 5; ++p)
        #pragma unroll
        for (int c = 0; c < 16; ++c)
          W[p * 16 + c] = *(const i32x4*)(wp[p] + rowb + c * 64 + l4 * 16);
    }
    double bsd[4];
    #pragma unroll
    for (int q = 0; q < 4; ++q) bsd[q] = bias1[j * 64 + w * 16 + l4 * 4 + q];
    double c0 = 0.0, c1 = 0.0;
    unsigned int* srcflag = pflagL0 + gi * 32 + ((lane < 32) ? lane : 0);
    unsigned int* peerflag = pflagH2 + gi * 32 + ((lane >= 32) ? (lane - 32) : 0);

    for (int t = 0; t < 1024; ++t){
      // merged poll: lanes<32 h1[t] ready; lanes>=32 peers' h2[t-1]
      if (tid < 64){
        unsigned int* fp = (lane < 32) ? srcflag : peerflag;
        unsigned int tgt = (lane < 32) ? (unsigned)(t + 1)
                          : ((t > 0) ? (unsigned)t : 0u);
        poll_ge(fp, tgt);
      }
      __syncthreads();

      i32x4 Gha[6], Ghb[6];
      #pragma unroll
      for (int k = 0; k < 6; ++k){ Gha[k]=z; Ghb[k]=z; }
      {
        const size_t sb = (size_t)(t & 7) << 16;
        phase8(W, 16, 0, h1p, sb + ringmt0 + l4 * 16, sb + ringmt1 + l4 * 16, Gha, Ghb);
      }
      if (t > 0){
        const size_t sb = (size_t)((t - 1) & 3) << 16;
        phase8(W, 16, 8, h2p, sb + ringmt0 + l4 * 16, sb + ringmt1 + l4 * 16, Gha, Ghb);
      }

      const size_t rb = (size_t)(t & 3) << 16;
      #pragma unroll
      for (int mt = 0; mt < 2; ++mt){
        i32x4* Gh = mt ? Ghb : Gha;
        double g[4];
        #pragma unroll
        for (int q = 0; q < 4; ++q){
          double s = bsd[q];
          #pragma unroll
          for (int k = 0; k < 6; ++k) s += (double)Gh[k][q] * SH_[k];
          g[q] = s;
        }
        double& cs = mt ? c1 : c0;
        cs = sigd(g[1]) * cs + sigd(g[0]) * tanh(g[2]);
        double hv = sigd(g[3]) * tanh(cs);
        size_t o = rb + (mt ? ringmt1 : ringmt0) + hid;
        char v1c, v2c, v3c, v4c, v5c;
        hsplit5(hv, &v1c, &v2c, &v3c, &v4c, &v5c);
        st1(h2p[0] + o, v1c); st1(h2p[1] + o, v2c); st1(h2p[2] + o, v3c);
        st1(h2p[3] + o, v4c); st1(h2p[4] + o, v5c);
        // attention-facing: f16 hi + RELATIVE i8 residual (units of ulp(hh)/256)
        float hf = (float)hv;
        _Float16 hh = (_Float16)hf;
        float rs = hf - (float)hh;                    // exact in f32
        union { _Float16 h; unsigned short u; } cb; cb.h = hh;
        int E = (cb.u >> 10) & 31; if (E < 1) E = 1;
        int qr = (int)rintf(ldexpf(rs, 33 - E));
        qr = qr < -127 ? -127 : (qr > 127 ? 127 : qr);
        size_t pb = ((size_t)(mt ? b1 : b0) * 1024 + t) * 512 + hid;
        h2h[pb] = hh;                 // normal cached store (kernel-end flush)
        h2l8[pb] = (char)qr;
      }

      drain_vm();
      __syncthreads();
      // one bypass-store release: step t complete (h1[t] consumed AND h2[t] published)
      if (tid == 0) st_flag(pflagH2 + wgl, (unsigned)(t + 1));
    }
  }
}

// ---------------- attention energies: exact integer GEMM + f64 epilogue ----------------
__global__ __launch_bounds__(256) void k_att_e(
    const _Float16* __restrict__ h2, const char* __restrict__ h2l8,
    const char* __restrict__ wa1, const char* __restrict__ wa2,
    const char* __restrict__ wa3, const char* __restrict__ wa4,
    const float* __restrict__ b_a, const float* __restrict__ v_a,
    const float* __restrict__ b_v, double* __restrict__ e)
{
  __shared__ char Ap[4][32][528];
  __shared__ char Wp[2][4][16][528];
  __shared__ double partial[2][32];
  const int tid  = threadIdx.x;
  const int w    = tid >> 6;
  const int mt   = w & 1;
  const int nh   = w >> 1;
  const int lane = tid & 63;
  const int l15  = lane & 15;
  const int l4   = lane >> 4;
  const size_t rid0 = (size_t)blockIdx.x * 32;

  // stage h: reconstruct exact f32 from f16 + rel-i8, split into 4 i8 planes
  for (int i = tid; i < 2048; i += 256){
    int row = i >> 6, c8 = (i & 63) << 3;
    const _Float16* hp = h2 + (rid0 + row) * 512 + c8;
    const char*     rp = h2l8 + (rid0 + row) * 512 + c8;
    unsigned long long o1 = 0, o2 = 0, o3 = 0, o4 = 0;
    #pragma unroll
    for (int q = 0; q < 8; ++q){
      union { _Float16 h; unsigned short u; } cb; cb.h = hp[q];
      int E = (cb.u >> 10) & 31; if (E < 1) E = 1;
      float h = (float)cb.h + ldexpf((float)rp[q], E - 33);
      float q1 = rintf(h * 64.f);     float r1 = fmaf(q1, -0x1p-6f, h);
      float q2 = rintf(r1 * 0x1p13f); float r2 = fmaf(q2, -0x1p-13f, r1);
      float q3 = rintf(r2 * 0x1p20f); float r3 = fmaf(q3, -0x1p-20f, r2);
      float q4 = rintf(r3 * 0x1p27f);
      o1 |= ((unsigned long long)(unsigned char)(char)(int)q1) << (8 * q);
      o2 |= ((unsigned long long)(unsigned char)(char)(int)q2) << (8 * q);
      o3 |= ((unsigned long long)(unsigned char)(char)(int)q3) << (8 * q);
      o4 |= ((unsigned long long)(unsigned char)(char)(int)q4) << (8 * q);
    }
    *(unsigned long long*)&Ap[0][row][c8] = o1;
    *(unsigned long long*)&Ap[1][row][c8] = o2;
    *(unsigned long long*)&Ap[2][row][c8] = o3;
    *(unsigned long long*)&Ap[3][row][c8] = o4;
  }
  __syncthreads();

  const int sh = tid >> 7;         // staging half (0: nh0, 1: nh1)
  const int st = tid & 127;
  double ep0 = 0.0, ep1 = 0.0, ep2 = 0.0, ep3 = 0.0;
  for (int it = 0; it < 16; ++it){
    if (it) __syncthreads();
    {
      int nt = sh * 16 + it;
      for (int i = st; i < 512; i += 128){
        int row = (i >> 5) & 15, c16 = (i & 31) << 4;
        size_t go = (size_t)(nt * 16 + row) * 512 + c16;
        *(i32x4*)&Wp[sh][0][row][c16] = *(const i32x4*)(wa1 + go);
        *(i32x4*)&Wp[sh][1][row][c16] = *(const i32x4*)(wa2 + go);
        *(i32x4*)&Wp[sh][2][row][c16] = *(const i32x4*)(wa3 + go);
        *(i32x4*)&Wp[sh][3][row][c16] = *(const i32x4*)(wa4 + go);
      }
    }
    __syncthreads();
    i32x4 G0={0,0,0,0},G1={0,0,0,0},G2={0,0,0,0},G3={0,0,0,0},G4={0,0,0,0},G5={0,0,0,0};
    #pragma unroll
    for (int c = 0; c < 8; ++c){
      int ko = c * 64 + l4 * 16;
      i32x4 A1 = *(const i32x4*)&Ap[0][mt * 16 + l15][ko];
      i32x4 A2 = *(const i32x4*)&Ap[1][mt * 16 + l15][ko];
      i32x4 A3 = *(const i32x4*)&Ap[2][mt * 16 + l15][ko];
      i32x4 A4 = *(const i32x4*)&Ap[3][mt * 16 + l15][ko];
      i32x4 B1 = *(const i32x4*)&Wp[nh][0][l15][ko];
      i32x4 B2 = *(const i32x4*)&Wp[nh][1][l15][ko];
      i32x4 B3 = *(const i32x4*)&Wp[nh][2][l15][ko];
      i32x4 B4 = *(const i32x4*)&Wp[nh][3][l15][ko];
      G0 = mfma8i(A1, B1, G0);
      G1 = mfma8i(A1, B2, G1); G1 = mfma8i(A2, B1, G1);
      G2 = mfma8i(A1, B3, G2); G2 = mfma8i(A2, B2, G2); G2 = mfma8i(A3, B1, G2);
      G3 = mfma8i(A1, B4, G3); G3 = mfma8i(A2, B3, G3); G3 = mfma8i(A3, B2, G3); G3 = mfma8i(A4, B1, G3);
      G4 = mfma8i(A2, B4, G4); G4 = mfma8i(A3, B3, G4); G4 = mfma8i(A4, B2, G4);
      G5 = mfma8i(A3, B4, G5); G5 = mfma8i(A4, B3, G5);
    }
    int n = (nh * 16 + it) * 16 + l15;
    double ban = (double)b_a[n], van = (double)v_a[n];
    #pragma unroll
    for (int q = 0; q < 4; ++q){
      double val = (double)G0[q]*SH_[0] + (double)G1[q]*SH_[1] + (double)G2[q]*SH_[2]
                 + (double)G3[q]*SH_[3] + (double)G4[q]*SH_[4] + (double)G5[q]*SH_[5] + ban;
      double tv = tanh(val) * van;
      if (q == 0) ep0 += tv; else if (q == 1) ep1 += tv;
      else if (q == 2) ep2 += tv; else ep3 += tv;
    }
  }
  #pragma unroll
  for (int m = 1; m < 16; m <<= 1){
    ep0 += __shfl_xor(ep0, m); ep1 += __shfl_xor(ep1, m);
    ep2 += __shfl_xor(ep2, m); ep3 += __shfl_xor(ep3, m);
  }
  if (l15 == 0){
    int rbase = mt * 16 + l4 * 4;
    partial[nh][rbase + 0] = ep0;
    partial[nh][rbase + 1] = ep1;
    partial[nh][rbase + 2] = ep2;
    partial[nh][rbase + 3] = ep3;
  }
  __syncthreads();
  if (tid < 32)
    e[rid0 + tid] = partial[0][tid] + partial[1][tid] + (double)b_v[0];
}

// ---------------- entmax15 (f64) + context + FC ----------------
__global__ __launch_bounds__(256) void k_entmax(
    const double* __restrict__ e, const _Float16* __restrict__ h2,
    const float* __restrict__ fcW, const float* __restrict__ fcb,
    float* __restrict__ out)
{
  __shared__ double xu[1024], sbd[1024], t0d[1024], t1d[1024];
  __shared__ float sbf[1024];
  __shared__ float red4[4];
  __shared__ double redd[4];
  __shared__ double scald;
  const int tid  = threadIdx.x;
  const int b    = blockIdx.x;
  const int wv   = tid >> 6;
  const int lane = tid & 63;

  double lm = -1e300;
  for (int i = tid; i < 1024; i += 256){
    double v = e[b * 1024 + i];
    xu[i] = v;
    lm = fmax(lm, v);
  }
  for (int m = 32; m >= 1; m >>= 1) lm = fmax(lm, __shfl_xor(lm, m));
  if (lane == 0) redd[wv] = lm;
  __syncthreads();
  double rowmax = fmax(fmax(redd[0], redd[1]), fmax(redd[2], redd[3]));
  __syncthreads();
  for (int i = tid; i < 1024; i += 256){
    double v = xu[i] - rowmax;
    xu[i] = v; sbd[i] = v;
  }
  __syncthreads();

  // bitonic ascending sort (f64)
  for (int ksz = 2; ksz <= 1024; ksz <<= 1){
    for (int jj = ksz >> 1; jj > 0; jj >>= 1){
      for (int i = tid; i < 1024; i += 256){
        int ixj = i ^ jj;
        if (ixj > i){
          double a = sbd[i], c = sbd[ixj];
          if (((i & ksz) == 0) ? (a > c) : (a < c)){ sbd[i] = c; sbd[ixj] = a; }
        }
      }
      __syncthreads();
    }
  }

  // descending view; inclusive scan (f64)
  for (int i = tid; i < 1024; i += 256) t0d[i] = sbd[1023 - i];
  __syncthreads();
  double* src = t0d; double* dst = t1d;
  for (int off = 1; off < 1024; off <<= 1){
    for (int i = tid; i < 1024; i += 256)
      dst[i] = src[i] + ((i >= off) ? src[i - off] : 0.0);
    __syncthreads();
    double* tmp = src; src = dst; dst = tmp;
  }

  float lc = 0.f;
  for (int i = tid; i < 1024; i += 256){
    double xs_i = sbd[1023 - i];
    double sup = (double)(i + 1) * xs_i - src[i] + 0.5;
    if (sup > 0.0) lc += 1.f;
  }
  for (int m = 32; m >= 1; m >>= 1) lc += __shfl_xor(lc, m);
  if (lane == 0) red4[wv] = lc;
  __syncthreads();
  if (tid == 0){
    int cntS = (int)(red4[0] + red4[1] + red4[2] + red4[3] + 0.5f);
    int ss = cntS < 1 ? 1 : (cntS > 1023 ? 1023 : cntS);
    double xss = sbd[1023 - ss];
    scald = ((double)(ss + 1) * xss - src[ss] + 0.5) / (double)(ss + 1);
  }
  __syncthreads();
  double tau = scald;

  double ls = 0.0;
  for (int i = tid; i < 1024; i += 256){
    double d = xu[i] - tau;
    double y = (d > 0.0) ? sqrt(d) : 0.0;
    dst[i] = y;
    ls += y;
  }
  for (int m = 32; m >= 1; m >>= 1) ls += __shfl_xor(ls, m);
  if (lane == 0) redd[wv] = ls;
  __syncthreads();
  double Z = redd[0] + redd[1] + redd[2] + redd[3];
  __syncthreads();
  for (int i = tid; i < 1024; i += 256){
    float a = (float)(dst[i] / Z);
    sbf[i] = a;
    out[128 + b * 1024 + i] = a;
  }
  __syncthreads();

  // context over nonzero weights + FC (O=1)
  const int h0 = tid * 2;
  float cx0 = 0.f, cx1 = 0.f;
  for (int s = 0; s < 1024; ++s){
    float wt = sbf[s];
    if (wt > 0.f){
      unsigned int u = *(const unsigned int*)(h2 + ((size_t)b * 1024 + s) * 512 + h0);
      union { unsigned int u; _Float16 h[2]; } cv; cv.u = u;
      cx0 += wt * (float)cv.h[0];
      cx1 += wt * (float)cv.h[1];
    }
  }
  float p = fcW[h0] * cx0 + fcW[h0 + 1] * cx1;
  for (int m = 32; m >= 1; m >>= 1) p += __shfl_xor(p, m);
  if (lane == 0) red4[wv] = p;
  __syncthreads();
  if (tid == 0) out[b] = red4[0] + red4[1] + red4[2] + red4[3] + fcb[0];
}

// ---------------- host launch ----------------
extern "C" void kernel_launch(void* const* d_in, const int* in_sizes, int n_in,
                              void* d_out, int out_size, void* d_ws, size_t ws_size,
                              hipStream_t stream)
{
  (void)in_sizes; (void)n_in; (void)out_size;
  const float* x    = (const float*)d_in[0];
  const float* Wih0 = (const float*)d_in[1];
  const float* Whh0 = (const float*)d_in[2];
  const float* bih0 = (const float*)d_in[3];
  const float* bhh0 = (const float*)d_in[4];
  const float* Wih1 = (const float*)d_in[5];
  const float* Whh1 = (const float*)d_in[6];
  const float* bih1 = (const float*)d_in[7];
  const float* bhh1 = (const float*)d_in[8];
  const float* Wa   = (const float*)d_in[9];
  const float* ba   = (const float*)d_in[10];
  const float* va   = (const float*)d_in[11];
  const float* bv   = (const float*)d_in[12];
  const float* fcW  = (const float*)d_in[13];
  const float* fcb  = (const float*)d_in[14];

  const size_t NEED = 223773696ull;
  if (ws_size < NEED) return;

  char* ws = (char*)d_ws;
  unsigned int* cnt = (unsigned int*)(ws);                  // 1 KiB (256 flags)
  char* w0p[5]; for (int p = 0; p < 5; ++p) w0p[p] = ws + 1024ull + (size_t)p * 1179648ull;
  double* bias0 = (double*)(ws + 5899264ull);               // 16,384
  char* w1p[5]; for (int p = 0; p < 5; ++p) w1p[p] = ws + 5915648ull + (size_t)p * 2097152ull;
  double* bias1 = (double*)(ws + 16401408ull);              // 16,384
  char* wa1 = ws + 16417792ull;                             // 4 x 262,144
  char* wa2 = wa1 + 262144ull;
  char* wa3 = wa2 + 262144ull;
  char* wa4 = wa3 + 262144ull;
  char* h1p[5]; for (int p = 0; p < 5; ++p) h1p[p] = ws + 17466368ull + (size_t)p * 524288ull;  // 8 slots
  char* h2p[5]; for (int p = 0; p < 5; ++p) h2p[p] = ws + 20087808ull + (size_t)p * 262144ull;  // 4 slots
  double* ebuf = (double*)(ws + 21398528ull);               // 1,048,576
  _Float16* h2h = (_Float16*)(ws + 22447104ull);            // 134,217,728
  char* h2l8 = ws + 156664832ull;                           // 67,108,864
  float* out = (float*)d_out;

  k_prep_zero<<<1, 256, 0, stream>>>(cnt);
  k_prep_w0<<<4608, 256, 0, stream>>>(Wih0, Whh0, w0p[0], w0p[1], w0p[2], w0p[3], w0p[4]);
  k_prep_w1<<<8192, 256, 0, stream>>>(Wih1, Whh1, w1p[0], w1p[1], w1p[2], w1p[3], w1p[4]);
  k_prep_b<<<16, 256, 0, stream>>>(bih0, bhh0, bih1, bhh1, bias0, bias1);
  k_prep_wa<<<1024, 256, 0, stream>>>(Wa, wa1, wa2, wa3, wa4);
  k_lstm_fused<<<256, 256, 0, stream>>>(x,
      w0p[0], w0p[1], w0p[2], w0p[3], w0p[4], bias0,
      w1p[0], w1p[1], w1p[2], w1p[3], w1p[4], bias1,
      h1p[0], h1p[1], h1p[2], h1p[3], h1p[4],
      h2p[0], h2p[1], h2p[2], h2p[3], h2p[4],
      h2h, h2l8, cnt);
  k_att_e<<<4096, 256, 0, stream>>>(h2h, h2l8, wa1, wa2, wa3, wa4, ba, va, bv, ebuf);
  k_entmax<<<128, 256, 0, stream>>>(ebuf, h2h, fcW, fcb, out);
}

// Round 15
// 21632.359 us; speedup vs baseline: 3.5538x; 1.2239x over previous
//
#include <hip/hip_runtime.h>

typedef __attribute__((ext_vector_type(8))) _Float16 half8;
typedef __attribute__((ext_vector_type(4))) float f32x4;
typedef __attribute__((ext_vector_type(4))) int   i32x4;

#define DEV static __device__ __forceinline__

DEV i32x4 mfma8i(i32x4 a, i32x4 b, i32x4 c){
  return __builtin_amdgcn_mfma_i32_16x16x64_i8(a, b, c, 0, 0, 0);
}
// MALL-bypass primitives (sc0 sc1: skip L1+L2)
DEV void ld4(i32x4& d, const char* p){
  asm volatile("global_load_dwordx4 %0, %1, off sc0 sc1" : "=v"(d) : "v"(p));
}
DEV void st1(char* p, int v){
  asm volatile("global_store_byte %0, %1, off sc0 sc1" :: "v"(p), "v"(v) : "memory");
}
DEV void st_flag(unsigned int* p, unsigned int v){
  asm volatile("s_waitcnt vmcnt(0)" ::: "memory");
  asm volatile("global_store_dword %0, %1, off sc0 sc1" :: "v"(p), "v"(v) : "memory");
}
DEV void drain_vm(){ asm volatile("s_waitcnt vmcnt(0)" ::: "memory"); }
DEV void poll_ge(unsigned int* fp, unsigned int tgt){
  for (;;){
    unsigned int v = __hip_atomic_load(fp, __ATOMIC_RELAXED, __HIP_MEMORY_SCOPE_AGENT);
    if (__all(v >= tgt)) break;
    __builtin_amdgcn_s_sleep(1);
  }
}

// W5 x H5 plane products grouped by scale d=i+j (d=2..7)
DEV void str_h(const i32x4* W, const i32x4* B, i32x4* G){
  G[0]=mfma8i(W[0],B[0],G[0]);
  G[1]=mfma8i(W[0],B[1],G[1]); G[1]=mfma8i(W[1],B[0],G[1]);
  G[2]=mfma8i(W[0],B[2],G[2]); G[2]=mfma8i(W[1],B[1],G[2]); G[2]=mfma8i(W[2],B[0],G[2]);
  G[3]=mfma8i(W[0],B[3],G[3]); G[3]=mfma8i(W[1],B[2],G[3]); G[3]=mfma8i(W[2],B[1],G[3]); G[3]=mfma8i(W[3],B[0],G[3]);
  G[4]=mfma8i(W[0],B[4],G[4]); G[4]=mfma8i(W[1],B[3],G[4]); G[4]=mfma8i(W[2],B[2],G[4]); G[4]=mfma8i(W[3],B[1],G[4]); G[4]=mfma8i(W[4],B[0],G[4]);
  G[5]=mfma8i(W[1],B[4],G[5]); G[5]=mfma8i(W[2],B[3],G[5]); G[5]=mfma8i(W[3],B[2],G[5]); G[5]=mfma8i(W[4],B[1],G[5]);
}
// W5 x X6 plane products grouped by scale (d=2..7)
DEV void str_x(const i32x4* W, const i32x4* X, i32x4* G){
  G[0]=mfma8i(W[0],X[0],G[0]);
  G[1]=mfma8i(W[0],X[1],G[1]); G[1]=mfma8i(W[1],X[0],G[1]);
  G[2]=mfma8i(W[0],X[2],G[2]); G[2]=mfma8i(W[1],X[1],G[2]); G[2]=mfma8i(W[2],X[0],G[2]);
  G[3]=mfma8i(W[0],X[3],G[3]); G[3]=mfma8i(W[1],X[2],G[3]); G[3]=mfma8i(W[2],X[1],G[3]); G[3]=mfma8i(W[3],X[0],G[3]);
  G[4]=mfma8i(W[0],X[4],G[4]); G[4]=mfma8i(W[1],X[3],G[4]); G[4]=mfma8i(W[2],X[2],G[4]); G[4]=mfma8i(W[3],X[1],G[4]); G[4]=mfma8i(W[4],X[0],G[4]);
  G[5]=mfma8i(W[0],X[5],G[5]); G[5]=mfma8i(W[1],X[4],G[5]); G[5]=mfma8i(W[2],X[3],G[5]); G[5]=mfma8i(W[3],X[2],G[5]); G[5]=mfma8i(W[4],X[1],G[5]);
}

#define SEG_STRIDE 4352   // 16 rows x 272B (256 data + 16 pad) per (plane,tile) segment
#define LDS_BYTES  (10 * SEG_STRIDE)

// Cooperative half-phase stage: 40KB (10 segs x 16 rows x 256B) MALL -> LDS.
// tbase = ring slot base + (gi*32)*512 (no per-lane terms).
DEV void stage_half(char* const* hp, size_t tbase, int half, char* lds, int tid){
  const int row = tid >> 4;
  const int off = (tid & 15) * 16;
  i32x4 v[10];
  #pragma unroll
  for (int u = 0; u < 10; ++u){
    int plane = u >> 1, tile = u & 1;
    ld4(v[u], hp[plane] + tbase + (size_t)(tile * 16 + row) * 512 + (size_t)half * 256 + off);
  }
  asm volatile("s_waitcnt vmcnt(0)" ::: "memory");
  __builtin_amdgcn_sched_barrier(0);
  #pragma unroll
  for (int u = 0; u < 10; ++u)
    *(i32x4*)(lds + u * SEG_STRIDE + row * 272 + off) = v[u];
}

// Compute 4 chunks of one half from LDS; W streamed from L2 per chunk.
DEV void compute_half(const char* const* wp, size_t rowb, int wofs, int hc,
                      const char* lds, int l15, int l4, i32x4* Ga, i32x4* Gb){
  #pragma unroll
  for (int c = 0; c < 4; ++c){
    i32x4 Wc[5], Ba[5], Bb[5];
    #pragma unroll
    for (int p = 0; p < 5; ++p)
      Wc[p] = *(const i32x4*)(wp[p] + rowb + (size_t)(wofs + hc + c) * 64 + l4 * 16);
    #pragma unroll
    for (int p = 0; p < 5; ++p){
      Ba[p] = *(const i32x4*)(lds + (p * 2 + 0) * SEG_STRIDE + l15 * 272 + c * 64 + l4 * 16);
      Bb[p] = *(const i32x4*)(lds + (p * 2 + 1) * SEG_STRIDE + l15 * 272 + c * 64 + l4 * 16);
    }
    str_h(Wc, Ba, Ga);
    str_h(Wc, Bb, Gb);
  }
}

// ---------------- prep ----------------
__global__ void k_prep_zero(unsigned int* cnt){
  cnt[threadIdx.x] = 0u;    // 256 flags
}

// W planes: W = p1*2^-11 + ... + p5*2^-39 (trunc 2^-40)
DEV void wsplit5(float v, char* o1, char* o2, char* o3, char* o4, char* o5){
  float q1 = rintf(v * 0x1p11f);
  float r1 = fmaf(q1, -0x1p-11f, v);
  float q2 = rintf(r1 * 0x1p18f);
  float r2 = fmaf(q2, -0x1p-18f, r1);
  float q3 = rintf(r2 * 0x1p25f);
  float r3 = fmaf(q3, -0x1p-25f, r2);
  float q4 = rintf(r3 * 0x1p32f);
  float r4 = fmaf(q4, -0x1p-32f, r3);
  float q5 = rintf(r4 * 0x1p39f);
  *o1=(char)(int)q1; *o2=(char)(int)q2; *o3=(char)(int)q3;
  *o4=(char)(int)q4; *o5=(char)(int)q5;
}

__global__ void k_prep_w0(const float* __restrict__ Wih0, const float* __restrict__ Whh0,
                          char* __restrict__ p1, char* __restrict__ p2, char* __restrict__ p3,
                          char* __restrict__ p4, char* __restrict__ p5){
  int idx = blockIdx.x * 256 + threadIdx.x;      // 1179648
  int k = idx % 576;
  int r = (idx / 576) & 63;
  int j = idx / 36864;
  int R = (r & 3) * 512 + j * 16 + (r >> 2);
  float v = (k < 512) ? Whh0[(size_t)R * 512 + k] : Wih0[(size_t)R * 64 + (k - 512)];
  wsplit5(v, p1 + idx, p2 + idx, p3 + idx, p4 + idx, p5 + idx);
}

__global__ void k_prep_w1(const float* __restrict__ Wih1, const float* __restrict__ Whh1,
                          char* __restrict__ p1, char* __restrict__ p2, char* __restrict__ p3,
                          char* __restrict__ p4, char* __restrict__ p5){
  int idx = blockIdx.x * 256 + threadIdx.x;      // 2097152
  int k = idx & 1023;
  int r = (idx >> 10) & 63;
  int j = idx >> 16;
  int R = (r & 3) * 512 + j * 16 + (r >> 2);
  float v = (k < 512) ? Wih1[(size_t)R * 512 + k] : Whh1[(size_t)R * 512 + (k - 512)];
  wsplit5(v, p1 + idx, p2 + idx, p3 + idx, p4 + idx, p5 + idx);
}

__global__ void k_prep_b(const float* __restrict__ bih0, const float* __restrict__ bhh0,
                         const float* __restrict__ bih1, const float* __restrict__ bhh1,
                         double* __restrict__ bias0, double* __restrict__ bias1){
  int idx = blockIdx.x * 256 + threadIdx.x;      // 4096
  int i2 = idx & 2047;
  int j = i2 >> 6, r = i2 & 63;
  int R = (r & 3) * 512 + j * 16 + (r >> 2);
  if (idx < 2048) bias0[i2] = (double)bih0[R] + (double)bhh0[R];
  else            bias1[i2] = (double)bih1[R] + (double)bhh1[R];
}

// W_a -> 4 i8 planes (2^-11,-18,-25,-32; residual <= 2^-33)
__global__ void k_prep_wa(const float* __restrict__ Wa,
                          char* __restrict__ p1, char* __restrict__ p2,
                          char* __restrict__ p3, char* __restrict__ p4){
  int idx = blockIdx.x * 256 + threadIdx.x;      // 262144
  float v = Wa[idx];
  float q1 = rintf(v * 0x1p11f);
  float r1 = fmaf(q1, -0x1p-11f, v);
  float q2 = rintf(r1 * 0x1p18f);
  float r2 = fmaf(q2, -0x1p-18f, r1);
  float q3 = rintf(r2 * 0x1p25f);
  float r3 = fmaf(q3, -0x1p-25f, r2);
  float q4 = rintf(r3 * 0x1p32f);
  p1[idx]=(char)(int)q1; p2[idx]=(char)(int)q2;
  p3[idx]=(char)(int)q3; p4[idx]=(char)(int)q4;
}

// h split from f64: 5 planes at 2^-6,-13,-20,-27,-34 (trunc 2^-35)
DEV void hsplit5(double hd, char* o1, char* o2, char* o3, char* o4, char* o5){
  double q1 = rint(hd * 64.0);
  double r1 = hd - q1 * 0x1p-6;
  double q2 = rint(r1 * 0x1p13);
  double r2 = r1 - q2 * 0x1p-13;
  double q3 = rint(r2 * 0x1p20);
  double r3 = r2 - q3 * 0x1p-20;
  double q4 = rint(r3 * 0x1p27);
  double r4 = r3 - q4 * 0x1p-27;
  double q5 = rint(r4 * 0x1p34);
  *o1=(char)(int)q1; *o2=(char)(int)q2; *o3=(char)(int)q3;
  *o4=(char)(int)q4; *o5=(char)(int)q5;
}

DEV double sigd(double xv){ return 1.0 / (1.0 + exp(-xv)); }

// group scales
__constant__ double SH_[6] = {0x1p-17, 0x1p-24, 0x1p-31, 0x1p-38, 0x1p-45, 0x1p-52};
__constant__ double SX_[6] = {0x1p-13, 0x1p-20, 0x1p-27, 0x1p-34, 0x1p-41, 0x1p-48};

// ---------------- fused persistent 2-layer LSTM (exact-integer GEMM, f64 cell) ----------
__global__ __launch_bounds__(256, 1) void k_lstm_fused(
    const float* __restrict__ x,
    const char* w0p1, const char* w0p2, const char* w0p3, const char* w0p4, const char* w0p5,
    const double* __restrict__ bias0,
    const char* w1p1, const char* w1p2, const char* w1p3, const char* w1p4, const char* w1p5,
    const double* __restrict__ bias1,
    char* h1a, char* h1b, char* h1c, char* h1d, char* h1e,
    char* h2a, char* h2b, char* h2c, char* h2d, char* h2e,
    _Float16* __restrict__ h2h, char* __restrict__ h2l8,
    unsigned int* __restrict__ cnt)
{
  __shared__ char sbuf[LDS_BYTES];
  const int wg   = blockIdx.x;
  const int tid  = threadIdx.x;
  const int w    = tid >> 6;
  const int lane = tid & 63;
  const int l15  = lane & 15;
  const int l4   = lane >> 4;
  unsigned int* pflagL0 = cnt;          // [128]
  unsigned int* pflagH2 = cnt + 128;    // [128]

  const int isL1 = wg >= 128;
  const int wgl  = isL1 ? wg - 128 : wg;
  const int gi   = wgl >> 5;
  const int j    = wgl & 31;
  const int r0   = w * 16 + l15;
  const int b0   = gi * 32 + l15;
  const int b1   = b0 + 16;
  const int hid  = j * 16 + w * 4 + l4;
  const size_t ringmt0 = (size_t)b0 * 512;
  const size_t ringmt1 = (size_t)b1 * 512;
  const size_t gbase   = (size_t)(gi * 32) * 512;   // group batch base (no per-lane)

  char* h1p[5] = {h1a, h1b, h1c, h1d, h1e};
  char* h2p[5] = {h2a, h2b, h2c, h2d, h2e};
  const i32x4 z = {0,0,0,0};

  if (!isL1){
    // ---------- layer 0 ----------
    const char* wp[5] = {w0p1, w0p2, w0p3, w0p4, w0p5};
    const size_t rowb = ((size_t)j * 64 + r0) * 576;
    i32x4 WX[5];    // x-block W chunk (loop-invariant, resident)
    #pragma unroll
    for (int p = 0; p < 5; ++p)
      WX[p] = *(const i32x4*)(wp[p] + rowb + 8 * 64 + l4 * 16);
    double bsd[4];
    #pragma unroll
    for (int q = 0; q < 4; ++q) bsd[q] = bias0[j * 64 + w * 16 + l4 * 4 + q];
    double c0 = 0.0, c1 = 0.0;

    for (int t = 0; t < 1024; ++t){
      i32x4 XA[6], XB[6];
      {
        #pragma unroll
        for (int mt = 0; mt < 2; ++mt){
          const float* xr = x + ((size_t)(mt ? b1 : b0) * 1024 + t) * 64 + l4 * 16;
          unsigned int a[6][4] = {{0,0,0,0},{0,0,0,0},{0,0,0,0},{0,0,0,0},{0,0,0,0},{0,0,0,0}};
          #pragma unroll
          for (int i = 0; i < 16; ++i){
            float v = xr[i];
            float q1 = rintf(v * 4.0f);
            float r1 = fmaf(q1, -0.25f, v);
            float q2 = rintf(r1 * 0x1p9f);
            float r2 = fmaf(q2, -0x1p-9f, r1);
            float q3 = rintf(r2 * 0x1p16f);
            float r3 = fmaf(q3, -0x1p-16f, r2);
            float q4 = rintf(r3 * 0x1p23f);
            float r4 = fmaf(q4, -0x1p-23f, r3);
            float q5 = rintf(r4 * 0x1p30f);
            float r5 = fmaf(q5, -0x1p-30f, r4);
            float q6 = rintf(r5 * 0x1p37f);
            int wi = i >> 2, sh = (i & 3) * 8;
            a[0][wi] |= ((unsigned)(unsigned char)(char)(int)q1) << sh;
            a[1][wi] |= ((unsigned)(unsigned char)(char)(int)q2) << sh;
            a[2][wi] |= ((unsigned)(unsigned char)(char)(int)q3) << sh;
            a[3][wi] |= ((unsigned)(unsigned char)(char)(int)q4) << sh;
            a[4][wi] |= ((unsigned)(unsigned char)(char)(int)q5) << sh;
            a[5][wi] |= ((unsigned)(unsigned char)(char)(int)q6) << sh;
          }
          i32x4* X = mt ? XB : XA;
          #pragma unroll
          for (int p = 0; p < 6; ++p)
            X[p] = i32x4{(int)a[p][0], (int)a[p][1], (int)a[p][2], (int)a[p][3]};
        }
      }
      i32x4 Gha[6], Ghb[6], Gxa[6], Gxb[6];
      #pragma unroll
      for (int k = 0; k < 6; ++k){ Gha[k]=z; Ghb[k]=z; Gxa[k]=z; Gxb[k]=z; }
      str_x(WX, XA, Gxa);
      str_x(WX, XB, Gxb);

      // polls: lanes<32 (wave0) peers' h1[t-1]; wave1 lanes<32 backpressure
      if (w == 0 && lane < 32)
        poll_ge(pflagL0 + gi * 32 + lane, (unsigned)t);
      if (w == 1 && lane < 32 && t >= 8)
        poll_ge(pflagH2 + gi * 32 + lane, (unsigned)(t - 7));
      __syncthreads();

      if (t > 0){
        const size_t sb = ((size_t)((t - 1) & 7) << 16) + gbase;
        stage_half(h1p, sb, 0, sbuf, tid);
        __syncthreads();
        compute_half(wp, rowb, 0, 0, sbuf, l15, l4, Gha, Ghb);
        __syncthreads();
        stage_half(h1p, sb, 1, sbuf, tid);
        __syncthreads();
        compute_half(wp, rowb, 0, 4, sbuf, l15, l4, Gha, Ghb);
      }

      const size_t rb = (size_t)(t & 7) << 16;
      #pragma unroll
      for (int mt = 0; mt < 2; ++mt){
        i32x4* Gh = mt ? Ghb : Gha;
        i32x4* Gx = mt ? Gxb : Gxa;
        double g[4];
        #pragma unroll
        for (int q = 0; q < 4; ++q){
          double s = bsd[q];
          #pragma unroll
          for (int k = 0; k < 6; ++k)
            s += (double)Gh[k][q] * SH_[k] + (double)Gx[k][q] * SX_[k];
          g[q] = s;
        }
        double& cs = mt ? c1 : c0;
        cs = sigd(g[1]) * cs + sigd(g[0]) * tanh(g[2]);
        double hv = sigd(g[3]) * tanh(cs);
        size_t o = rb + (mt ? ringmt1 : ringmt0) + hid;
        char v1c, v2c, v3c, v4c, v5c;
        hsplit5(hv, &v1c, &v2c, &v3c, &v4c, &v5c);
        st1(h1p[0] + o, v1c); st1(h1p[1] + o, v2c); st1(h1p[2] + o, v3c);
        st1(h1p[3] + o, v4c); st1(h1p[4] + o, v5c);
      }

      drain_vm();
      __syncthreads();
      if (tid == 0) st_flag(pflagL0 + wgl, (unsigned)(t + 1));
    }
  } else {
    // ---------- layer 1 ----------
    const char* wp[5] = {w1p1, w1p2, w1p3, w1p4, w1p5};
    const size_t rowb = ((size_t)j * 64 + r0) * 1024;
    double bsd[4];
    #pragma unroll
    for (int q = 0; q < 4; ++q) bsd[q] = bias1[j * 64 + w * 16 + l4 * 4 + q];
    double c0 = 0.0, c1 = 0.0;

    for (int t = 0; t < 1024; ++t){
      // poll h1[t] ready (available early due to ring slack)
      if (w == 0 && lane < 32)
        poll_ge(pflagL0 + gi * 32 + lane, (unsigned)(t + 1));
      __syncthreads();

      i32x4 Gha[6], Ghb[6];
      #pragma unroll
      for (int k = 0; k < 6; ++k){ Gha[k]=z; Ghb[k]=z; }
      {
        const size_t sb = ((size_t)(t & 7) << 16) + gbase;
        stage_half(h1p, sb, 0, sbuf, tid);
        __syncthreads();
        compute_half(wp, rowb, 0, 0, sbuf, l15, l4, Gha, Ghb);
        __syncthreads();
        stage_half(h1p, sb, 1, sbuf, tid);
        __syncthreads();
        compute_half(wp, rowb, 0, 4, sbuf, l15, l4, Gha, Ghb);
        __syncthreads();
      }

      // poll peers' h2[t-1] (the true recurrence dependency)
      if (t > 0){
        if (w == 0 && lane < 32)
          poll_ge(pflagH2 + gi * 32 + lane, (unsigned)t);
        __syncthreads();
        const size_t sb = ((size_t)((t - 1) & 3) << 16) + gbase;
        stage_half(h2p, sb, 0, sbuf, tid);
        __syncthreads();
        compute_half(wp, rowb, 8, 0, sbuf, l15, l4, Gha, Ghb);
        __syncthreads();
        stage_half(h2p, sb, 1, sbuf, tid);
        __syncthreads();
        compute_half(wp, rowb, 8, 4, sbuf, l15, l4, Gha, Ghb);
      }

      const size_t rb = (size_t)(t & 3) << 16;
      #pragma unroll
      for (int mt = 0; mt < 2; ++mt){
        i32x4* Gh = mt ? Ghb : Gha;
        double g[4];
        #pragma unroll
        for (int q = 0; q < 4; ++q){
          double s = bsd[q];
          #pragma unroll
          for (int k = 0; k < 6; ++k) s += (double)Gh[k][q] * SH_[k];
          g[q] = s;
        }
        double& cs = mt ? c1 : c0;
        cs = sigd(g[1]) * cs + sigd(g[0]) * tanh(g[2]);
        double hv = sigd(g[3]) * tanh(cs);
        size_t o = rb + (mt ? ringmt1 : ringmt0) + hid;
        char v1c, v2c, v3c, v4c, v5c;
        hsplit5(hv, &v1c, &v2c, &v3c, &v4c, &v5c);
        st1(h2p[0] + o, v1c); st1(h2p[1] + o, v2c); st1(h2p[2] + o, v3c);
        st1(h2p[3] + o, v4c); st1(h2p[4] + o, v5c);
        // attention-facing: f16 hi + RELATIVE i8 residual (units of ulp(hh)/256)
        float hf = (float)hv;
        _Float16 hh = (_Float16)hf;
        float rs = hf - (float)hh;                    // exact in f32
        union { _Float16 h; unsigned short u; } cb; cb.h = hh;
        int E = (cb.u >> 10) & 31; if (E < 1) E = 1;
        int qr = (int)rintf(ldexpf(rs, 33 - E));
        qr = qr < -127 ? -127 : (qr > 127 ? 127 : qr);
        size_t pb = ((size_t)(mt ? b1 : b0) * 1024 + t) * 512 + hid;
        h2h[pb] = hh;                 // normal cached store (kernel-end flush)
        h2l8[pb] = (char)qr;
      }

      drain_vm();
      __syncthreads();
      if (tid == 0) st_flag(pflagH2 + wgl, (unsigned)(t + 1));
    }
  }
}

// ---------------- attention energies: exact integer GEMM + f64 epilogue ----------------
__global__ __launch_bounds__(256) void k_att_e(
    const _Float16* __restrict__ h2, const char* __restrict__ h2l8,
    const char* __restrict__ wa1, const char* __restrict__ wa2,
    const char* __restrict__ wa3, const char* __restrict__ wa4,
    const float* __restrict__ b_a, const float* __restrict__ v_a,
    const float* __restrict__ b_v, double* __restrict__ e)
{
  __shared__ char Ap[4][32][528];
  __shared__ char Wp[2][4][16][528];
  __shared__ double partial[2][32];
  const int tid  = threadIdx.x;
  const int w    = tid >> 6;
  const int mt   = w & 1;
  const int nh   = w >> 1;
  const int lane = tid & 63;
  const int l15  = lane & 15;
  const int l4   = lane >> 4;
  const size_t rid0 = (size_t)blockIdx.x * 32;

  // stage h: reconstruct exact f32 from f16 + rel-i8, split into 4 i8 planes
  for (int i = tid; i < 2048; i += 256){
    int row = i >> 6, c8 = (i & 63) << 3;
    const _Float16* hp = h2 + (rid0 + row) * 512 + c8;
    const char*     rp = h2l8 + (rid0 + row) * 512 + c8;
    unsigned long long o1 = 0, o2 = 0, o3 = 0, o4 = 0;
    #pragma unroll
    for (int q = 0; q < 8; ++q){
      union { _Float16 h; unsigned short u; } cb; cb.h = hp[q];
      int E = (cb.u >> 10) & 31; if (E < 1) E = 1;
      float h = (float)cb.h + ldexpf((float)rp[q], E - 33);
      float q1 = rintf(h * 64.f);     float r1 = fmaf(q1, -0x1p-6f, h);
      float q2 = rintf(r1 * 0x1p13f); float r2 = fmaf(q2, -0x1p-13f, r1);
      float q3 = rintf(r2 * 0x1p20f); float r3 = fmaf(q3, -0x1p-20f, r2);
      float q4 = rintf(r3 * 0x1p27f);
      o1 |= ((unsigned long long)(unsigned char)(char)(int)q1) << (8 * q);
      o2 |= ((unsigned long long)(unsigned char)(char)(int)q2) << (8 * q);
      o3 |= ((unsigned long long)(unsigned char)(char)(int)q3) << (8 * q);
      o4 |= ((unsigned long long)(unsigned char)(char)(int)q4) << (8 * q);
    }
    *(unsigned long long*)&Ap[0][row][c8] = o1;
    *(unsigned long long*)&Ap[1][row][c8] = o2;
    *(unsigned long long*)&Ap[2][row][c8] = o3;
    *(unsigned long long*)&Ap[3][row][c8] = o4;
  }
  __syncthreads();

  const int sh = tid >> 7;         // staging half (0: nh0, 1: nh1)
  const int st = tid & 127;
  double ep0 = 0.0, ep1 = 0.0, ep2 = 0.0, ep3 = 0.0;
  for (int it = 0; it < 16; ++it){
    if (it) __syncthreads();
    {
      int nt = sh * 16 + it;
      for (int i = st; i < 512; i += 128){
        int row = (i >> 5) & 15, c16 = (i & 31) << 4;
        size_t go = (size_t)(nt * 16 + row) * 512 + c16;
        *(i32x4*)&Wp[sh][0][row][c16] = *(const i32x4*)(wa1 + go);
        *(i32x4*)&Wp[sh][1][row][c16] = *(const i32x4*)(wa2 + go);
        *(i32x4*)&Wp[sh][2][row][c16] = *(const i32x4*)(wa3 + go);
        *(i32x4*)&Wp[sh][3][row][c16] = *(const i32x4*)(wa4 + go);
      }
    }
    __syncthreads();
    i32x4 G0={0,0,0,0},G1={0,0,0,0},G2={0,0,0,0},G3={0,0,0,0},G4={0,0,0,0},G5={0,0,0,0};
    #pragma unroll
    for (int c = 0; c < 8; ++c){
      int ko = c * 64 + l4 * 16;
      i32x4 A1 = *(const i32x4*)&Ap[0][mt * 16 + l15][ko];
      i32x4 A2 = *(const i32x4*)&Ap[1][mt * 16 + l15][ko];
      i32x4 A3 = *(const i32x4*)&Ap[2][mt * 16 + l15][ko];
      i32x4 A4 = *(const i32x4*)&Ap[3][mt * 16 + l15][ko];
      i32x4 B1 = *(const i32x4*)&Wp[nh][0][l15][ko];
      i32x4 B2 = *(const i32x4*)&Wp[nh][1][l15][ko];
      i32x4 B3 = *(const i32x4*)&Wp[nh][2][l15][ko];
      i32x4 B4 = *(const i32x4*)&Wp[nh][3][l15][ko];
      G0 = mfma8i(A1, B1, G0);
      G1 = mfma8i(A1, B2, G1); G1 = mfma8i(A2, B1, G1);
      G2 = mfma8i(A1, B3, G2); G2 = mfma8i(A2, B2, G2); G2 = mfma8i(A3, B1, G2);
      G3 = mfma8i(A1, B4, G3); G3 = mfma8i(A2, B3, G3); G3 = mfma8i(A3, B2, G3); G3 = mfma8i(A4, B1, G3);
      G4 = mfma8i(A2, B4, G4); G4 = mfma8i(A3, B3, G4); G4 = mfma8i(A4, B2, G4);
      G5 = mfma8i(A3, B4, G5); G5 = mfma8i(A4, B3, G5);
    }
    int n = (nh * 16 + it) * 16 + l15;
    double ban = (double)b_a[n], van = (double)v_a[n];
    #pragma unroll
    for (int q = 0; q < 4; ++q){
      double val = (double)G0[q]*SH_[0] + (double)G1[q]*SH_[1] + (double)G2[q]*SH_[2]
                 + (double)G3[q]*SH_[3] + (double)G4[q]*SH_[4] + (double)G5[q]*SH_[5] + ban;
      double tv = tanh(val) * van;
      if (q == 0) ep0 += tv; else if (q == 1) ep1 += tv;
      else if (q == 2) ep2 += tv; else ep3 += tv;
    }
  }
  #pragma unroll
  for (int m = 1; m < 16; m <<= 1){
    ep0 += __shfl_xor(ep0, m); ep1 += __shfl_xor(ep1, m);
    ep2 += __shfl_xor(ep2, m); ep3 += __shfl_xor(ep3, m);
  }
  if (l15 == 0){
    int rbase = mt * 16 + l4 * 4;
    partial[nh][rbase + 0] = ep0;
    partial[nh][rbase + 1] = ep1;
    partial[nh][rbase + 2] = ep2;
    partial[nh][rbase + 3] = ep3;
  }
  __syncthreads();
  if (tid < 32)
    e[rid0 + tid] = partial[0][tid] + partial[1][tid] + (double)b_v[0];
}

// ---------------- entmax15 (f64) + context + FC ----------------
__global__ __launch_bounds__(256) void k_entmax(
    const double* __restrict__ e, const _Float16* __restrict__ h2,
    const float* __restrict__ fcW, const float* __restrict__ fcb,
    float* __restrict__ out)
{
  __shared__ double xu[1024], sbd[1024], t0d[1024], t1d[1024];
  __shared__ float sbf[1024];
  __shared__ float red4[4];
  __shared__ double redd[4];
  __shared__ double scald;
  const int tid  = threadIdx.x;
  const int b    = blockIdx.x;
  const int wv   = tid >> 6;
  const int lane = tid & 63;

  double lm = -1e300;
  for (int i = tid; i < 1024; i += 256){
    double v = e[b * 1024 + i];
    xu[i] = v;
    lm = fmax(lm, v);
  }
  for (int m = 32; m >= 1; m >>= 1) lm = fmax(lm, __shfl_xor(lm, m));
  if (lane == 0) redd[wv] = lm;
  __syncthreads();
  double rowmax = fmax(fmax(redd[0], redd[1]), fmax(redd[2], redd[3]));
  __syncthreads();
  for (int i = tid; i < 1024; i += 256){
    double v = xu[i] - rowmax;
    xu[i] = v; sbd[i] = v;
  }
  __syncthreads();

  // bitonic ascending sort (f64)
  for (int ksz = 2; ksz <= 1024; ksz <<= 1){
    for (int jj = ksz >> 1; jj > 0; jj >>= 1){
      for (int i = tid; i < 1024; i += 256){
        int ixj = i ^ jj;
        if (ixj > i){
          double a = sbd[i], c = sbd[ixj];
          if (((i & ksz) == 0) ? (a > c) : (a < c)){ sbd[i] = c; sbd[ixj] = a; }
        }
      }
      __syncthreads();
    }
  }

  // descending view; inclusive scan (f64)
  for (int i = tid; i < 1024; i += 256) t0d[i] = sbd[1023 - i];
  __syncthreads();
  double* src = t0d; double* dst = t1d;
  for (int off = 1; off < 1024; off <<= 1){
    for (int i = tid; i < 1024; i += 256)
      dst[i] = src[i] + ((i >= off) ? src[i - off] : 0.0);
    __syncthreads();
    double* tmp = src; src = dst; dst = tmp;
  }

  float lc = 0.f;
  for (int i = tid; i < 1024; i += 256){
    double xs_i = sbd[1023 - i];
    double sup = (double)(i + 1) * xs_i - src[i] + 0.5;
    if (sup > 0.0) lc += 1.f;
  }
  for (int m = 32; m >= 1; m >>= 1) lc += __shfl_xor(lc, m);
  if (lane == 0) red4[wv] = lc;
  __syncthreads();
  if (tid == 0){
    int cntS = (int)(red4[0] + red4[1] + red4[2] + red4[3] + 0.5f);
    int ss = cntS < 1 ? 1 : (cntS > 1023 ? 1023 : cntS);
    double xss = sbd[1023 - ss];
    scald = ((double)(ss + 1) * xss - src[ss] + 0.5) / (double)(ss + 1);
  }
  __syncthreads();
  double tau = scald;

  double ls = 0.0;
  for (int i = tid; i < 1024; i += 256){
    double d = xu[i] - tau;
    double y = (d > 0.0) ? sqrt(d) : 0.0;
    dst[i] = y;
    ls += y;
  }
  for (int m = 32; m >= 1; m >>= 1) ls += __shfl_xor(ls, m);
  if (lane == 0) redd[wv] = ls;
  __syncthreads();
  double Z = redd[0] + redd[1] + redd[2] + redd[3];
  __syncthreads();
  for (int i = tid; i < 1024; i += 256){
    float a = (float)(dst[i] / Z);
    sbf[i] = a;
    out[128 + b * 1024 + i] = a;
  }
  __syncthreads();

  // context over nonzero weights + FC (O=1)
  const int h0 = tid * 2;
  float cx0 = 0.f, cx1 = 0.f;
  for (int s = 0; s < 1024; ++s){
    float wt = sbf[s];
    if (wt > 0.f){
      unsigned int u = *(const unsigned int*)(h2 + ((size_t)b * 1024 + s) * 512 + h0);
      union { unsigned int u; _Float16 h[2]; } cv; cv.u = u;
      cx0 += wt * (float)cv.h[0];
      cx1 += wt * (float)cv.h[1];
    }
  }
  float p = fcW[h0] * cx0 + fcW[h0 + 1] * cx1;
  for (int m = 32; m >= 1; m >>= 1) p += __shfl_xor(p, m);
  if (lane == 0) red4[wv] = p;
  __syncthreads();
  if (tid == 0) out[b] = red4[0] + red4[1] + red4[2] + red4[3] + fcb[0];
}

// ---------------- host launch ----------------
extern "C" void kernel_launch(void* const* d_in, const int* in_sizes, int n_in,
                              void* d_out, int out_size, void* d_ws, size_t ws_size,
                              hipStream_t stream)
{
  (void)in_sizes; (void)n_in; (void)out_size;
  const float* x    = (const float*)d_in[0];
  const float* Wih0 = (const float*)d_in[1];
  const float* Whh0 = (const float*)d_in[2];
  const float* bih0 = (const float*)d_in[3];
  const float* bhh0 = (const float*)d_in[4];
  const float* Wih1 = (const float*)d_in[5];
  const float* Whh1 = (const float*)d_in[6];
  const float* bih1 = (const float*)d_in[7];
  const float* bhh1 = (const float*)d_in[8];
  const float* Wa   = (const float*)d_in[9];
  const float* ba   = (const float*)d_in[10];
  const float* va   = (const float*)d_in[11];
  const float* bv   = (const float*)d_in[12];
  const float* fcW  = (const float*)d_in[13];
  const float* fcb  = (const float*)d_in[14];

  const size_t NEED = 223773696ull;
  if (ws_size < NEED) return;

  char* ws = (char*)d_ws;
  unsigned int* cnt = (unsigned int*)(ws);                  // 1 KiB (256 flags)
  char* w0p[5]; for (int p = 0; p < 5; ++p) w0p[p] = ws + 1024ull + (size_t)p * 1179648ull;
  double* bias0 = (double*)(ws + 5899264ull);               // 16,384
  char* w1p[5]; for (int p = 0; p < 5; ++p) w1p[p] = ws + 5915648ull + (size_t)p * 2097152ull;
  double* bias1 = (double*)(ws + 16401408ull);              // 16,384
  char* wa1 = ws + 16417792ull;                             // 4 x 262,144
  char* wa2 = wa1 + 262144ull;
  char* wa3 = wa2 + 262144ull;
  char* wa4 = wa3 + 262144ull;
  char* h1p[5]; for (int p = 0; p < 5; ++p) h1p[p] = ws + 17466368ull + (size_t)p * 524288ull;  // 8 slots
  char* h2p[5]; for (int p = 0; p < 5; ++p) h2p[p] = ws + 20087808ull + (size_t)p * 262144ull;  // 4 slots
  double* ebuf = (double*)(ws + 21398528ull);               // 1,048,576
  _Float16* h2h = (_Float16*)(ws + 22447104ull);            // 134,217,728
  char* h2l8 = ws + 156664832ull;                           // 67,108,864
  float* out = (float*)d_out;

  k_prep_zero<<<1, 256, 0, stream>>>(cnt);
  k_prep_w0<<<4608, 256, 0, stream>>>(Wih0, Whh0, w0p[0], w0p[1], w0p[2], w0p[3], w0p[4]);
  k_prep_w1<<<8192, 256, 0, stream>>>(Wih1, Whh1, w1p[0], w1p[1], w1p[2], w1p[3], w1p[4]);
  k_prep_b<<<16, 256, 0, stream>>>(bih0, bhh0, bih1, bhh1, bias0, bias1);
  k_prep_wa<<<1024, 256, 0, stream>>>(Wa, wa1, wa2, wa3, wa4);
  k_lstm_fused<<<256, 256, 0, stream>>>(x,
      w0p[0], w0p[1], w0p[2], w0p[3], w0p[4], bias0,
      w1p[0], w1p[1], w1p[2], w1p[3], w1p[4], bias1,
      h1p[0], h1p[1], h1p[2], h1p[3], h1p[4],
      h2p[0], h2p[1], h2p[2], h2p[3], h2p[4],
      h2h, h2l8, cnt);
  k_att_e<<<4096, 256, 0, stream>>>(h2h, h2l8, wa1, wa2, wa3, wa4, ba, va, bv, ebuf);
  k_entmax<<<128, 256, 0, stream>>>(ebuf, h2h, fcW, fcb, out);
}

// Round 16
// 19412.231 us; speedup vs baseline: 3.9602x; 1.1144x over previous
//
#include <hip/hip_runtime.h>

typedef __attribute__((ext_vector_type(8))) _Float16 half8;
typedef __attribute__((ext_vector_type(4))) float f32x4;
typedef __attribute__((ext_vector_type(4))) int   i32x4;

#define DEV static __device__ __forceinline__

DEV i32x4 mfma8i(i32x4 a, i32x4 b, i32x4 c){
  return __builtin_amdgcn_mfma_i32_16x16x64_i8(a, b, c, 0, 0, 0);
}
// MALL-bypass primitives (sc0 sc1: skip L1+L2)
DEV void ld4(i32x4& d, const char* p){
  asm volatile("global_load_dwordx4 %0, %1, off sc0 sc1" : "=v"(d) : "v"(p));
}
DEV void st1(char* p, int v){
  asm volatile("global_store_byte %0, %1, off sc0 sc1" :: "v"(p), "v"(v) : "memory");
}
DEV void st_flag(unsigned int* p, unsigned int v){
  asm volatile("s_waitcnt vmcnt(0)" ::: "memory");
  asm volatile("global_store_dword %0, %1, off sc0 sc1" :: "v"(p), "v"(v) : "memory");
}
DEV void drain_vm(){ asm volatile("s_waitcnt vmcnt(0)" ::: "memory"); }
DEV void poll_ge(unsigned int* fp, unsigned int tgt){
  for (;;){
    unsigned int v = __hip_atomic_load(fp, __ATOMIC_RELAXED, __HIP_MEMORY_SCOPE_AGENT);
    if (__all(v >= tgt)) break;
    __builtin_amdgcn_s_sleep(1);
  }
}

// W5 x H5 plane products grouped by scale d=i+j (d=2..7)
DEV void str_h(const i32x4* W, const i32x4* B, i32x4* G){
  G[0]=mfma8i(W[0],B[0],G[0]);
  G[1]=mfma8i(W[0],B[1],G[1]); G[1]=mfma8i(W[1],B[0],G[1]);
  G[2]=mfma8i(W[0],B[2],G[2]); G[2]=mfma8i(W[1],B[1],G[2]); G[2]=mfma8i(W[2],B[0],G[2]);
  G[3]=mfma8i(W[0],B[3],G[3]); G[3]=mfma8i(W[1],B[2],G[3]); G[3]=mfma8i(W[2],B[1],G[3]); G[3]=mfma8i(W[3],B[0],G[3]);
  G[4]=mfma8i(W[0],B[4],G[4]); G[4]=mfma8i(W[1],B[3],G[4]); G[4]=mfma8i(W[2],B[2],G[4]); G[4]=mfma8i(W[3],B[1],G[4]); G[4]=mfma8i(W[4],B[0],G[4]);
  G[5]=mfma8i(W[1],B[4],G[5]); G[5]=mfma8i(W[2],B[3],G[5]); G[5]=mfma8i(W[3],B[2],G[5]); G[5]=mfma8i(W[4],B[1],G[5]);
}
// W5 x X6 plane products grouped by scale (d=2..7)
DEV void str_x(const i32x4* W, const i32x4* X, i32x4* G){
  G[0]=mfma8i(W[0],X[0],G[0]);
  G[1]=mfma8i(W[0],X[1],G[1]); G[1]=mfma8i(W[1],X[0],G[1]);
  G[2]=mfma8i(W[0],X[2],G[2]); G[2]=mfma8i(W[1],X[1],G[2]); G[2]=mfma8i(W[2],X[0],G[2]);
  G[3]=mfma8i(W[0],X[3],G[3]); G[3]=mfma8i(W[1],X[2],G[3]); G[3]=mfma8i(W[2],X[1],G[3]); G[3]=mfma8i(W[3],X[0],G[3]);
  G[4]=mfma8i(W[0],X[4],G[4]); G[4]=mfma8i(W[1],X[3],G[4]); G[4]=mfma8i(W[2],X[2],G[4]); G[4]=mfma8i(W[3],X[1],G[4]); G[4]=mfma8i(W[4],X[0],G[4]);
  G[5]=mfma8i(W[0],X[5],G[5]); G[5]=mfma8i(W[1],X[4],G[5]); G[5]=mfma8i(W[2],X[3],G[5]); G[5]=mfma8i(W[3],X[2],G[5]); G[5]=mfma8i(W[4],X[1],G[5]);
}

#define SEG_STRIDE 4352   // 16 rows x 272B per (plane,tile,half) segment
#define NSEG 20
#define LDS_BYTES  (NSEG * SEG_STRIDE)

// Full-phase stage: 80KB (20 segs) MALL -> regs (one exposure).
// u = plane*4 + tile*2 + half
DEV void stage_issue(char* const* hp, size_t tbase, i32x4* v, int tid){
  const int row = tid >> 4;
  const int off = (tid & 15) * 16;
  #pragma unroll
  for (int u = 0; u < NSEG; ++u){
    int plane = u >> 2, tile = (u >> 1) & 1, half = u & 1;
    ld4(v[u], hp[plane] + tbase + (size_t)(tile * 16 + row) * 512 + (size_t)half * 256 + off);
  }
}
DEV void stage_write(const i32x4* v, char* lds, int tid){
  const int row = tid >> 4;
  const int off = (tid & 15) * 16;
  #pragma unroll
  for (int u = 0; u < NSEG; ++u)
    *(i32x4*)(lds + u * SEG_STRIDE + row * 272 + off) = v[u];
}

// Compute full phase (8 chunks) from LDS; W streamed from L2 per chunk.
DEV void compute_full(const char* const* wp, size_t rowb, int wofs,
                      const char* lds, int l15, int l4, i32x4* Ga, i32x4* Gb){
  #pragma unroll
  for (int c = 0; c < 8; ++c){
    const int half = c >> 2, cc = c & 3;
    i32x4 Wc[5], Ba[5], Bb[5];
    #pragma unroll
    for (int p = 0; p < 5; ++p)
      Wc[p] = *(const i32x4*)(wp[p] + rowb + (size_t)(wofs + c) * 64 + l4 * 16);
    #pragma unroll
    for (int p = 0; p < 5; ++p){
      Ba[p] = *(const i32x4*)(lds + (p * 4 + 0 + half) * SEG_STRIDE + l15 * 272 + cc * 64 + l4 * 16);
      Bb[p] = *(const i32x4*)(lds + (p * 4 + 2 + half) * SEG_STRIDE + l15 * 272 + cc * 64 + l4 * 16);
    }
    str_h(Wc, Ba, Ga);
    str_h(Wc, Bb, Gb);
  }
}

// ---------------- prep ----------------
__global__ void k_prep_zero(unsigned int* cnt){
  cnt[threadIdx.x] = 0u;    // 256 flags
}

// W planes: W = p1*2^-11 + ... + p5*2^-39 (trunc 2^-40)
DEV void wsplit5(float v, char* o1, char* o2, char* o3, char* o4, char* o5){
  float q1 = rintf(v * 0x1p11f);
  float r1 = fmaf(q1, -0x1p-11f, v);
  float q2 = rintf(r1 * 0x1p18f);
  float r2 = fmaf(q2, -0x1p-18f, r1);
  float q3 = rintf(r2 * 0x1p25f);
  float r3 = fmaf(q3, -0x1p-25f, r2);
  float q4 = rintf(r3 * 0x1p32f);
  float r4 = fmaf(q4, -0x1p-32f, r3);
  float q5 = rintf(r4 * 0x1p39f);
  *o1=(char)(int)q1; *o2=(char)(int)q2; *o3=(char)(int)q3;
  *o4=(char)(int)q4; *o5=(char)(int)q5;
}

__global__ void k_prep_w0(const float* __restrict__ Wih0, const float* __restrict__ Whh0,
                          char* __restrict__ p1, char* __restrict__ p2, char* __restrict__ p3,
                          char* __restrict__ p4, char* __restrict__ p5){
  int idx = blockIdx.x * 256 + threadIdx.x;      // 1179648
  int k = idx % 576;
  int r = (idx / 576) & 63;
  int j = idx / 36864;
  int R = (r & 3) * 512 + j * 16 + (r >> 2);
  float v = (k < 512) ? Whh0[(size_t)R * 512 + k] : Wih0[(size_t)R * 64 + (k - 512)];
  wsplit5(v, p1 + idx, p2 + idx, p3 + idx, p4 + idx, p5 + idx);
}

__global__ void k_prep_w1(const float* __restrict__ Wih1, const float* __restrict__ Whh1,
                          char* __restrict__ p1, char* __restrict__ p2, char* __restrict__ p3,
                          char* __restrict__ p4, char* __restrict__ p5){
  int idx = blockIdx.x * 256 + threadIdx.x;      // 2097152
  int k = idx & 1023;
  int r = (idx >> 10) & 63;
  int j = idx >> 16;
  int R = (r & 3) * 512 + j * 16 + (r >> 2);
  float v = (k < 512) ? Wih1[(size_t)R * 512 + k] : Whh1[(size_t)R * 512 + (k - 512)];
  wsplit5(v, p1 + idx, p2 + idx, p3 + idx, p4 + idx, p5 + idx);
}

__global__ void k_prep_b(const float* __restrict__ bih0, const float* __restrict__ bhh0,
                         const float* __restrict__ bih1, const float* __restrict__ bhh1,
                         double* __restrict__ bias0, double* __restrict__ bias1){
  int idx = blockIdx.x * 256 + threadIdx.x;      // 4096
  int i2 = idx & 2047;
  int j = i2 >> 6, r = i2 & 63;
  int R = (r & 3) * 512 + j * 16 + (r >> 2);
  if (idx < 2048) bias0[i2] = (double)bih0[R] + (double)bhh0[R];
  else            bias1[i2] = (double)bih1[R] + (double)bhh1[R];
}

// W_a -> 4 i8 planes (2^-11,-18,-25,-32; residual <= 2^-33)
__global__ void k_prep_wa(const float* __restrict__ Wa,
                          char* __restrict__ p1, char* __restrict__ p2,
                          char* __restrict__ p3, char* __restrict__ p4){
  int idx = blockIdx.x * 256 + threadIdx.x;      // 262144
  float v = Wa[idx];
  float q1 = rintf(v * 0x1p11f);
  float r1 = fmaf(q1, -0x1p-11f, v);
  float q2 = rintf(r1 * 0x1p18f);
  float r2 = fmaf(q2, -0x1p-18f, r1);
  float q3 = rintf(r2 * 0x1p25f);
  float r3 = fmaf(q3, -0x1p-25f, r2);
  float q4 = rintf(r3 * 0x1p32f);
  p1[idx]=(char)(int)q1; p2[idx]=(char)(int)q2;
  p3[idx]=(char)(int)q3; p4[idx]=(char)(int)q4;
}

// h split from f64: 5 planes at 2^-6,-13,-20,-27,-34 (trunc 2^-35)
DEV void hsplit5(double hd, char* o1, char* o2, char* o3, char* o4, char* o5){
  double q1 = rint(hd * 64.0);
  double r1 = hd - q1 * 0x1p-6;
  double q2 = rint(r1 * 0x1p13);
  double r2 = r1 - q2 * 0x1p-13;
  double q3 = rint(r2 * 0x1p20);
  double r3 = r2 - q3 * 0x1p-20;
  double q4 = rint(r3 * 0x1p27);
  double r4 = r3 - q4 * 0x1p-27;
  double q5 = rint(r4 * 0x1p34);
  *o1=(char)(int)q1; *o2=(char)(int)q2; *o3=(char)(int)q3;
  *o4=(char)(int)q4; *o5=(char)(int)q5;
}

DEV double sigd(double xv){ return 1.0 / (1.0 + exp(-xv)); }

// group scales
__constant__ double SH_[6] = {0x1p-17, 0x1p-24, 0x1p-31, 0x1p-38, 0x1p-45, 0x1p-52};
__constant__ double SX_[6] = {0x1p-13, 0x1p-20, 0x1p-27, 0x1p-34, 0x1p-41, 0x1p-48};

// ---------------- fused persistent 2-layer LSTM (exact-integer GEMM, f64 cell) ----------
__global__ __launch_bounds__(256, 1) void k_lstm_fused(
    const float* __restrict__ x,
    const char* w0p1, const char* w0p2, const char* w0p3, const char* w0p4, const char* w0p5,
    const double* __restrict__ bias0,
    const char* w1p1, const char* w1p2, const char* w1p3, const char* w1p4, const char* w1p5,
    const double* __restrict__ bias1,
    char* h1a, char* h1b, char* h1c, char* h1d, char* h1e,
    char* h2a, char* h2b, char* h2c, char* h2d, char* h2e,
    _Float16* __restrict__ h2h, char* __restrict__ h2l8,
    unsigned int* __restrict__ cnt)
{
  __shared__ char sbuf[LDS_BYTES];
  const int wg   = blockIdx.x;
  const int tid  = threadIdx.x;
  const int w    = tid >> 6;
  const int lane = tid & 63;
  const int l15  = lane & 15;
  const int l4   = lane >> 4;
  unsigned int* pflagL0 = cnt;          // [128]
  unsigned int* pflagH2 = cnt + 128;    // [128]

  const int isL1 = wg >= 128;
  const int wgl  = isL1 ? wg - 128 : wg;
  const int gi   = wgl >> 5;
  const int j    = wgl & 31;
  const int r0   = w * 16 + l15;
  const int b0   = gi * 32 + l15;
  const int b1   = b0 + 16;
  const int hid  = j * 16 + w * 4 + l4;
  const size_t ringmt0 = (size_t)b0 * 512;
  const size_t ringmt1 = (size_t)b1 * 512;
  const size_t gbase   = (size_t)(gi * 32) * 512;   // group batch base

  char* h1p[5] = {h1a, h1b, h1c, h1d, h1e};
  char* h2p[5] = {h2a, h2b, h2c, h2d, h2e};
  const i32x4 z = {0,0,0,0};

  if (!isL1){
    // ---------- layer 0 ----------
    const char* wp[5] = {w0p1, w0p2, w0p3, w0p4, w0p5};
    const size_t rowb = ((size_t)j * 64 + r0) * 576;
    i32x4 WX[5];    // x-block W chunk (loop-invariant, resident)
    #pragma unroll
    for (int p = 0; p < 5; ++p)
      WX[p] = *(const i32x4*)(wp[p] + rowb + 8 * 64 + l4 * 16);
    double bsd[4];
    #pragma unroll
    for (int q = 0; q < 4; ++q) bsd[q] = bias0[j * 64 + w * 16 + l4 * 4 + q];
    double c0 = 0.0, c1 = 0.0;

    for (int t = 0; t < 1024; ++t){
      i32x4 XA[6], XB[6];
      {
        #pragma unroll
        for (int mt = 0; mt < 2; ++mt){
          const float* xr = x + ((size_t)(mt ? b1 : b0) * 1024 + t) * 64 + l4 * 16;
          unsigned int a[6][4] = {{0,0,0,0},{0,0,0,0},{0,0,0,0},{0,0,0,0},{0,0,0,0},{0,0,0,0}};
          #pragma unroll
          for (int i = 0; i < 16; ++i){
            float v = xr[i];
            float q1 = rintf(v * 4.0f);
            float r1 = fmaf(q1, -0.25f, v);
            float q2 = rintf(r1 * 0x1p9f);
            float r2 = fmaf(q2, -0x1p-9f, r1);
            float q3 = rintf(r2 * 0x1p16f);
            float r3 = fmaf(q3, -0x1p-16f, r2);
            float q4 = rintf(r3 * 0x1p23f);
            float r4 = fmaf(q4, -0x1p-23f, r3);
            float q5 = rintf(r4 * 0x1p30f);
            float r5 = fmaf(q5, -0x1p-30f, r4);
            float q6 = rintf(r5 * 0x1p37f);
            int wi = i >> 2, sh = (i & 3) * 8;
            a[0][wi] |= ((unsigned)(unsigned char)(char)(int)q1) << sh;
            a[1][wi] |= ((unsigned)(unsigned char)(char)(int)q2) << sh;
            a[2][wi] |= ((unsigned)(unsigned char)(char)(int)q3) << sh;
            a[3][wi] |= ((unsigned)(unsigned char)(char)(int)q4) << sh;
            a[4][wi] |= ((unsigned)(unsigned char)(char)(int)q5) << sh;
            a[5][wi] |= ((unsigned)(unsigned char)(char)(int)q6) << sh;
          }
          i32x4* X = mt ? XB : XA;
          #pragma unroll
          for (int p = 0; p < 6; ++p)
            X[p] = i32x4{(int)a[p][0], (int)a[p][1], (int)a[p][2], (int)a[p][3]};
        }
      }
      i32x4 Gha[6], Ghb[6], Gxa[6], Gxb[6];
      #pragma unroll
      for (int k = 0; k < 6; ++k){ Gha[k]=z; Ghb[k]=z; Gxa[k]=z; Gxb[k]=z; }
      str_x(WX, XA, Gxa);
      str_x(WX, XB, Gxb);

      // merged poll (wave0): lanes<32 peers' h1[t-1]; lanes>=32 L1 backpressure
      if (w == 0){
        unsigned int* fp = (lane < 32) ? (pflagL0 + gi * 32 + lane)
                                       : (pflagH2 + gi * 32 + (lane - 32));
        unsigned int tgt = (lane < 32) ? (unsigned)t
                          : ((t >= 8) ? (unsigned)(t - 7) : 0u);
        poll_ge(fp, tgt);
      }
      __syncthreads();

      if (t > 0){
        i32x4 A[NSEG];
        const size_t sb = ((size_t)((t - 1) & 7) << 16) + gbase;
        stage_issue(h1p, sb, A, tid);
        drain_vm();
        __builtin_amdgcn_sched_barrier(0);
        stage_write(A, sbuf, tid);
        __syncthreads();
        compute_full(wp, rowb, 0, sbuf, l15, l4, Gha, Ghb);
      }

      const size_t rb = (size_t)(t & 7) << 16;
      #pragma unroll
      for (int mt = 0; mt < 2; ++mt){
        i32x4* Gh = mt ? Ghb : Gha;
        i32x4* Gx = mt ? Gxb : Gxa;
        double g[4];
        #pragma unroll
        for (int q = 0; q < 4; ++q){
          double s = bsd[q];
          #pragma unroll
          for (int k = 0; k < 6; ++k)
            s += (double)Gh[k][q] * SH_[k] + (double)Gx[k][q] * SX_[k];
          g[q] = s;
        }
        double& cs = mt ? c1 : c0;
        cs = sigd(g[1]) * cs + sigd(g[0]) * tanh(g[2]);
        double hv = sigd(g[3]) * tanh(cs);
        size_t o = rb + (mt ? ringmt1 : ringmt0) + hid;
        char v1c, v2c, v3c, v4c, v5c;
        hsplit5(hv, &v1c, &v2c, &v3c, &v4c, &v5c);
        st1(h1p[0] + o, v1c); st1(h1p[1] + o, v2c); st1(h1p[2] + o, v3c);
        st1(h1p[3] + o, v4c); st1(h1p[4] + o, v5c);
      }

      drain_vm();
      __syncthreads();
      if (tid == 0) st_flag(pflagL0 + wgl, (unsigned)(t + 1));
    }
  } else {
    // ---------- layer 1 ----------
    const char* wp[5] = {w1p1, w1p2, w1p3, w1p4, w1p5};
    const size_t rowb = ((size_t)j * 64 + r0) * 1024;
    double bsd[4];
    #pragma unroll
    for (int q = 0; q < 4; ++q) bsd[q] = bias1[j * 64 + w * 16 + l4 * 4 + q];
    double c0 = 0.0, c1 = 0.0;

    for (int t = 0; t < 1024; ++t){
      // merged poll (wave0): lanes<32 h1[t] ready; lanes>=32 peers' h2[t-1]
      if (w == 0){
        unsigned int* fp = (lane < 32) ? (pflagL0 + gi * 32 + lane)
                                       : (pflagH2 + gi * 32 + (lane - 32));
        unsigned int tgt = (lane < 32) ? (unsigned)(t + 1)
                          : ((t > 0) ? (unsigned)t : 0u);
        poll_ge(fp, tgt);
      }
      __syncthreads();

      i32x4 Gha[6], Ghb[6];
      #pragma unroll
      for (int k = 0; k < 6; ++k){ Gha[k]=z; Ghb[k]=z; }

      i32x4 A[NSEG], Bv[NSEG];
      const size_t sbA = ((size_t)(t & 7) << 16) + gbase;
      stage_issue(h1p, sbA, A, tid);
      if (t > 0){
        const size_t sbB = ((size_t)((t - 1) & 3) << 16) + gbase;
        stage_issue(h2p, sbB, Bv, tid);
        asm volatile("s_waitcnt vmcnt(20)" ::: "memory");   // A complete; B in flight
      } else {
        drain_vm();
      }
      __builtin_amdgcn_sched_barrier(0);
      stage_write(A, sbuf, tid);
      __syncthreads();
      compute_full(wp, rowb, 0, sbuf, l15, l4, Gha, Ghb);   // h1 phase (B flying)
      __syncthreads();                                      // all waves done with h1 LDS

      if (t > 0){
        drain_vm();                                         // B complete
        __builtin_amdgcn_sched_barrier(0);
        stage_write(Bv, sbuf, tid);
        __syncthreads();
        compute_full(wp, rowb, 8, sbuf, l15, l4, Gha, Ghb); // h2 phase
      }

      const size_t rb = (size_t)(t & 3) << 16;
      #pragma unroll
      for (int mt = 0; mt < 2; ++mt){
        i32x4* Gh = mt ? Ghb : Gha;
        double g[4];
        #pragma unroll
        for (int q = 0; q < 4; ++q){
          double s = bsd[q];
          #pragma unroll
          for (int k = 0; k < 6; ++k) s += (double)Gh[k][q] * SH_[k];
          g[q] = s;
        }
        double& cs = mt ? c1 : c0;
        cs = sigd(g[1]) * cs + sigd(g[0]) * tanh(g[2]);
        double hv = sigd(g[3]) * tanh(cs);
        size_t o = rb + (mt ? ringmt1 : ringmt0) + hid;
        char v1c, v2c, v3c, v4c, v5c;
        hsplit5(hv, &v1c, &v2c, &v3c, &v4c, &v5c);
        st1(h2p[0] + o, v1c); st1(h2p[1] + o, v2c); st1(h2p[2] + o, v3c);
        st1(h2p[3] + o, v4c); st1(h2p[4] + o, v5c);
        // attention-facing: f16 hi + RELATIVE i8 residual (units of ulp(hh)/256)
        float hf = (float)hv;
        _Float16 hh = (_Float16)hf;
        float rs = hf - (float)hh;                    // exact in f32
        union { _Float16 h; unsigned short u; } cb; cb.h = hh;
        int E = (cb.u >> 10) & 31; if (E < 1) E = 1;
        int qr = (int)rintf(ldexpf(rs, 33 - E));
        qr = qr < -127 ? -127 : (qr > 127 ? 127 : qr);
        size_t pb = ((size_t)(mt ? b1 : b0) * 1024 + t) * 512 + hid;
        h2h[pb] = hh;                 // normal cached store (kernel-end flush)
        h2l8[pb] = (char)qr;
      }

      drain_vm();
      __syncthreads();
      if (tid == 0) st_flag(pflagH2 + wgl, (unsigned)(t + 1));
    }
  }
}

// ---------------- attention energies: exact integer GEMM + f64 epilogue ----------------
__global__ __launch_bounds__(256) void k_att_e(
    const _Float16* __restrict__ h2, const char* __restrict__ h2l8,
    const char* __restrict__ wa1, const char* __restrict__ wa2,
    const char* __restrict__ wa3, const char* __restrict__ wa4,
    const float* __restrict__ b_a, const float* __restrict__ v_a,
    const float* __restrict__ b_v, double* __restrict__ e)
{
  __shared__ char Ap[4][32][528];
  __shared__ char Wp[2][4][16][528];
  __shared__ double partial[2][32];
  const int tid  = threadIdx.x;
  const int w    = tid >> 6;
  const int mt   = w & 1;
  const int nh   = w >> 1;
  const int lane = tid & 63;
  const int l15  = lane & 15;
  const int l4   = lane >> 4;
  const size_t rid0 = (size_t)blockIdx.x * 32;

  // stage h: reconstruct exact f32 from f16 + rel-i8, split into 4 i8 planes
  for (int i = tid; i < 2048; i += 256){
    int row = i >> 6, c8 = (i & 63) << 3;
    const _Float16* hp = h2 + (rid0 + row) * 512 + c8;
    const char*     rp = h2l8 + (rid0 + row) * 512 + c8;
    unsigned long long o1 = 0, o2 = 0, o3 = 0, o4 = 0;
    #pragma unroll
    for (int q = 0; q < 8; ++q){
      union { _Float16 h; unsigned short u; } cb; cb.h = hp[q];
      int E = (cb.u >> 10) & 31; if (E < 1) E = 1;
      float h = (float)cb.h + ldexpf((float)rp[q], E - 33);
      float q1 = rintf(h * 64.f);     float r1 = fmaf(q1, -0x1p-6f, h);
      float q2 = rintf(r1 * 0x1p13f); float r2 = fmaf(q2, -0x1p-13f, r1);
      float q3 = rintf(r2 * 0x1p20f); float r3 = fmaf(q3, -0x1p-20f, r2);
      float q4 = rintf(r3 * 0x1p27f);
      o1 |= ((unsigned long long)(unsigned char)(char)(int)q1) << (8 * q);
      o2 |= ((unsigned long long)(unsigned char)(char)(int)q2) << (8 * q);
      o3 |= ((unsigned long long)(unsigned char)(char)(int)q3) << (8 * q);
      o4 |= ((unsigned long long)(unsigned char)(char)(int)q4) << (8 * q);
    }
    *(unsigned long long*)&Ap[0][row][c8] = o1;
    *(unsigned long long*)&Ap[1][row][c8] = o2;
    *(unsigned long long*)&Ap[2][row][c8] = o3;
    *(unsigned long long*)&Ap[3][row][c8] = o4;
  }
  __syncthreads();

  const int sh = tid >> 7;         // staging half (0: nh0, 1: nh1)
  const int st = tid & 127;
  double ep0 = 0.0, ep1 = 0.0, ep2 = 0.0, ep3 = 0.0;
  for (int it = 0; it < 16; ++it){
    if (it) __syncthreads();
    {
      int nt = sh * 16 + it;
      for (int i = st; i < 512; i += 128){
        int row = (i >> 5) & 15, c16 = (i & 31) << 4;
        size_t go = (size_t)(nt * 16 + row) * 512 + c16;
        *(i32x4*)&Wp[sh][0][row][c16] = *(const i32x4*)(wa1 + go);
        *(i32x4*)&Wp[sh][1][row][c16] = *(const i32x4*)(wa2 + go);
        *(i32x4*)&Wp[sh][2][row][c16] = *(const i32x4*)(wa3 + go);
        *(i32x4*)&Wp[sh][3][row][c16] = *(const i32x4*)(wa4 + go);
      }
    }
    __syncthreads();
    i32x4 G0={0,0,0,0},G1={0,0,0,0},G2={0,0,0,0},G3={0,0,0,0},G4={0,0,0,0},G5={0,0,0,0};
    #pragma unroll
    for (int c = 0; c < 8; ++c){
      int ko = c * 64 + l4 * 16;
      i32x4 A1 = *(const i32x4*)&Ap[0][mt * 16 + l15][ko];
      i32x4 A2 = *(const i32x4*)&Ap[1][mt * 16 + l15][ko];
      i32x4 A3 = *(const i32x4*)&Ap[2][mt * 16 + l15][ko];
      i32x4 A4 = *(const i32x4*)&Ap[3][mt * 16 + l15][ko];
      i32x4 B1 = *(const i32x4*)&Wp[nh][0][l15][ko];
      i32x4 B2 = *(const i32x4*)&Wp[nh][1][l15][ko];
      i32x4 B3 = *(const i32x4*)&Wp[nh][2][l15][ko];
      i32x4 B4 = *(const i32x4*)&Wp[nh][3][l15][ko];
      G0 = mfma8i(A1, B1, G0);
      G1 = mfma8i(A1, B2, G1); G1 = mfma8i(A2, B1, G1);
      G2 = mfma8i(A1, B3, G2); G2 = mfma8i(A2, B2, G2); G2 = mfma8i(A3, B1, G2);
      G3 = mfma8i(A1, B4, G3); G3 = mfma8i(A2, B3, G3); G3 = mfma8i(A3, B2, G3); G3 = mfma8i(A4, B1, G3);
      G4 = mfma8i(A2, B4, G4); G4 = mfma8i(A3, B3, G4); G4 = mfma8i(A4, B2, G4);
      G5 = mfma8i(A3, B4, G5); G5 = mfma8i(A4, B3, G5);
    }
    int n = (nh * 16 + it) * 16 + l15;
    double ban = (double)b_a[n], van = (double)v_a[n];
    #pragma unroll
    for (int q = 0; q < 4; ++q){
      double val = (double)G0[q]*SH_[0] + (double)G1[q]*SH_[1] + (double)G2[q]*SH_[2]
                 + (double)G3[q]*SH_[3] + (double)G4[q]*SH_[4] + (double)G5[q]*SH_[5] + ban;
      double tv = tanh(val) * van;
      if (q == 0) ep0 += tv; else if (q == 1) ep1 += tv;
      else if (q == 2) ep2 += tv; else ep3 += tv;
    }
  }
  #pragma unroll
  for (int m = 1; m < 16; m <<= 1){
    ep0 += __shfl_xor(ep0, m); ep1 += __shfl_xor(ep1, m);
    ep2 += __shfl_xor(ep2, m); ep3 += __shfl_xor(ep3, m);
  }
  if (l15 == 0){
    int rbase = mt * 16 + l4 * 4;
    partial[nh][rbase + 0] = ep0;
    partial[nh][rbase + 1] = ep1;
    partial[nh][rbase + 2] = ep2;
    partial[nh][rbase + 3] = ep3;
  }
  __syncthreads();
  if (tid < 32)
    e[rid0 + tid] = partial[0][tid] + partial[1][tid] + (double)b_v[0];
}

// ---------------- entmax15 (f64) + context + FC ----------------
__global__ __launch_bounds__(256) void k_entmax(
    const double* __restrict__ e, const _Float16* __restrict__ h2,
    const float* __restrict__ fcW, const float* __restrict__ fcb,
    float* __restrict__ out)
{
  __shared__ double xu[1024], sbd[1024], t0d[1024], t1d[1024];
  __shared__ float sbf[1024];
  __shared__ float red4[4];
  __shared__ double redd[4];
  __shared__ double scald;
  const int tid  = threadIdx.x;
  const int b    = blockIdx.x;
  const int wv   = tid >> 6;
  const int lane = tid & 63;

  double lm = -1e300;
  for (int i = tid; i < 1024; i += 256){
    double v = e[b * 1024 + i];
    xu[i] = v;
    lm = fmax(lm, v);
  }
  for (int m = 32; m >= 1; m >>= 1) lm = fmax(lm, __shfl_xor(lm, m));
  if (lane == 0) redd[wv] = lm;
  __syncthreads();
  double rowmax = fmax(fmax(redd[0], redd[1]), fmax(redd[2], redd[3]));
  __syncthreads();
  for (int i = tid; i < 1024; i += 256){
    double v = xu[i] - rowmax;
    xu[i] = v; sbd[i] = v;
  }
  __syncthreads();

  // bitonic ascending sort (f64)
  for (int ksz = 2; ksz <= 1024; ksz <<= 1){
    for (int jj = ksz >> 1; jj > 0; jj >>= 1){
      for (int i = tid; i < 1024; i += 256){
        int ixj = i ^ jj;
        if (ixj > i){
          double a = sbd[i], c = sbd[ixj];
          if (((i & ksz) == 0) ? (a > c) : (a < c)){ sbd[i] = c; sbd[ixj] = a; }
        }
      }
      __syncthreads();
    }
  }

  // descending view; inclusive scan (f64)
  for (int i = tid; i < 1024; i += 256) t0d[i] = sbd[1023 - i];
  __syncthreads();
  double* src = t0d; double* dst = t1d;
  for (int off = 1; off < 1024; off <<= 1){
    for (int i = tid; i < 1024; i += 256)
      dst[i] = src[i] + ((i >= off) ? src[i - off] : 0.0);
    __syncthreads();
    double* tmp = src; src = dst; dst = tmp;
  }

  float lc = 0.f;
  for (int i = tid; i < 1024; i += 256){
    double xs_i = sbd[1023 - i];
    double sup = (double)(i + 1) * xs_i - src[i] + 0.5;
    if (sup > 0.0) lc += 1.f;
  }
  for (int m = 32; m >= 1; m >>= 1) lc += __shfl_xor(lc, m);
  if (lane == 0) red4[wv] = lc;
  __syncthreads();
  if (tid == 0){
    int cntS = (int)(red4[0] + red4[1] + red4[2] + red4[3] + 0.5f);
    int ss = cntS < 1 ? 1 : (cntS > 1023 ? 1023 : cntS);
    double xss = sbd[1023 - ss];
    scald = ((double)(ss + 1) * xss - src[ss] + 0.5) / (double)(ss + 1);
  }
  __syncthreads();
  double tau = scald;

  double ls = 0.0;
  for (int i = tid; i < 1024; i += 256){
    double d = xu[i] - tau;
    double y = (d > 0.0) ? sqrt(d) : 0.0;
    dst[i] = y;
    ls += y;
  }
  for (int m = 32; m >= 1; m >>= 1) ls += __shfl_xor(ls, m);
  if (lane == 0) redd[wv] = ls;
  __syncthreads();
  double Z = redd[0] + redd[1] + redd[2] + redd[3];
  __syncthreads();
  for (int i = tid; i < 1024; i += 256){
    float a = (float)(dst[i] / Z);
    sbf[i] = a;
    out[128 + b * 1024 + i] = a;
  }
  __syncthreads();

  // context over nonzero weights + FC (O=1)
  const int h0 = tid * 2;
  float cx0 = 0.f, cx1 = 0.f;
  for (int s = 0; s < 1024; ++s){
    float wt = sbf[s];
    if (wt > 0.f){
      unsigned int u = *(const unsigned int*)(h2 + ((size_t)b * 1024 + s) * 512 + h0);
      union { unsigned int u; _Float16 h[2]; } cv; cv.u = u;
      cx0 += wt * (float)cv.h[0];
      cx1 += wt * (float)cv.h[1];
    }
  }
  float p = fcW[h0] * cx0 + fcW[h0 + 1] * cx1;
  for (int m = 32; m >= 1; m >>= 1) p += __shfl_xor(p, m);
  if (lane == 0) red4[wv] = p;
  __syncthreads();
  if (tid == 0) out[b] = red4[0] + red4[1] + red4[2] + red4[3] + fcb[0];
}

// ---------------- host launch ----------------
extern "C" void kernel_launch(void* const* d_in, const int* in_sizes, int n_in,
                              void* d_out, int out_size, void* d_ws, size_t ws_size,
                              hipStream_t stream)
{
  (void)in_sizes; (void)n_in; (void)out_size;
  const float* x    = (const float*)d_in[0];
  const float* Wih0 = (const float*)d_in[1];
  const float* Whh0 = (const float*)d_in[2];
  const float* bih0 = (const float*)d_in[3];
  const float* bhh0 = (const float*)d_in[4];
  const float* Wih1 = (const float*)d_in[5];
  const float* Whh1 = (const float*)d_in[6];
  const float* bih1 = (const float*)d_in[7];
  const float* bhh1 = (const float*)d_in[8];
  const float* Wa   = (const float*)d_in[9];
  const float* ba   = (const float*)d_in[10];
  const float* va   = (const float*)d_in[11];
  const float* bv   = (const float*)d_in[12];
  const float* fcW  = (const float*)d_in[13];
  const float* fcb  = (const float*)d_in[14];

  const size_t NEED = 223773696ull;
  if (ws_size < NEED) return;

  char* ws = (char*)d_ws;
  unsigned int* cnt = (unsigned int*)(ws);                  // 1 KiB (256 flags)
  char* w0p[5]; for (int p = 0; p < 5; ++p) w0p[p] = ws + 1024ull + (size_t)p * 1179648ull;
  double* bias0 = (double*)(ws + 5899264ull);               // 16,384
  char* w1p[5]; for (int p = 0; p < 5; ++p) w1p[p] = ws + 5915648ull + (size_t)p * 2097152ull;
  double* bias1 = (double*)(ws + 16401408ull);              // 16,384
  char* wa1 = ws + 16417792ull;                             // 4 x 262,144
  char* wa2 = wa1 + 262144ull;
  char* wa3 = wa2 + 262144ull;
  char* wa4 = wa3 + 262144ull;
  char* h1p[5]; for (int p = 0; p < 5; ++p) h1p[p] = ws + 17466368ull + (size_t)p * 524288ull;  // 8 slots
  char* h2p[5]; for (int p = 0; p < 5; ++p) h2p[p] = ws + 20087808ull + (size_t)p * 262144ull;  // 4 slots
  double* ebuf = (double*)(ws + 21398528ull);               // 1,048,576
  _Float16* h2h = (_Float16*)(ws + 22447104ull);            // 134,217,728
  char* h2l8 = ws + 156664832ull;                           // 67,108,864
  float* out = (float*)d_out;

  k_prep_zero<<<1, 256, 0, stream>>>(cnt);
  k_prep_w0<<<4608, 256, 0, stream>>>(Wih0, Whh0, w0p[0], w0p[1], w0p[2], w0p[3], w0p[4]);
  k_prep_w1<<<8192, 256, 0, stream>>>(Wih1, Whh1, w1p[0], w1p[1], w1p[2], w1p[3], w1p[4]);
  k_prep_b<<<16, 256, 0, stream>>>(bih0, bhh0, bih1, bhh1, bias0, bias1);
  k_prep_wa<<<1024, 256, 0, stream>>>(Wa, wa1, wa2, wa3, wa4);
  k_lstm_fused<<<256, 256, 0, stream>>>(x,
      w0p[0], w0p[1], w0p[2], w0p[3], w0p[4], bias0,
      w1p[0], w1p[1], w1p[2], w1p[3], w1p[4], bias1,
      h1p[0], h1p[1], h1p[2], h1p[3], h1p[4],
      h2p[0], h2p[1], h2p[2], h2p[3], h2p[4],
      h2h, h2l8, cnt);
  k_att_e<<<4096, 256, 0, stream>>>(h2h, h2l8, wa1, wa2, wa3, wa4, ba, va, bv, ebuf);
  k_entmax<<<128, 256, 0, stream>>>(ebuf, h2h, fcW, fcb, out);
}